// Round 2
// baseline (518.989 us; speedup 1.0000x reference)
//
#include <hip/hip_runtime.h>
#include <stdint.h>

// ---------- types ----------
typedef float f32x4 __attribute__((ext_vector_type(4)));
typedef __bf16 bf16x8 __attribute__((ext_vector_type(8)));
typedef __bf16 bf16x8_a __attribute__((ext_vector_type(8), may_alias));
typedef unsigned int u32x4_a __attribute__((ext_vector_type(4), may_alias));
typedef unsigned short u16x4_a __attribute__((ext_vector_type(4), may_alias));

#define DEV __device__ __forceinline__

DEV unsigned short f2b(float f) {  // f32 -> bf16 RNE
  unsigned int u = __float_as_uint(f);
  u = u + 0x7FFFu + ((u >> 16) & 1u);
  return (unsigned short)(u >> 16);
}

// async global->LDS, 16B per lane; LDS dest is wave-uniform base + lane*16
#define GLOAD_LDS16(gsrc, ldst)                                                  \
  __builtin_amdgcn_global_load_lds(                                              \
      (__attribute__((address_space(1))) void*)(uintptr_t)(const void*)(gsrc),   \
      (__attribute__((address_space(3))) void*)(ldst), 16, 0, 0)

// ---------- conversion kernels ----------
__global__ __launch_bounds__(256) void cvt_kernel(const float* __restrict__ in,
                                                  unsigned short* __restrict__ out, int n4) {
  int i = blockIdx.x * 256 + threadIdx.x;
  if (i < n4) {
    float4 v = ((const float4*)in)[i];
    u16x4_a t = {f2b(v.x), f2b(v.y), f2b(v.z), f2b(v.w)};
    ((u16x4_a*)out)[i] = t;
  }
}

// in: [rows][cols] f32 (batched on z) -> out: [cols][rows] bf16 (*scale)
__global__ __launch_bounds__(256) void transpose_cvt(const float* __restrict__ in,
                                                     unsigned short* __restrict__ out,
                                                     int rows, int cols, float scale) {
  __shared__ float tile[32][33];
  const int tx = threadIdx.x & 31, ty = threadIdx.x >> 5;
  const int c0 = blockIdx.x * 32, r0 = blockIdx.y * 32;
  const float* ip = in + (size_t)blockIdx.z * rows * cols;
  unsigned short* op = out + (size_t)blockIdx.z * rows * cols;
#pragma unroll
  for (int j = 0; j < 32; j += 8)
    tile[ty + j][tx] = ip[(size_t)(r0 + ty + j) * cols + (c0 + tx)];
  __syncthreads();
#pragma unroll
  for (int j = 0; j < 32; j += 8)
    op[(size_t)(c0 + ty + j) * rows + (r0 + tx)] = f2b(tile[tx][ty + j] * scale);
}

__global__ void build_bias_qkv(const float* __restrict__ bq, const float* __restrict__ bk,
                               const float* __restrict__ bv, float* __restrict__ out) {
  int c = blockIdx.x * 256 + threadIdx.x;  // 0..3071
  int which = c >> 10, idx = c & 1023;
  float v = which == 0 ? bq[idx] : (which == 1 ? bk[idx] : bv[idx]);
  out[c] = which == 0 ? v * 0.125f : v;  // fold 1/sqrt(HD) into q
}

// ---------- GEMM: C[M][N] = A[M][K](bf16) * Bt[N][K]^T(bf16), m97 structure ----------
// EP 0: QKV scatter->bf16 Q,K:[B*H,S,HD], V: transposed [B*H,HD,S] (+bias).
// EP 1: f32 out = acc+bias+addf (residual). EP 2: bf16 out = relu(acc+bias).
template <int EP>
__global__ __launch_bounds__(256) void gemm_bt_kernel(
    const unsigned short* __restrict__ A, const unsigned short* __restrict__ Bt,
    int M, int N, int K,
    const float* __restrict__ bias, const float* __restrict__ addf,
    float* __restrict__ outf, unsigned short* __restrict__ outb,
    unsigned short* __restrict__ q_out, unsigned short* __restrict__ k_out,
    unsigned short* __restrict__ v_out) {
  __shared__ __align__(16) unsigned short sA[128 * 32];
  __shared__ __align__(16) unsigned short sB[128 * 32];
  const int tid = threadIdx.x;
  const int wid = tid >> 6, lane = tid & 63;
  const int g = lane >> 4, r15 = lane & 15;
  const int wr = wid >> 1, wc = wid & 1;
  const int row0 = blockIdx.y * 128, col0 = blockIdx.x * 128;

  f32x4 acc[4][4] = {};

  const int c0 = wid * 128 + lane;
  const unsigned short* gA0 = A + (size_t)row0 * K;
  const unsigned short* gB0 = Bt + (size_t)col0 * K;

  for (int k0 = 0; k0 < K; k0 += 32) {
#pragma unroll
    for (int j = 0; j < 2; ++j) {
      int c = c0 + j * 64;
      GLOAD_LDS16(gA0 + (size_t)(c >> 2) * K + k0 + (c & 3) * 8, &sA[(wid * 128 + j * 64) * 8]);
      GLOAD_LDS16(gB0 + (size_t)(c >> 2) * K + k0 + (c & 3) * 8, &sB[(wid * 128 + j * 64) * 8]);
    }
    __syncthreads();
    bf16x8 af[4], bfr[4];
#pragma unroll
    for (int m = 0; m < 4; ++m)
      af[m] = *(const bf16x8_a*)&sA[(wr * 64 + m * 16 + r15) * 32 + g * 8];
#pragma unroll
    for (int n = 0; n < 4; ++n)
      bfr[n] = *(const bf16x8_a*)&sB[(wc * 64 + n * 16 + r15) * 32 + g * 8];
#pragma unroll
    for (int m = 0; m < 4; ++m)
#pragma unroll
      for (int n = 0; n < 4; ++n)
        acc[m][n] = __builtin_amdgcn_mfma_f32_16x16x32_bf16(af[m], bfr[n], acc[m][n], 0, 0, 0);
    __syncthreads();
  }

// epilogue: D row = row0+wr*64+m*16+g*4+r ; col = col0+wc*64+n*16+r15
#pragma unroll
  for (int m = 0; m < 4; ++m) {
    const int rbase = row0 + wr * 64 + m * 16 + g * 4;
#pragma unroll
    for (int n = 0; n < 4; ++n) {
      const int col = col0 + wc * 64 + n * 16 + r15;
      const float bb = bias[col];
#pragma unroll
      for (int r = 0; r < 4; ++r) {
        const int row = rbase + r;
        float v = acc[m][n][r] + bb;
        if constexpr (EP == 0) {
          int which = col >> 10, cc = col & 1023;
          int h = cc >> 6, e = cc & 63;
          int b = row >> 11, s = row & 2047;
          if (which == 2) {
            // V transposed: [bh][d][s]
            v_out[(((size_t)(b * 16 + h) * 64) + e) * 2048 + s] = f2b(v);
          } else {
            unsigned short* dst = which == 0 ? q_out : k_out;
            dst[(((size_t)(b * 16 + h) * 2048) + s) * 64 + e] = f2b(v);
          }
        } else if constexpr (EP == 1) {
          size_t idx = (size_t)row * N + col;
          outf[idx] = v + addf[idx];
        } else {
          outb[(size_t)row * N + col] = f2b(v > 0.f ? v : 0.f);
        }
      }
    }
  }
}

// ---------- flash attention: Q,K bf16 [BH,S,64], Vt bf16 [BH,64,S] -> concat bf16 [B*S,1024]
// 4 independent waves per block, wave w owns q rows [q0+16w, q0+16w+16); KVBLK=64.
// No LDS staging of K/V (L2-resident), no __syncthreads. Only per-wave sP round-trip.
__global__ __launch_bounds__(256) void attn_kernel(const unsigned short* __restrict__ Q,
                                                   const unsigned short* __restrict__ K,
                                                   const unsigned short* __restrict__ Vt,
                                                   unsigned short* __restrict__ out) {
  // XCD-aware swizzle: each XCD owns 4 consecutive bh (KV footprint 2MB -> L2-resident)
  const int flat = blockIdx.y * gridDim.x + blockIdx.x;  // 0..1023
  const int xcd = flat & 7, rest = flat >> 3;            // rest 0..127
  const int bh = xcd * 4 + (rest >> 5);
  const int q0 = (rest & 31) * 64;

  const int tid = threadIdx.x, wid = tid >> 6, lane = tid & 63;
  const int g = lane >> 4, r15 = lane & 15;
  __shared__ __align__(16) unsigned short sP[4][16 * 72];  // per-wave P [q][key], stride 72
  const size_t base = (size_t)bh * (2048 * 64);

  const int qrow = q0 + wid * 16 + r15;
  bf16x8 qf[2];
  qf[0] = *(const bf16x8_a*)(Q + base + (size_t)qrow * 64 + g * 8);
  qf[1] = *(const bf16x8_a*)(Q + base + (size_t)qrow * 64 + 32 + g * 8);

  // bf16 1.0 splat for row-sum MFMA
  union {
    unsigned short u[8];
    bf16x8 v;
  } ou;
#pragma unroll
  for (int i = 0; i < 8; ++i) ou.u[i] = 0x3F80;
  const bf16x8 onesb = ou.v;

  f32x4 o[4] = {};
  float mrow[4], lrow[4];
#pragma unroll
  for (int r = 0; r < 4; ++r) { mrow[r] = -1e30f; lrow[r] = 0.f; }

  const unsigned short* Kb = K + base;
  const unsigned short* Vb = Vt + base;

  for (int kt0 = 0; kt0 < 2048; kt0 += 64) {
    // scores: 16q x 64k, K fragments straight from global (L1/L2)
    f32x4 sc[4] = {};
#pragma unroll
    for (int kt = 0; kt < 4; ++kt) {
      const unsigned short* kr = Kb + (size_t)(kt0 + kt * 16 + r15) * 64;
      bf16x8 kf0 = *(const bf16x8_a*)(kr + g * 8);
      bf16x8 kf1 = *(const bf16x8_a*)(kr + 32 + g * 8);
      sc[kt] = __builtin_amdgcn_mfma_f32_16x16x32_bf16(qf[0], kf0, sc[kt], 0, 0, 0);
      sc[kt] = __builtin_amdgcn_mfma_f32_16x16x32_bf16(qf[1], kf1, sc[kt], 0, 0, 0);
    }

    // online softmax; row q = g*4+r lives in the 16 lanes of group g
    float fac[4];
#pragma unroll
    for (int r = 0; r < 4; ++r) {
      float mx = fmaxf(fmaxf(sc[0][r], sc[1][r]), fmaxf(sc[2][r], sc[3][r]));
#pragma unroll
      for (int msk = 1; msk < 16; msk <<= 1) mx = fmaxf(mx, __shfl_xor(mx, msk));
      float nm = fmaxf(mrow[r], mx);
      fac[r] = __expf(mrow[r] - nm);
      mrow[r] = nm;
#pragma unroll
      for (int kt = 0; kt < 4; ++kt) {
        float p = __expf(sc[kt][r] - nm);
        sP[wid][(g * 4 + r) * 72 + kt * 16 + r15] = f2b(p);
      }
#pragma unroll
      for (int dt = 0; dt < 4; ++dt) o[dt][r] *= fac[r];
    }

    // P fragments (A-operand layout: row q=r15, keys g*8..): in-order DS ops make
    // the cross-lane write->read safe within a wave without a barrier.
    bf16x8 pf0 = *(const bf16x8_a*)&sP[wid][r15 * 72 + g * 8];
    bf16x8 pf1 = *(const bf16x8_a*)&sP[wid][r15 * 72 + 32 + g * 8];

    // row sums via MFMA with ones-B (replaces 16 shuffles)
    f32x4 lacc = {};
    lacc = __builtin_amdgcn_mfma_f32_16x16x32_bf16(pf0, onesb, lacc, 0, 0, 0);
    lacc = __builtin_amdgcn_mfma_f32_16x16x32_bf16(pf1, onesb, lacc, 0, 0, 0);
#pragma unroll
    for (int r = 0; r < 4; ++r) lrow[r] = lrow[r] * fac[r] + lacc[r];

    // PV: B-operand from V^T rows, straight from global
#pragma unroll
    for (int dt = 0; dt < 4; ++dt) {
      const unsigned short* vr = Vb + (size_t)(dt * 16 + r15) * 2048 + kt0;
      bf16x8 vf0 = *(const bf16x8_a*)(vr + g * 8);
      bf16x8 vf1 = *(const bf16x8_a*)(vr + 32 + g * 8);
      o[dt] = __builtin_amdgcn_mfma_f32_16x16x32_bf16(pf0, vf0, o[dt], 0, 0, 0);
      o[dt] = __builtin_amdgcn_mfma_f32_16x16x32_bf16(pf1, vf1, o[dt], 0, 0, 0);
    }
  }

  // epilogue: out[b][s][h*64+d]
  const int b = bh >> 4, h = bh & 15;
#pragma unroll
  for (int r = 0; r < 4; ++r) {
    float inv = 1.f / lrow[r];
    int s = q0 + wid * 16 + g * 4 + r;
    size_t rowoff = ((size_t)(b * 2048 + s)) * 1024 + h * 64;
#pragma unroll
    for (int dt = 0; dt < 4; ++dt) out[rowoff + dt * 16 + r15] = f2b(o[dt][r] * inv);
  }
}

// ---------- LayerNorm over 1024 cols; optional f32 and bf16 outputs ----------
__global__ __launch_bounds__(256) void ln_kernel(const float* __restrict__ in,
                                                 const float* __restrict__ gamma,
                                                 const float* __restrict__ beta,
                                                 float* __restrict__ outf,
                                                 unsigned short* __restrict__ outb) {
  const int row = blockIdx.x, tid = threadIdx.x;
  float4 v = ((const float4*)(in + (size_t)row * 1024))[tid];
  float s = v.x + v.y + v.z + v.w;
  float ss = v.x * v.x + v.y * v.y + v.z * v.z + v.w * v.w;
#pragma unroll
  for (int off = 32; off > 0; off >>= 1) {
    s += __shfl_down(s, off);
    ss += __shfl_down(ss, off);
  }
  __shared__ float red[8];
  const int wid = tid >> 6;
  if ((tid & 63) == 0) { red[wid] = s; red[4 + wid] = ss; }
  __syncthreads();
  float S = red[0] + red[1] + red[2] + red[3];
  float SS = red[4] + red[5] + red[6] + red[7];
  const float mean = S * (1.f / 1024.f);
  const float var = SS * (1.f / 1024.f) - mean * mean;
  const float inv = 1.f / sqrtf(var + 1e-10f);
  float4 gg = ((const float4*)gamma)[tid];
  float4 bb = ((const float4*)beta)[tid];
  float4 o;
  o.x = (v.x - mean) * inv * gg.x + bb.x;
  o.y = (v.y - mean) * inv * gg.y + bb.y;
  o.z = (v.z - mean) * inv * gg.z + bb.z;
  o.w = (v.w - mean) * inv * gg.w + bb.w;
  if (outf) ((float4*)(outf + (size_t)row * 1024))[tid] = o;
  if (outb) {
    u16x4_a t = {f2b(o.x), f2b(o.y), f2b(o.z), f2b(o.w)};
    *(u16x4_a*)(outb + (size_t)row * 1024 + tid * 4) = t;
  }
}

// ---------- launch ----------
extern "C" void kernel_launch(void* const* d_in, const int* in_sizes, int n_in,
                              void* d_out, int out_size, void* d_ws, size_t ws_size,
                              hipStream_t stream) {
  const float* x      = (const float*)d_in[0];
  const float* wq     = (const float*)d_in[1];
  const float* bq     = (const float*)d_in[2];
  const float* wk     = (const float*)d_in[3];
  const float* bk     = (const float*)d_in[4];
  const float* wv     = (const float*)d_in[5];
  const float* bv     = (const float*)d_in[6];
  const float* w_proj = (const float*)d_in[7];
  const float* b_proj = (const float*)d_in[8];
  const float* gamma1 = (const float*)d_in[9];
  const float* beta1  = (const float*)d_in[10];
  const float* w1     = (const float*)d_in[11];
  const float* b1     = (const float*)d_in[12];
  const float* w2     = (const float*)d_in[13];
  const float* b2     = (const float*)d_in[14];
  const float* gamma2 = (const float*)d_in[15];
  const float* beta2  = (const float*)d_in[16];

  char* p = (char*)d_ws;
  auto alloc = [&](size_t bytes) {
    char* r = p;
    p += (bytes + 255) & ~(size_t)255;
    return r;
  };
  unsigned short* xb      = (unsigned short*)alloc(4096ull * 1024 * 2);  // reused as concat
  unsigned short* Wqkv_t  = (unsigned short*)alloc(3072ull * 1024 * 2);
  unsigned short* Wproj_t = (unsigned short*)alloc(1024ull * 1024 * 2);
  unsigned short* W1t     = (unsigned short*)alloc(4096ull * 1024 * 2);
  unsigned short* W2t     = (unsigned short*)alloc(1024ull * 4096 * 2);
  float*          biasq   = (float*)alloc(3072 * 4);
  unsigned short* Qb      = (unsigned short*)alloc(4096ull * 1024 * 2);
  unsigned short* Kb      = (unsigned short*)alloc(4096ull * 1024 * 2);
  unsigned short* Vtb     = (unsigned short*)alloc(4096ull * 1024 * 2);  // [BH][64][2048]
  float*          resid1  = (float*)alloc(4096ull * 1024 * 4);  // reused as resid2
  float*          out1f   = (float*)alloc(4096ull * 1024 * 4);
  unsigned short* out1b   = (unsigned short*)alloc(4096ull * 1024 * 2);
  unsigned short* ffn_h   = (unsigned short*)alloc(4096ull * 4096 * 2);
  unsigned short* concat  = xb;
  float*          resid2  = resid1;

  cvt_kernel<<<4096, 256, 0, stream>>>(x, xb, 4096 * 1024 / 4);
  transpose_cvt<<<dim3(2, 32, 16), 256, 0, stream>>>(wq, Wqkv_t, 1024, 64, 0.125f);
  transpose_cvt<<<dim3(2, 32, 16), 256, 0, stream>>>(wk, Wqkv_t + 1024 * 1024, 1024, 64, 1.f);
  transpose_cvt<<<dim3(2, 32, 16), 256, 0, stream>>>(wv, Wqkv_t + 2048 * 1024, 1024, 64, 1.f);
  transpose_cvt<<<dim3(32, 32, 1), 256, 0, stream>>>(w_proj, Wproj_t, 1024, 1024, 1.f);
  transpose_cvt<<<dim3(128, 32, 1), 256, 0, stream>>>(w1, W1t, 1024, 4096, 1.f);
  transpose_cvt<<<dim3(32, 128, 1), 256, 0, stream>>>(w2, W2t, 4096, 1024, 1.f);
  build_bias_qkv<<<12, 256, 0, stream>>>(bq, bk, bv, biasq);

  gemm_bt_kernel<0><<<dim3(24, 32), 256, 0, stream>>>(xb, Wqkv_t, 4096, 3072, 1024, biasq,
                                                      nullptr, nullptr, nullptr, Qb, Kb, Vtb);
  attn_kernel<<<dim3(32, 32), 256, 0, stream>>>(Qb, Kb, Vtb, concat);
  gemm_bt_kernel<1><<<dim3(8, 32), 256, 0, stream>>>(concat, Wproj_t, 4096, 1024, 1024, b_proj,
                                                     x, resid1, nullptr, nullptr, nullptr, nullptr);
  ln_kernel<<<4096, 256, 0, stream>>>(resid1, gamma1, beta1, out1f, out1b);
  gemm_bt_kernel<2><<<dim3(32, 32), 256, 0, stream>>>(out1b, W1t, 4096, 4096, 1024, b1, nullptr,
                                                      nullptr, ffn_h, nullptr, nullptr, nullptr);
  gemm_bt_kernel<1><<<dim3(8, 32), 256, 0, stream>>>(ffn_h, W2t, 4096, 1024, 4096, b2, out1f,
                                                     resid2, nullptr, nullptr, nullptr, nullptr);
  ln_kernel<<<4096, 256, 0, stream>>>(resid2, gamma2, beta2, (float*)d_out, nullptr);
}

// Round 3
// 404.082 us; speedup vs baseline: 1.2844x; 1.2844x over previous
//
#include <hip/hip_runtime.h>
#include <stdint.h>

// ---------- types ----------
typedef float f32x4 __attribute__((ext_vector_type(4)));
typedef __bf16 bf16x8 __attribute__((ext_vector_type(8)));
typedef __bf16 bf16x8_a __attribute__((ext_vector_type(8), may_alias));
typedef unsigned int u32x4_a __attribute__((ext_vector_type(4), may_alias));
typedef unsigned short u16x4_a __attribute__((ext_vector_type(4), may_alias));

#define DEV __device__ __forceinline__

DEV unsigned short f2b(float f) {  // f32 -> bf16 RNE
  unsigned int u = __float_as_uint(f);
  u = u + 0x7FFFu + ((u >> 16) & 1u);
  return (unsigned short)(u >> 16);
}

// async global->LDS, 16B per lane; LDS dest is wave-uniform base + lane*16
#define GLOAD_LDS16(gsrc, ldst)                                                  \
  __builtin_amdgcn_global_load_lds(                                              \
      (__attribute__((address_space(1))) void*)(uintptr_t)(const void*)(gsrc),   \
      (__attribute__((address_space(3))) void*)(ldst), 16, 0, 0)

// ---------- conversion kernels ----------
__global__ __launch_bounds__(256) void cvt_kernel(const float* __restrict__ in,
                                                  unsigned short* __restrict__ out, int n4) {
  int i = blockIdx.x * 256 + threadIdx.x;
  if (i < n4) {
    float4 v = ((const float4*)in)[i];
    u16x4_a t = {f2b(v.x), f2b(v.y), f2b(v.z), f2b(v.w)};
    ((u16x4_a*)out)[i] = t;
  }
}

// in: [rows][cols] f32 (batched on z) -> out: [cols][rows] bf16 (*scale)
__global__ __launch_bounds__(256) void transpose_cvt(const float* __restrict__ in,
                                                     unsigned short* __restrict__ out,
                                                     int rows, int cols, float scale) {
  __shared__ float tile[32][33];
  const int tx = threadIdx.x & 31, ty = threadIdx.x >> 5;
  const int c0 = blockIdx.x * 32, r0 = blockIdx.y * 32;
  const float* ip = in + (size_t)blockIdx.z * rows * cols;
  unsigned short* op = out + (size_t)blockIdx.z * rows * cols;
#pragma unroll
  for (int j = 0; j < 32; j += 8)
    tile[ty + j][tx] = ip[(size_t)(r0 + ty + j) * cols + (c0 + tx)];
  __syncthreads();
#pragma unroll
  for (int j = 0; j < 32; j += 8)
    op[(size_t)(c0 + ty + j) * rows + (r0 + tx)] = f2b(tile[tx][ty + j] * scale);
}

__global__ void build_bias_qkv(const float* __restrict__ bq, const float* __restrict__ bk,
                               const float* __restrict__ bv, float* __restrict__ out) {
  int c = blockIdx.x * 256 + threadIdx.x;  // 0..3071
  int which = c >> 10, idx = c & 1023;
  float v = which == 0 ? bq[idx] : (which == 1 ? bk[idx] : bv[idx]);
  out[c] = which == 0 ? v * 0.125f : v;  // fold 1/sqrt(HD) into q
}

// ---------- GEMM: C[M][N] = A[M][K](bf16) * Bt[N][K]^T(bf16), m97 structure ----------
// EP 0: QKV scatter->bf16 Q,K:[B*H,S,HD], V: transposed [B*H,HD,S] (+bias).
// EP 1: f32 out = acc+bias+addf (residual). EP 2: bf16 out = relu(acc+bias).
template <int EP>
__global__ __launch_bounds__(256) void gemm_bt_kernel(
    const unsigned short* __restrict__ A, const unsigned short* __restrict__ Bt,
    int M, int N, int K,
    const float* __restrict__ bias, const float* __restrict__ addf,
    float* __restrict__ outf, unsigned short* __restrict__ outb,
    unsigned short* __restrict__ q_out, unsigned short* __restrict__ k_out,
    unsigned short* __restrict__ v_out) {
  __shared__ __align__(16) unsigned short sA[128 * 32];
  __shared__ __align__(16) unsigned short sB[128 * 32];
  const int tid = threadIdx.x;
  const int wid = tid >> 6, lane = tid & 63;
  const int g = lane >> 4, r15 = lane & 15;
  const int wr = wid >> 1, wc = wid & 1;
  const int row0 = blockIdx.y * 128, col0 = blockIdx.x * 128;

  f32x4 acc[4][4] = {};

  const int c0 = wid * 128 + lane;
  const unsigned short* gA0 = A + (size_t)row0 * K;
  const unsigned short* gB0 = Bt + (size_t)col0 * K;

  for (int k0 = 0; k0 < K; k0 += 32) {
#pragma unroll
    for (int j = 0; j < 2; ++j) {
      int c = c0 + j * 64;
      GLOAD_LDS16(gA0 + (size_t)(c >> 2) * K + k0 + (c & 3) * 8, &sA[(wid * 128 + j * 64) * 8]);
      GLOAD_LDS16(gB0 + (size_t)(c >> 2) * K + k0 + (c & 3) * 8, &sB[(wid * 128 + j * 64) * 8]);
    }
    __syncthreads();
    bf16x8 af[4], bfr[4];
#pragma unroll
    for (int m = 0; m < 4; ++m)
      af[m] = *(const bf16x8_a*)&sA[(wr * 64 + m * 16 + r15) * 32 + g * 8];
#pragma unroll
    for (int n = 0; n < 4; ++n)
      bfr[n] = *(const bf16x8_a*)&sB[(wc * 64 + n * 16 + r15) * 32 + g * 8];
#pragma unroll
    for (int m = 0; m < 4; ++m)
#pragma unroll
      for (int n = 0; n < 4; ++n)
        acc[m][n] = __builtin_amdgcn_mfma_f32_16x16x32_bf16(af[m], bfr[n], acc[m][n], 0, 0, 0);
    __syncthreads();
  }

// epilogue: D row = row0+wr*64+m*16+g*4+r ; col = col0+wc*64+n*16+r15
#pragma unroll
  for (int m = 0; m < 4; ++m) {
    const int rbase = row0 + wr * 64 + m * 16 + g * 4;
#pragma unroll
    for (int n = 0; n < 4; ++n) {
      const int col = col0 + wc * 64 + n * 16 + r15;
      const float bb = bias[col];
#pragma unroll
      for (int r = 0; r < 4; ++r) {
        const int row = rbase + r;
        float v = acc[m][n][r] + bb;
        if constexpr (EP == 0) {
          int which = col >> 10, cc = col & 1023;
          int h = cc >> 6, e = cc & 63;
          int b = row >> 11, s = row & 2047;
          if (which == 2) {
            // V transposed: [bh][d][s]
            v_out[(((size_t)(b * 16 + h) * 64) + e) * 2048 + s] = f2b(v);
          } else {
            unsigned short* dst = which == 0 ? q_out : k_out;
            dst[(((size_t)(b * 16 + h) * 2048) + s) * 64 + e] = f2b(v);
          }
        } else if constexpr (EP == 1) {
          size_t idx = (size_t)row * N + col;
          outf[idx] = v + addf[idx];
        } else {
          outb[(size_t)row * N + col] = f2b(v > 0.f ? v : 0.f);
        }
      }
    }
  }
}

// ---------- flash attention: Q,K bf16 [BH,S,64], Vt bf16 [BH,64,S] -> concat bf16 [B*S,1024]
// 4 waves, wave w owns q rows [q0+16w, q0+16w+16); KVBLK=64.
// K and V^T staged in LDS via global_load_lds (16B), DOUBLE-BUFFERED; XOR-swizzled
// layout (linear LDS dest + inverse-swizzled global source + swizzled read offsets).
__global__ __launch_bounds__(256) void attn_kernel(const unsigned short* __restrict__ Q,
                                                   const unsigned short* __restrict__ K,
                                                   const unsigned short* __restrict__ Vt,
                                                   unsigned short* __restrict__ out) {
  // XCD-aware swizzle: each XCD owns 4 consecutive bh (KV footprint 2MB -> L2-resident)
  const int flat = blockIdx.y * gridDim.x + blockIdx.x;  // 0..1023
  const int xcd = flat & 7, rest = flat >> 3;            // rest 0..127
  const int bh = xcd * 4 + (rest >> 5);
  const int q0 = (rest & 31) * 64;

  const int tid = threadIdx.x, wid = tid >> 6, lane = tid & 63;
  const int g = lane >> 4, r15 = lane & 15;
  // swizzle: 16B-slot within a 128B row is stored at slot^(row&7)
  const int h = r15 & 7;
  const int s0 = ((g ^ h) * 8);        // ushort offset of slot g in swizzled row
  const int s1 = (((g + 4) ^ h) * 8);  // ushort offset of slot 4+g

  __shared__ __align__(16) unsigned short sK[2][64 * 64];
  __shared__ __align__(16) unsigned short sV[2][64 * 64];
  __shared__ __align__(16) unsigned short sP[4][16 * 72];  // per-wave P [q][key], stride 72

  const size_t base = (size_t)bh * (2048 * 64);
  const unsigned short* Kb = K + base;
  const unsigned short* Vb = Vt + base;

  const int qrow = q0 + wid * 16 + r15;
  bf16x8 qf[2];
  qf[0] = *(const bf16x8_a*)(Q + base + (size_t)qrow * 64 + g * 8);
  qf[1] = *(const bf16x8_a*)(Q + base + (size_t)qrow * 64 + 32 + g * 8);

  // staging geometry: wave w stages rows 16w..16w+15 (2 instrs x 8 rows);
  // lane covers row = 8*inst + (lane>>3), chunk = (lane&7) ^ (lane>>3)  (inverse swizzle)
  const int srow = lane >> 3;                 // 0..7 within 8-row group
  const int schunk = ((lane & 7) ^ srow) * 8; // ushort offset of this lane's 16B chunk

  // bf16 1.0 splat for row-sum MFMA
  union {
    unsigned short u[8];
    bf16x8 v;
  } ou;
#pragma unroll
  for (int i = 0; i < 8; ++i) ou.u[i] = 0x3F80;
  const bf16x8 onesb = ou.v;

  f32x4 o[4] = {};
  float mrow[4], lrow[4];
#pragma unroll
  for (int r = 0; r < 4; ++r) { mrow[r] = -1e30f; lrow[r] = 0.f; }

  auto stage = [&](int bufi, int kt0s) {
#pragma unroll
    for (int i = 0; i < 2; ++i) {
      const int inst = wid * 2 + i;          // 0..7 -> rows 8*inst..8*inst+7
      const int row = 8 * inst + srow;
      GLOAD_LDS16(Kb + (size_t)(kt0s + row) * 64 + schunk, &sK[bufi][inst * 512]);
      GLOAD_LDS16(Vb + (size_t)row * 2048 + kt0s + schunk, &sV[bufi][inst * 512]);
    }
  };

  stage(0, 0);

  for (int t = 0; t < 32; ++t) {
    const int cur = t & 1;
    __syncthreads();  // drains vmcnt -> buf[cur] ready; all reads of buf[cur^1] done
    if (t < 31) stage(cur ^ 1, (t + 1) * 64);

    // scores: 16q x 64k from swizzled sK
    f32x4 sc[4] = {};
#pragma unroll
    for (int kt = 0; kt < 4; ++kt) {
      const int rb = (kt * 16 + r15) * 64;
      bf16x8 kf0 = *(const bf16x8_a*)&sK[cur][rb + s0];
      bf16x8 kf1 = *(const bf16x8_a*)&sK[cur][rb + s1];
      sc[kt] = __builtin_amdgcn_mfma_f32_16x16x32_bf16(qf[0], kf0, sc[kt], 0, 0, 0);
      sc[kt] = __builtin_amdgcn_mfma_f32_16x16x32_bf16(qf[1], kf1, sc[kt], 0, 0, 0);
    }

    // online softmax; row q = g*4+r lives in the 16 lanes of group g
    float fac[4];
#pragma unroll
    for (int r = 0; r < 4; ++r) {
      float mx = fmaxf(fmaxf(sc[0][r], sc[1][r]), fmaxf(sc[2][r], sc[3][r]));
#pragma unroll
      for (int msk = 1; msk < 16; msk <<= 1) mx = fmaxf(mx, __shfl_xor(mx, msk));
      float nm = fmaxf(mrow[r], mx);
      fac[r] = __expf(mrow[r] - nm);
      mrow[r] = nm;
#pragma unroll
      for (int kt = 0; kt < 4; ++kt) {
        float p = __expf(sc[kt][r] - nm);
        sP[wid][(g * 4 + r) * 72 + kt * 16 + r15] = f2b(p);
      }
#pragma unroll
      for (int dt = 0; dt < 4; ++dt) o[dt][r] *= fac[r];
    }

    // P fragments (A-operand: row q=r15, keys g*8..). In-wave DS ordering makes the
    // cross-lane write->read safe without a barrier (verified R1/R2).
    bf16x8 pf0 = *(const bf16x8_a*)&sP[wid][r15 * 72 + g * 8];
    bf16x8 pf1 = *(const bf16x8_a*)&sP[wid][r15 * 72 + 32 + g * 8];

    // row sums via MFMA with ones-B
    f32x4 lacc = {};
    lacc = __builtin_amdgcn_mfma_f32_16x16x32_bf16(pf0, onesb, lacc, 0, 0, 0);
    lacc = __builtin_amdgcn_mfma_f32_16x16x32_bf16(pf1, onesb, lacc, 0, 0, 0);
#pragma unroll
    for (int r = 0; r < 4; ++r) lrow[r] = lrow[r] * fac[r] + lacc[r];

    // PV: B-operand = V^T rows (d, keys) from swizzled sV
#pragma unroll
    for (int dt = 0; dt < 4; ++dt) {
      const int rb = (dt * 16 + r15) * 64;
      bf16x8 vf0 = *(const bf16x8_a*)&sV[cur][rb + s0];
      bf16x8 vf1 = *(const bf16x8_a*)&sV[cur][rb + s1];
      o[dt] = __builtin_amdgcn_mfma_f32_16x16x32_bf16(pf0, vf0, o[dt], 0, 0, 0);
      o[dt] = __builtin_amdgcn_mfma_f32_16x16x32_bf16(pf1, vf1, o[dt], 0, 0, 0);
    }
  }

  // epilogue: out[b][s][h*64+d]
  const int b = bh >> 4, hh = bh & 15;
#pragma unroll
  for (int r = 0; r < 4; ++r) {
    float inv = 1.f / lrow[r];
    int s = q0 + wid * 16 + g * 4 + r;
    size_t rowoff = ((size_t)(b * 2048 + s)) * 1024 + hh * 64;
#pragma unroll
    for (int dt = 0; dt < 4; ++dt) out[rowoff + dt * 16 + r15] = f2b(o[dt][r] * inv);
  }
}

// ---------- LayerNorm over 1024 cols; optional f32 and bf16 outputs ----------
__global__ __launch_bounds__(256) void ln_kernel(const float* __restrict__ in,
                                                 const float* __restrict__ gamma,
                                                 const float* __restrict__ beta,
                                                 float* __restrict__ outf,
                                                 unsigned short* __restrict__ outb) {
  const int row = blockIdx.x, tid = threadIdx.x;
  float4 v = ((const float4*)(in + (size_t)row * 1024))[tid];
  float s = v.x + v.y + v.z + v.w;
  float ss = v.x * v.x + v.y * v.y + v.z * v.z + v.w * v.w;
#pragma unroll
  for (int off = 32; off > 0; off >>= 1) {
    s += __shfl_down(s, off);
    ss += __shfl_down(ss, off);
  }
  __shared__ float red[8];
  const int wid = tid >> 6;
  if ((tid & 63) == 0) { red[wid] = s; red[4 + wid] = ss; }
  __syncthreads();
  float S = red[0] + red[1] + red[2] + red[3];
  float SS = red[4] + red[5] + red[6] + red[7];
  const float mean = S * (1.f / 1024.f);
  const float var = SS * (1.f / 1024.f) - mean * mean;
  const float inv = 1.f / sqrtf(var + 1e-10f);
  float4 gg = ((const float4*)gamma)[tid];
  float4 bb = ((const float4*)beta)[tid];
  float4 o;
  o.x = (v.x - mean) * inv * gg.x + bb.x;
  o.y = (v.y - mean) * inv * gg.y + bb.y;
  o.z = (v.z - mean) * inv * gg.z + bb.z;
  o.w = (v.w - mean) * inv * gg.w + bb.w;
  if (outf) ((float4*)(outf + (size_t)row * 1024))[tid] = o;
  if (outb) {
    u16x4_a t = {f2b(o.x), f2b(o.y), f2b(o.z), f2b(o.w)};
    *(u16x4_a*)(outb + (size_t)row * 1024 + tid * 4) = t;
  }
}

// ---------- launch ----------
extern "C" void kernel_launch(void* const* d_in, const int* in_sizes, int n_in,
                              void* d_out, int out_size, void* d_ws, size_t ws_size,
                              hipStream_t stream) {
  const float* x      = (const float*)d_in[0];
  const float* wq     = (const float*)d_in[1];
  const float* bq     = (const float*)d_in[2];
  const float* wk     = (const float*)d_in[3];
  const float* bk     = (const float*)d_in[4];
  const float* wv     = (const float*)d_in[5];
  const float* bv     = (const float*)d_in[6];
  const float* w_proj = (const float*)d_in[7];
  const float* b_proj = (const float*)d_in[8];
  const float* gamma1 = (const float*)d_in[9];
  const float* beta1  = (const float*)d_in[10];
  const float* w1     = (const float*)d_in[11];
  const float* b1     = (const float*)d_in[12];
  const float* w2     = (const float*)d_in[13];
  const float* b2     = (const float*)d_in[14];
  const float* gamma2 = (const float*)d_in[15];
  const float* beta2  = (const float*)d_in[16];

  char* p = (char*)d_ws;
  auto alloc = [&](size_t bytes) {
    char* r = p;
    p += (bytes + 255) & ~(size_t)255;
    return r;
  };
  unsigned short* xb      = (unsigned short*)alloc(4096ull * 1024 * 2);  // reused as concat
  unsigned short* Wqkv_t  = (unsigned short*)alloc(3072ull * 1024 * 2);
  unsigned short* Wproj_t = (unsigned short*)alloc(1024ull * 1024 * 2);
  unsigned short* W1t     = (unsigned short*)alloc(4096ull * 1024 * 2);
  unsigned short* W2t     = (unsigned short*)alloc(1024ull * 4096 * 2);
  float*          biasq   = (float*)alloc(3072 * 4);
  unsigned short* Qb      = (unsigned short*)alloc(4096ull * 1024 * 2);
  unsigned short* Kb      = (unsigned short*)alloc(4096ull * 1024 * 2);
  unsigned short* Vtb     = (unsigned short*)alloc(4096ull * 1024 * 2);  // [BH][64][2048]
  float*          resid1  = (float*)alloc(4096ull * 1024 * 4);  // reused as resid2
  float*          out1f   = (float*)alloc(4096ull * 1024 * 4);
  unsigned short* out1b   = (unsigned short*)alloc(4096ull * 1024 * 2);
  unsigned short* ffn_h   = (unsigned short*)alloc(4096ull * 4096 * 2);
  unsigned short* concat  = xb;
  float*          resid2  = resid1;

  cvt_kernel<<<4096, 256, 0, stream>>>(x, xb, 4096 * 1024 / 4);
  transpose_cvt<<<dim3(2, 32, 16), 256, 0, stream>>>(wq, Wqkv_t, 1024, 64, 0.125f);
  transpose_cvt<<<dim3(2, 32, 16), 256, 0, stream>>>(wk, Wqkv_t + 1024 * 1024, 1024, 64, 1.f);
  transpose_cvt<<<dim3(2, 32, 16), 256, 0, stream>>>(wv, Wqkv_t + 2048 * 1024, 1024, 64, 1.f);
  transpose_cvt<<<dim3(32, 32, 1), 256, 0, stream>>>(w_proj, Wproj_t, 1024, 1024, 1.f);
  transpose_cvt<<<dim3(128, 32, 1), 256, 0, stream>>>(w1, W1t, 1024, 4096, 1.f);
  transpose_cvt<<<dim3(32, 128, 1), 256, 0, stream>>>(w2, W2t, 4096, 1024, 1.f);
  build_bias_qkv<<<12, 256, 0, stream>>>(bq, bk, bv, biasq);

  gemm_bt_kernel<0><<<dim3(24, 32), 256, 0, stream>>>(xb, Wqkv_t, 4096, 3072, 1024, biasq,
                                                      nullptr, nullptr, nullptr, Qb, Kb, Vtb);
  attn_kernel<<<dim3(32, 32), 256, 0, stream>>>(Qb, Kb, Vtb, concat);
  gemm_bt_kernel<1><<<dim3(8, 32), 256, 0, stream>>>(concat, Wproj_t, 4096, 1024, 1024, b_proj,
                                                     x, resid1, nullptr, nullptr, nullptr, nullptr);
  ln_kernel<<<4096, 256, 0, stream>>>(resid1, gamma1, beta1, out1f, out1b);
  gemm_bt_kernel<2><<<dim3(32, 32), 256, 0, stream>>>(out1b, W1t, 4096, 4096, 1024, b1, nullptr,
                                                      nullptr, ffn_h, nullptr, nullptr, nullptr);
  gemm_bt_kernel<1><<<dim3(8, 32), 256, 0, stream>>>(ffn_h, W2t, 4096, 1024, 4096, b2, out1f,
                                                     resid2, nullptr, nullptr, nullptr, nullptr);
  ln_kernel<<<4096, 256, 0, stream>>>(resid2, gamma2, beta2, (float*)d_out, nullptr);
}

// Round 4
// 372.817 us; speedup vs baseline: 1.3921x; 1.0839x over previous
//
#include <hip/hip_runtime.h>
#include <stdint.h>

// ---------- types ----------
typedef float f32x4 __attribute__((ext_vector_type(4)));
typedef __bf16 bf16x8 __attribute__((ext_vector_type(8)));
typedef __bf16 bf16x8_a __attribute__((ext_vector_type(8), may_alias));
typedef unsigned int u32x4_a __attribute__((ext_vector_type(4), may_alias));
typedef unsigned short u16x4_a __attribute__((ext_vector_type(4), may_alias));

#define DEV __device__ __forceinline__
#define MFMA_B16(a, b, c) __builtin_amdgcn_mfma_f32_16x16x32_bf16((a), (b), (c), 0, 0, 0)

DEV unsigned short f2b(float f) {  // f32 -> bf16 RNE
  unsigned int u = __float_as_uint(f);
  u = u + 0x7FFFu + ((u >> 16) & 1u);
  return (unsigned short)(u >> 16);
}

// async global->LDS, 16B per lane; LDS dest is wave-uniform base + lane*16
#define GLOAD_LDS16(gsrc, ldst)                                                  \
  __builtin_amdgcn_global_load_lds(                                              \
      (__attribute__((address_space(1))) void*)(uintptr_t)(const void*)(gsrc),   \
      (__attribute__((address_space(3))) void*)(ldst), 16, 0, 0)

// ---------- conversion kernels ----------
__global__ __launch_bounds__(256) void cvt_kernel(const float* __restrict__ in,
                                                  unsigned short* __restrict__ out, int n4) {
  int i = blockIdx.x * 256 + threadIdx.x;
  if (i < n4) {
    float4 v = ((const float4*)in)[i];
    u16x4_a t = {f2b(v.x), f2b(v.y), f2b(v.z), f2b(v.w)};
    ((u16x4_a*)out)[i] = t;
  }
}

// in: [rows][cols] f32 (batched on z) -> out: [cols][rows] bf16 (*scale)
__global__ __launch_bounds__(256) void transpose_cvt(const float* __restrict__ in,
                                                     unsigned short* __restrict__ out,
                                                     int rows, int cols, float scale) {
  __shared__ float tile[32][33];
  const int tx = threadIdx.x & 31, ty = threadIdx.x >> 5;
  const int c0 = blockIdx.x * 32, r0 = blockIdx.y * 32;
  const float* ip = in + (size_t)blockIdx.z * rows * cols;
  unsigned short* op = out + (size_t)blockIdx.z * rows * cols;
#pragma unroll
  for (int j = 0; j < 32; j += 8)
    tile[ty + j][tx] = ip[(size_t)(r0 + ty + j) * cols + (c0 + tx)];
  __syncthreads();
#pragma unroll
  for (int j = 0; j < 32; j += 8)
    op[(size_t)(c0 + ty + j) * rows + (r0 + tx)] = f2b(tile[tx][ty + j] * scale);
}

__global__ void build_bias_qkv(const float* __restrict__ bq, const float* __restrict__ bk,
                               const float* __restrict__ bv, float* __restrict__ out) {
  int c = blockIdx.x * 256 + threadIdx.x;  // 0..3071
  int which = c >> 10, idx = c & 1023;
  float v = which == 0 ? bq[idx] : (which == 1 ? bk[idx] : bv[idx]);
  out[c] = which == 0 ? v * 0.125f : v;  // fold 1/sqrt(HD) into q
}

// ---------- 256x256 8-phase GEMM (m201 template, plain HIP) ----------
// C[M][N] = A[M][K] * Bt[N][K]^T, bf16 in, f32 acc. 512 thr = 8 waves (2M x 4N),
// per-wave 128x64. BK=64, K-tile dbuf, slot-XOR LDS swizzle, counted-vmcnt at
// tile end only, raw barriers, setprio around MFMA clusters.
// EP 0: QKV scatter (q,k row-major [BH,S,64]; v transposed [BH,64,S]) + bias.
// EP 2: bf16 out = relu(acc + bias).
template <int EP>
__global__ __launch_bounds__(512, 2) void gemm256_kernel(
    const unsigned short* __restrict__ A, const unsigned short* __restrict__ Bt,
    int M, int N, int K, int nbx,
    const float* __restrict__ bias, unsigned short* __restrict__ outb,
    unsigned short* __restrict__ q_out, unsigned short* __restrict__ k_out,
    unsigned short* __restrict__ v_out) {
  __shared__ __align__(16) unsigned short sA[2][256 * 64];
  __shared__ __align__(16) unsigned short sB[2][256 * 64];

  const int tid = threadIdx.x;
  const int wid = tid >> 6, lane = tid & 63;
  const int g = lane >> 4, r15 = lane & 15;
  const int wm = wid >> 2, wn = wid & 3;

  // bijective XCD swizzle (nwg % 8 == 0 for our launches)
  const int nwg = gridDim.x, cpx = nwg >> 3, orig = blockIdx.x;
  const int wg = (orig & 7) * cpx + (orig >> 3);
  const int bx = wg % nbx, by = wg / nbx;
  const int row0 = by * 256, col0 = bx * 256;

  const unsigned short* gA0 = A + (size_t)row0 * K;
  const unsigned short* gB0 = Bt + (size_t)col0 * K;
  const int srow8 = lane >> 3;                  // row within 8-row staging group
  const int schunk = ((lane & 7) ^ srow8) * 8;  // inverse-swizzled global chunk

  f32x4 acc[8][4] = {};
  bf16x8 af[4][2], bfr[4][2];

  // stage instruction i (0..3): 8 rows [wid*32+i*8, +8) of the 256-row tile
  auto stA = [&](int buf, int k0, int i) {
    const int r = wid * 32 + i * 8;
    GLOAD_LDS16(gA0 + (size_t)(r + srow8) * K + k0 + schunk, &sA[buf][r * 64]);
  };
  auto stB = [&](int buf, int k0, int i) {
    const int r = wid * 32 + i * 8;
    GLOAD_LDS16(gB0 + (size_t)(r + srow8) * K + k0 + schunk, &sB[buf][r * 64]);
  };
  // fragment reads: row's 16B slot s stored at s ^ (row&7)
  auto ldA = [&](const unsigned short* p, int m, int ks) -> bf16x8 {
    const int row = wm * 128 + m * 16 + r15;
    return *(const bf16x8_a*)&p[row * 64 + (((ks * 4 + g) ^ (r15 & 7)) * 8)];
  };
  auto ldB = [&](const unsigned short* p, int n, int ks) -> bf16x8 {
    const int row = wn * 64 + n * 16 + r15;
    return *(const bf16x8_a*)&p[row * 64 + (((ks * 4 + g) ^ (r15 & 7)) * 8)];
  };

  const int NT = K >> 6;
  // prologue: stage tile 0 into buf 0
#pragma unroll
  for (int i = 0; i < 4; ++i) { stA(0, 0, i); stB(0, 0, i); }
  asm volatile("s_waitcnt vmcnt(0)" ::: "memory");
  __builtin_amdgcn_s_barrier();

  for (int kt = 0; kt < NT; ++kt) {
    const int cb = kt & 1, nb = cb ^ 1;
    const bool pf = (kt + 1) < NT;
    const int k1 = (kt + 1) << 6;
    const unsigned short* pA = sA[cb];
    const unsigned short* pB = sB[cb];

    // ---- phase 0: read A-half0 + all B frags; stage A halves 0,1; MFMA q(0,0) ----
#pragma unroll
    for (int m = 0; m < 4; ++m) { af[m][0] = ldA(pA, m, 0); af[m][1] = ldA(pA, m, 1); }
#pragma unroll
    for (int n = 0; n < 4; ++n) { bfr[n][0] = ldB(pB, n, 0); bfr[n][1] = ldB(pB, n, 1); }
    if (pf) { stA(nb, k1, 0); stA(nb, k1, 1); }
    __builtin_amdgcn_s_barrier();
    asm volatile("s_waitcnt lgkmcnt(0)" ::: "memory");
    __builtin_amdgcn_sched_barrier(0);
    __builtin_amdgcn_s_setprio(1);
#pragma unroll
    for (int m = 0; m < 4; ++m)
#pragma unroll
      for (int n = 0; n < 2; ++n) {
        acc[m][n] = MFMA_B16(af[m][0], bfr[n][0], acc[m][n]);
        acc[m][n] = MFMA_B16(af[m][1], bfr[n][1], acc[m][n]);
      }
    __builtin_amdgcn_s_setprio(0);
    __builtin_amdgcn_s_barrier();

    // ---- phase 1: stage A halves 2,3; MFMA q(0,1) ----
    if (pf) { stA(nb, k1, 2); stA(nb, k1, 3); }
    __builtin_amdgcn_s_barrier();
    __builtin_amdgcn_s_setprio(1);
#pragma unroll
    for (int m = 0; m < 4; ++m)
#pragma unroll
      for (int n = 2; n < 4; ++n) {
        acc[m][n] = MFMA_B16(af[m][0], bfr[n][0], acc[m][n]);
        acc[m][n] = MFMA_B16(af[m][1], bfr[n][1], acc[m][n]);
      }
    __builtin_amdgcn_s_setprio(0);
    __builtin_amdgcn_s_barrier();

    // ---- phase 2: read A-half1; stage B halves 0,1; MFMA q(1,0) ----
#pragma unroll
    for (int m = 0; m < 4; ++m) { af[m][0] = ldA(pA, m + 4, 0); af[m][1] = ldA(pA, m + 4, 1); }
    if (pf) { stB(nb, k1, 0); stB(nb, k1, 1); }
    __builtin_amdgcn_s_barrier();
    asm volatile("s_waitcnt lgkmcnt(0)" ::: "memory");
    __builtin_amdgcn_sched_barrier(0);
    __builtin_amdgcn_s_setprio(1);
#pragma unroll
    for (int m = 0; m < 4; ++m)
#pragma unroll
      for (int n = 0; n < 2; ++n) {
        acc[m + 4][n] = MFMA_B16(af[m][0], bfr[n][0], acc[m + 4][n]);
        acc[m + 4][n] = MFMA_B16(af[m][1], bfr[n][1], acc[m + 4][n]);
      }
    __builtin_amdgcn_s_setprio(0);
    __builtin_amdgcn_s_barrier();

    // ---- phase 3: stage B halves 2,3; MFMA q(1,1); tile-end vmcnt drain ----
    if (pf) { stB(nb, k1, 2); stB(nb, k1, 3); }
    __builtin_amdgcn_s_barrier();
    __builtin_amdgcn_s_setprio(1);
#pragma unroll
    for (int m = 0; m < 4; ++m)
#pragma unroll
      for (int n = 2; n < 4; ++n) {
        acc[m + 4][n] = MFMA_B16(af[m][0], bfr[n][0], acc[m + 4][n]);
        acc[m + 4][n] = MFMA_B16(af[m][1], bfr[n][1], acc[m + 4][n]);
      }
    __builtin_amdgcn_s_setprio(0);
    asm volatile("s_waitcnt vmcnt(0)" ::: "memory");
    __builtin_amdgcn_s_barrier();
  }

  // epilogue: row = row0+wm*128+m*16+g*4+r ; col = col0+wn*64+n*16+r15
#pragma unroll
  for (int m = 0; m < 8; ++m) {
    const int rbase = row0 + wm * 128 + m * 16 + g * 4;
#pragma unroll
    for (int n = 0; n < 4; ++n) {
      const int col = col0 + wn * 64 + n * 16 + r15;
      const float bb = bias[col];
#pragma unroll
      for (int r = 0; r < 4; ++r) {
        const int row = rbase + r;
        float v = acc[m][n][r] + bb;
        if constexpr (EP == 0) {
          int which = col >> 10, cc = col & 1023;
          int h = cc >> 6, e = cc & 63;
          int b = row >> 11, s = row & 2047;
          if (which == 2) {
            v_out[(((size_t)(b * 16 + h) * 64) + e) * 2048 + s] = f2b(v);
          } else {
            unsigned short* dst = which == 0 ? q_out : k_out;
            dst[(((size_t)(b * 16 + h) * 2048) + s) * 64 + e] = f2b(v);
          }
        } else {
          outb[(size_t)row * N + col] = f2b(v > 0.f ? v : 0.f);
        }
      }
    }
  }
}

// ---------- 128x128 GEMM (m97 structure + depth-1 dbuf overlap) ----------
// EP 1: f32 out = acc + bias + addf (residual).
template <int EP>
__global__ __launch_bounds__(256) void gemm_bt_kernel(
    const unsigned short* __restrict__ A, const unsigned short* __restrict__ Bt,
    int M, int N, int K,
    const float* __restrict__ bias, const float* __restrict__ addf,
    float* __restrict__ outf) {
  __shared__ __align__(16) unsigned short sA[2][128 * 32];
  __shared__ __align__(16) unsigned short sB[2][128 * 32];
  const int tid = threadIdx.x;
  const int wid = tid >> 6, lane = tid & 63;
  const int g = lane >> 4, r15 = lane & 15;
  const int wr = wid >> 1, wc = wid & 1;
  const int row0 = blockIdx.y * 128, col0 = blockIdx.x * 128;

  f32x4 acc[4][4] = {};

  const int c0 = wid * 128 + lane;
  const unsigned short* gA0 = A + (size_t)row0 * K;
  const unsigned short* gB0 = Bt + (size_t)col0 * K;

  auto stage = [&](int buf, int k0) {
#pragma unroll
    for (int j = 0; j < 2; ++j) {
      int c = c0 + j * 64;
      GLOAD_LDS16(gA0 + (size_t)(c >> 2) * K + k0 + (c & 3) * 8,
                  &sA[buf][(wid * 128 + j * 64) * 8]);
      GLOAD_LDS16(gB0 + (size_t)(c >> 2) * K + k0 + (c & 3) * 8,
                  &sB[buf][(wid * 128 + j * 64) * 8]);
    }
  };

  stage(0, 0);
  const int NT = K >> 5;
  for (int t = 0; t < NT; ++t) {
    const int cb = t & 1;
    __syncthreads();  // drains vmcnt: buf cb ready; all reads of cb^1 done
    if (t + 1 < NT) stage(cb ^ 1, (t + 1) * 32);  // in flight across this tile's MFMAs
    bf16x8 af[4], bfr[4];
#pragma unroll
    for (int m = 0; m < 4; ++m)
      af[m] = *(const bf16x8_a*)&sA[cb][(wr * 64 + m * 16 + r15) * 32 + g * 8];
#pragma unroll
    for (int n = 0; n < 4; ++n)
      bfr[n] = *(const bf16x8_a*)&sB[cb][(wc * 64 + n * 16 + r15) * 32 + g * 8];
#pragma unroll
    for (int m = 0; m < 4; ++m)
#pragma unroll
      for (int n = 0; n < 4; ++n)
        acc[m][n] = MFMA_B16(af[m], bfr[n], acc[m][n]);
  }

#pragma unroll
  for (int m = 0; m < 4; ++m) {
    const int rbase = row0 + wr * 64 + m * 16 + g * 4;
#pragma unroll
    for (int n = 0; n < 4; ++n) {
      const int col = col0 + wc * 64 + n * 16 + r15;
      const float bb = bias[col];
#pragma unroll
      for (int r = 0; r < 4; ++r) {
        const int row = rbase + r;
        size_t idx = (size_t)row * N + col;
        outf[idx] = acc[m][n][r] + bb + addf[idx];
      }
    }
  }
}

// ---------- flash attention (R3 structure, unchanged) ----------
__global__ __launch_bounds__(256) void attn_kernel(const unsigned short* __restrict__ Q,
                                                   const unsigned short* __restrict__ K,
                                                   const unsigned short* __restrict__ Vt,
                                                   unsigned short* __restrict__ out) {
  const int flat = blockIdx.y * gridDim.x + blockIdx.x;  // 0..1023
  const int xcd = flat & 7, rest = flat >> 3;
  const int bh = xcd * 4 + (rest >> 5);
  const int q0 = (rest & 31) * 64;

  const int tid = threadIdx.x, wid = tid >> 6, lane = tid & 63;
  const int g = lane >> 4, r15 = lane & 15;
  const int h = r15 & 7;
  const int s0 = ((g ^ h) * 8);
  const int s1 = (((g + 4) ^ h) * 8);

  __shared__ __align__(16) unsigned short sK[2][64 * 64];
  __shared__ __align__(16) unsigned short sV[2][64 * 64];
  __shared__ __align__(16) unsigned short sP[4][16 * 72];

  const size_t base = (size_t)bh * (2048 * 64);
  const unsigned short* Kb = K + base;
  const unsigned short* Vb = Vt + base;

  const int qrow = q0 + wid * 16 + r15;
  bf16x8 qf[2];
  qf[0] = *(const bf16x8_a*)(Q + base + (size_t)qrow * 64 + g * 8);
  qf[1] = *(const bf16x8_a*)(Q + base + (size_t)qrow * 64 + 32 + g * 8);

  const int srow = lane >> 3;
  const int schunk = ((lane & 7) ^ srow) * 8;

  union {
    unsigned short u[8];
    bf16x8 v;
  } ou;
#pragma unroll
  for (int i = 0; i < 8; ++i) ou.u[i] = 0x3F80;
  const bf16x8 onesb = ou.v;

  f32x4 o[4] = {};
  float mrow[4], lrow[4];
#pragma unroll
  for (int r = 0; r < 4; ++r) { mrow[r] = -1e30f; lrow[r] = 0.f; }

  auto stage = [&](int bufi, int kt0s) {
#pragma unroll
    for (int i = 0; i < 2; ++i) {
      const int inst = wid * 2 + i;
      const int row = 8 * inst + srow;
      GLOAD_LDS16(Kb + (size_t)(kt0s + row) * 64 + schunk, &sK[bufi][inst * 512]);
      GLOAD_LDS16(Vb + (size_t)row * 2048 + kt0s + schunk, &sV[bufi][inst * 512]);
    }
  };

  stage(0, 0);

  for (int t = 0; t < 32; ++t) {
    const int cur = t & 1;
    __syncthreads();
    if (t < 31) stage(cur ^ 1, (t + 1) * 64);

    f32x4 sc[4] = {};
#pragma unroll
    for (int kt = 0; kt < 4; ++kt) {
      const int rb = (kt * 16 + r15) * 64;
      bf16x8 kf0 = *(const bf16x8_a*)&sK[cur][rb + s0];
      bf16x8 kf1 = *(const bf16x8_a*)&sK[cur][rb + s1];
      sc[kt] = MFMA_B16(qf[0], kf0, sc[kt]);
      sc[kt] = MFMA_B16(qf[1], kf1, sc[kt]);
    }

    float fac[4];
#pragma unroll
    for (int r = 0; r < 4; ++r) {
      float mx = fmaxf(fmaxf(sc[0][r], sc[1][r]), fmaxf(sc[2][r], sc[3][r]));
#pragma unroll
      for (int msk = 1; msk < 16; msk <<= 1) mx = fmaxf(mx, __shfl_xor(mx, msk));
      float nm = fmaxf(mrow[r], mx);
      fac[r] = __expf(mrow[r] - nm);
      mrow[r] = nm;
#pragma unroll
      for (int kt = 0; kt < 4; ++kt) {
        float p = __expf(sc[kt][r] - nm);
        sP[wid][(g * 4 + r) * 72 + kt * 16 + r15] = f2b(p);
      }
#pragma unroll
      for (int dt = 0; dt < 4; ++dt) o[dt][r] *= fac[r];
    }

    bf16x8 pf0 = *(const bf16x8_a*)&sP[wid][r15 * 72 + g * 8];
    bf16x8 pf1 = *(const bf16x8_a*)&sP[wid][r15 * 72 + 32 + g * 8];

    f32x4 lacc = {};
    lacc = MFMA_B16(pf0, onesb, lacc);
    lacc = MFMA_B16(pf1, onesb, lacc);
#pragma unroll
    for (int r = 0; r < 4; ++r) lrow[r] = lrow[r] * fac[r] + lacc[r];

#pragma unroll
    for (int dt = 0; dt < 4; ++dt) {
      const int rb = (dt * 16 + r15) * 64;
      bf16x8 vf0 = *(const bf16x8_a*)&sV[cur][rb + s0];
      bf16x8 vf1 = *(const bf16x8_a*)&sV[cur][rb + s1];
      o[dt] = MFMA_B16(pf0, vf0, o[dt]);
      o[dt] = MFMA_B16(pf1, vf1, o[dt]);
    }
  }

  const int b = bh >> 4, hh = bh & 15;
#pragma unroll
  for (int r = 0; r < 4; ++r) {
    float inv = 1.f / lrow[r];
    int s = q0 + wid * 16 + g * 4 + r;
    size_t rowoff = ((size_t)(b * 2048 + s)) * 1024 + hh * 64;
#pragma unroll
    for (int dt = 0; dt < 4; ++dt) out[rowoff + dt * 16 + r15] = f2b(o[dt][r] * inv);
  }
}

// ---------- LayerNorm over 1024 cols; optional f32 and bf16 outputs ----------
__global__ __launch_bounds__(256) void ln_kernel(const float* __restrict__ in,
                                                 const float* __restrict__ gamma,
                                                 const float* __restrict__ beta,
                                                 float* __restrict__ outf,
                                                 unsigned short* __restrict__ outb) {
  const int row = blockIdx.x, tid = threadIdx.x;
  float4 v = ((const float4*)(in + (size_t)row * 1024))[tid];
  float s = v.x + v.y + v.z + v.w;
  float ss = v.x * v.x + v.y * v.y + v.z * v.z + v.w * v.w;
#pragma unroll
  for (int off = 32; off > 0; off >>= 1) {
    s += __shfl_down(s, off);
    ss += __shfl_down(ss, off);
  }
  __shared__ float red[8];
  const int wid = tid >> 6;
  if ((tid & 63) == 0) { red[wid] = s; red[4 + wid] = ss; }
  __syncthreads();
  float S = red[0] + red[1] + red[2] + red[3];
  float SS = red[4] + red[5] + red[6] + red[7];
  const float mean = S * (1.f / 1024.f);
  const float var = SS * (1.f / 1024.f) - mean * mean;
  const float inv = 1.f / sqrtf(var + 1e-10f);
  float4 gg = ((const float4*)gamma)[tid];
  float4 bb = ((const float4*)beta)[tid];
  float4 o;
  o.x = (v.x - mean) * inv * gg.x + bb.x;
  o.y = (v.y - mean) * inv * gg.y + bb.y;
  o.z = (v.z - mean) * inv * gg.z + bb.z;
  o.w = (v.w - mean) * inv * gg.w + bb.w;
  if (outf) ((float4*)(outf + (size_t)row * 1024))[tid] = o;
  if (outb) {
    u16x4_a t = {f2b(o.x), f2b(o.y), f2b(o.z), f2b(o.w)};
    *(u16x4_a*)(outb + (size_t)row * 1024 + tid * 4) = t;
  }
}

// ---------- launch ----------
extern "C" void kernel_launch(void* const* d_in, const int* in_sizes, int n_in,
                              void* d_out, int out_size, void* d_ws, size_t ws_size,
                              hipStream_t stream) {
  const float* x      = (const float*)d_in[0];
  const float* wq     = (const float*)d_in[1];
  const float* bq     = (const float*)d_in[2];
  const float* wk     = (const float*)d_in[3];
  const float* bk     = (const float*)d_in[4];
  const float* wv     = (const float*)d_in[5];
  const float* bv     = (const float*)d_in[6];
  const float* w_proj = (const float*)d_in[7];
  const float* b_proj = (const float*)d_in[8];
  const float* gamma1 = (const float*)d_in[9];
  const float* beta1  = (const float*)d_in[10];
  const float* w1     = (const float*)d_in[11];
  const float* b1     = (const float*)d_in[12];
  const float* w2     = (const float*)d_in[13];
  const float* b2     = (const float*)d_in[14];
  const float* gamma2 = (const float*)d_in[15];
  const float* beta2  = (const float*)d_in[16];

  char* p = (char*)d_ws;
  auto alloc = [&](size_t bytes) {
    char* r = p;
    p += (bytes + 255) & ~(size_t)255;
    return r;
  };
  unsigned short* xb      = (unsigned short*)alloc(4096ull * 1024 * 2);  // reused as concat
  unsigned short* Wqkv_t  = (unsigned short*)alloc(3072ull * 1024 * 2);
  unsigned short* Wproj_t = (unsigned short*)alloc(1024ull * 1024 * 2);
  unsigned short* W1t     = (unsigned short*)alloc(4096ull * 1024 * 2);
  unsigned short* W2t     = (unsigned short*)alloc(1024ull * 4096 * 2);
  float*          biasq   = (float*)alloc(3072 * 4);
  unsigned short* Qb      = (unsigned short*)alloc(4096ull * 1024 * 2);
  unsigned short* Kb      = (unsigned short*)alloc(4096ull * 1024 * 2);
  unsigned short* Vtb     = (unsigned short*)alloc(4096ull * 1024 * 2);  // [BH][64][2048]
  float*          resid1  = (float*)alloc(4096ull * 1024 * 4);  // reused as resid2
  float*          out1f   = (float*)alloc(4096ull * 1024 * 4);
  unsigned short* out1b   = (unsigned short*)alloc(4096ull * 1024 * 2);
  unsigned short* ffn_h   = (unsigned short*)alloc(4096ull * 4096 * 2);
  unsigned short* concat  = xb;
  float*          resid2  = resid1;

  cvt_kernel<<<4096, 256, 0, stream>>>(x, xb, 4096 * 1024 / 4);
  transpose_cvt<<<dim3(2, 32, 16), 256, 0, stream>>>(wq, Wqkv_t, 1024, 64, 0.125f);
  transpose_cvt<<<dim3(2, 32, 16), 256, 0, stream>>>(wk, Wqkv_t + 1024 * 1024, 1024, 64, 1.f);
  transpose_cvt<<<dim3(2, 32, 16), 256, 0, stream>>>(wv, Wqkv_t + 2048 * 1024, 1024, 64, 1.f);
  transpose_cvt<<<dim3(32, 32, 1), 256, 0, stream>>>(w_proj, Wproj_t, 1024, 1024, 1.f);
  transpose_cvt<<<dim3(128, 32, 1), 256, 0, stream>>>(w1, W1t, 1024, 4096, 1.f);
  transpose_cvt<<<dim3(32, 128, 1), 256, 0, stream>>>(w2, W2t, 4096, 1024, 1.f);
  build_bias_qkv<<<12, 256, 0, stream>>>(bq, bk, bv, biasq);

  // QKV: 256^2 8-phase, M=4096 N=3072 -> 16x12 = 192 blocks
  gemm256_kernel<0><<<192, 512, 0, stream>>>(xb, Wqkv_t, 4096, 3072, 1024, 12, biasq,
                                             nullptr, Qb, Kb, Vtb);
  attn_kernel<<<dim3(32, 32), 256, 0, stream>>>(Qb, Kb, Vtb, concat);
  gemm_bt_kernel<1><<<dim3(8, 32), 256, 0, stream>>>(concat, Wproj_t, 4096, 1024, 1024, b_proj,
                                                     x, resid1);
  ln_kernel<<<4096, 256, 0, stream>>>(resid1, gamma1, beta1, out1f, out1b);
  // FFN1: 256^2 8-phase, M=4096 N=4096 -> 16x16 = 256 blocks
  gemm256_kernel<2><<<256, 512, 0, stream>>>(out1b, W1t, 4096, 4096, 1024, 16, b1,
                                             ffn_h, nullptr, nullptr, nullptr);
  gemm_bt_kernel<1><<<dim3(8, 32), 256, 0, stream>>>(ffn_h, W2t, 4096, 1024, 4096, b2, out1f,
                                                     resid2);
  ln_kernel<<<4096, 256, 0, stream>>>(resid2, gamma2, beta2, (float*)d_out, nullptr);
}

// Round 5
// 343.077 us; speedup vs baseline: 1.5127x; 1.0867x over previous
//
#include <hip/hip_runtime.h>
#include <stdint.h>

// ---------- types ----------
typedef float f32x4 __attribute__((ext_vector_type(4)));
typedef __bf16 bf16x8 __attribute__((ext_vector_type(8)));
typedef __bf16 bf16x8_a __attribute__((ext_vector_type(8), may_alias));
typedef unsigned int u32x4_a __attribute__((ext_vector_type(4), may_alias));
typedef unsigned short u16x4_a __attribute__((ext_vector_type(4), may_alias));

#define DEV __device__ __forceinline__
#define MFMA_B16(a, b, c) __builtin_amdgcn_mfma_f32_16x16x32_bf16((a), (b), (c), 0, 0, 0)

DEV unsigned short f2b(float f) {  // f32 -> bf16 RNE
  unsigned int u = __float_as_uint(f);
  u = u + 0x7FFFu + ((u >> 16) & 1u);
  return (unsigned short)(u >> 16);
}

// async global->LDS, 16B per lane; LDS dest is wave-uniform base + lane*16
#define GLOAD_LDS16(gsrc, ldst)                                                  \
  __builtin_amdgcn_global_load_lds(                                              \
      (__attribute__((address_space(1))) void*)(uintptr_t)(const void*)(gsrc),   \
      (__attribute__((address_space(3))) void*)(ldst), 16, 0, 0)

// ---------- conversion kernels ----------
__global__ __launch_bounds__(256) void cvt_kernel(const float* __restrict__ in,
                                                  unsigned short* __restrict__ out, int n4) {
  int i = blockIdx.x * 256 + threadIdx.x;
  if (i < n4) {
    float4 v = ((const float4*)in)[i];
    u16x4_a t = {f2b(v.x), f2b(v.y), f2b(v.z), f2b(v.w)};
    ((u16x4_a*)out)[i] = t;
  }
}

// in: [rows][cols] f32 (batched on z) -> out: [cols][rows] bf16 (*scale)
__global__ __launch_bounds__(256) void transpose_cvt(const float* __restrict__ in,
                                                     unsigned short* __restrict__ out,
                                                     int rows, int cols, float scale) {
  __shared__ float tile[32][33];
  const int tx = threadIdx.x & 31, ty = threadIdx.x >> 5;
  const int c0 = blockIdx.x * 32, r0 = blockIdx.y * 32;
  const float* ip = in + (size_t)blockIdx.z * rows * cols;
  unsigned short* op = out + (size_t)blockIdx.z * rows * cols;
#pragma unroll
  for (int j = 0; j < 32; j += 8)
    tile[ty + j][tx] = ip[(size_t)(r0 + ty + j) * cols + (c0 + tx)];
  __syncthreads();
#pragma unroll
  for (int j = 0; j < 32; j += 8)
    op[(size_t)(c0 + ty + j) * rows + (r0 + tx)] = f2b(tile[tx][ty + j] * scale);
}

__global__ void build_bias_qkv(const float* __restrict__ bq, const float* __restrict__ bk,
                               const float* __restrict__ bv, float* __restrict__ out) {
  int c = blockIdx.x * 256 + threadIdx.x;  // 0..3071
  int which = c >> 10, idx = c & 1023;
  float v = which == 0 ? bq[idx] : (which == 1 ? bk[idx] : bv[idx]);
  out[c] = which == 0 ? v * 0.125f : v;  // fold 1/sqrt(HD) into q
}

// ---------- 256x256 8-phase GEMM (m201 template, plain HIP) ----------
template <int EP>
__global__ __launch_bounds__(512, 2) void gemm256_kernel(
    const unsigned short* __restrict__ A, const unsigned short* __restrict__ Bt,
    int M, int N, int K, int nbx,
    const float* __restrict__ bias, unsigned short* __restrict__ outb,
    unsigned short* __restrict__ q_out, unsigned short* __restrict__ k_out,
    unsigned short* __restrict__ v_out) {
  __shared__ __align__(16) unsigned short sA[2][256 * 64];
  __shared__ __align__(16) unsigned short sB[2][256 * 64];

  const int tid = threadIdx.x;
  const int wid = tid >> 6, lane = tid & 63;
  const int g = lane >> 4, r15 = lane & 15;
  const int wm = wid >> 2, wn = wid & 3;

  const int nwg = gridDim.x, cpx = nwg >> 3, orig = blockIdx.x;
  const int wg = (orig & 7) * cpx + (orig >> 3);
  const int bx = wg % nbx, by = wg / nbx;
  const int row0 = by * 256, col0 = bx * 256;

  const unsigned short* gA0 = A + (size_t)row0 * K;
  const unsigned short* gB0 = Bt + (size_t)col0 * K;
  const int srow8 = lane >> 3;
  const int schunk = ((lane & 7) ^ srow8) * 8;

  f32x4 acc[8][4] = {};
  bf16x8 af[4][2], bfr[4][2];

  auto stA = [&](int buf, int k0, int i) {
    const int r = wid * 32 + i * 8;
    GLOAD_LDS16(gA0 + (size_t)(r + srow8) * K + k0 + schunk, &sA[buf][r * 64]);
  };
  auto stB = [&](int buf, int k0, int i) {
    const int r = wid * 32 + i * 8;
    GLOAD_LDS16(gB0 + (size_t)(r + srow8) * K + k0 + schunk, &sB[buf][r * 64]);
  };
  auto ldA = [&](const unsigned short* p, int m, int ks) -> bf16x8 {
    const int row = wm * 128 + m * 16 + r15;
    return *(const bf16x8_a*)&p[row * 64 + (((ks * 4 + g) ^ (r15 & 7)) * 8)];
  };
  auto ldB = [&](const unsigned short* p, int n, int ks) -> bf16x8 {
    const int row = wn * 64 + n * 16 + r15;
    return *(const bf16x8_a*)&p[row * 64 + (((ks * 4 + g) ^ (r15 & 7)) * 8)];
  };

  const int NT = K >> 6;
#pragma unroll
  for (int i = 0; i < 4; ++i) { stA(0, 0, i); stB(0, 0, i); }
  asm volatile("s_waitcnt vmcnt(0)" ::: "memory");
  __builtin_amdgcn_s_barrier();

  for (int kt = 0; kt < NT; ++kt) {
    const int cb = kt & 1, nb = cb ^ 1;
    const bool pf = (kt + 1) < NT;
    const int k1 = (kt + 1) << 6;
    const unsigned short* pA = sA[cb];
    const unsigned short* pB = sB[cb];

#pragma unroll
    for (int m = 0; m < 4; ++m) { af[m][0] = ldA(pA, m, 0); af[m][1] = ldA(pA, m, 1); }
#pragma unroll
    for (int n = 0; n < 4; ++n) { bfr[n][0] = ldB(pB, n, 0); bfr[n][1] = ldB(pB, n, 1); }
    if (pf) { stA(nb, k1, 0); stA(nb, k1, 1); }
    __builtin_amdgcn_s_barrier();
    asm volatile("s_waitcnt lgkmcnt(0)" ::: "memory");
    __builtin_amdgcn_sched_barrier(0);
    __builtin_amdgcn_s_setprio(1);
#pragma unroll
    for (int m = 0; m < 4; ++m)
#pragma unroll
      for (int n = 0; n < 2; ++n) {
        acc[m][n] = MFMA_B16(af[m][0], bfr[n][0], acc[m][n]);
        acc[m][n] = MFMA_B16(af[m][1], bfr[n][1], acc[m][n]);
      }
    __builtin_amdgcn_s_setprio(0);
    __builtin_amdgcn_s_barrier();

    if (pf) { stA(nb, k1, 2); stA(nb, k1, 3); }
    __builtin_amdgcn_s_barrier();
    __builtin_amdgcn_s_setprio(1);
#pragma unroll
    for (int m = 0; m < 4; ++m)
#pragma unroll
      for (int n = 2; n < 4; ++n) {
        acc[m][n] = MFMA_B16(af[m][0], bfr[n][0], acc[m][n]);
        acc[m][n] = MFMA_B16(af[m][1], bfr[n][1], acc[m][n]);
      }
    __builtin_amdgcn_s_setprio(0);
    __builtin_amdgcn_s_barrier();

#pragma unroll
    for (int m = 0; m < 4; ++m) { af[m][0] = ldA(pA, m + 4, 0); af[m][1] = ldA(pA, m + 4, 1); }
    if (pf) { stB(nb, k1, 0); stB(nb, k1, 1); }
    __builtin_amdgcn_s_barrier();
    asm volatile("s_waitcnt lgkmcnt(0)" ::: "memory");
    __builtin_amdgcn_sched_barrier(0);
    __builtin_amdgcn_s_setprio(1);
#pragma unroll
    for (int m = 0; m < 4; ++m)
#pragma unroll
      for (int n = 0; n < 2; ++n) {
        acc[m + 4][n] = MFMA_B16(af[m][0], bfr[n][0], acc[m + 4][n]);
        acc[m + 4][n] = MFMA_B16(af[m][1], bfr[n][1], acc[m + 4][n]);
      }
    __builtin_amdgcn_s_setprio(0);
    __builtin_amdgcn_s_barrier();

    if (pf) { stB(nb, k1, 2); stB(nb, k1, 3); }
    __builtin_amdgcn_s_barrier();
    __builtin_amdgcn_s_setprio(1);
#pragma unroll
    for (int m = 0; m < 4; ++m)
#pragma unroll
      for (int n = 2; n < 4; ++n) {
        acc[m + 4][n] = MFMA_B16(af[m][0], bfr[n][0], acc[m + 4][n]);
        acc[m + 4][n] = MFMA_B16(af[m][1], bfr[n][1], acc[m + 4][n]);
      }
    __builtin_amdgcn_s_setprio(0);
    asm volatile("s_waitcnt vmcnt(0)" ::: "memory");
    __builtin_amdgcn_s_barrier();
  }

#pragma unroll
  for (int m = 0; m < 8; ++m) {
    const int rbase = row0 + wm * 128 + m * 16 + g * 4;
#pragma unroll
    for (int n = 0; n < 4; ++n) {
      const int col = col0 + wn * 64 + n * 16 + r15;
      const float bb = bias[col];
#pragma unroll
      for (int r = 0; r < 4; ++r) {
        const int row = rbase + r;
        float v = acc[m][n][r] + bb;
        if constexpr (EP == 0) {
          int which = col >> 10, cc = col & 1023;
          int h = cc >> 6, e = cc & 63;
          int b = row >> 11, s = row & 2047;
          if (which == 2) {
            v_out[(((size_t)(b * 16 + h) * 64) + e) * 2048 + s] = f2b(v);
          } else {
            unsigned short* dst = which == 0 ? q_out : k_out;
            dst[(((size_t)(b * 16 + h) * 2048) + s) * 64 + e] = f2b(v);
          }
        } else {
          outb[(size_t)row * N + col] = f2b(v > 0.f ? v : 0.f);
        }
      }
    }
  }
}

// ---------- 128x128 GEMM (m97 structure + depth-1 dbuf overlap) ----------
template <int EP>
__global__ __launch_bounds__(256) void gemm_bt_kernel(
    const unsigned short* __restrict__ A, const unsigned short* __restrict__ Bt,
    int M, int N, int K,
    const float* __restrict__ bias, const float* __restrict__ addf,
    float* __restrict__ outf) {
  __shared__ __align__(16) unsigned short sA[2][128 * 32];
  __shared__ __align__(16) unsigned short sB[2][128 * 32];
  const int tid = threadIdx.x;
  const int wid = tid >> 6, lane = tid & 63;
  const int g = lane >> 4, r15 = lane & 15;
  const int wr = wid >> 1, wc = wid & 1;
  const int row0 = blockIdx.y * 128, col0 = blockIdx.x * 128;

  f32x4 acc[4][4] = {};

  const int c0 = wid * 128 + lane;
  const unsigned short* gA0 = A + (size_t)row0 * K;
  const unsigned short* gB0 = Bt + (size_t)col0 * K;

  auto stage = [&](int buf, int k0) {
#pragma unroll
    for (int j = 0; j < 2; ++j) {
      int c = c0 + j * 64;
      GLOAD_LDS16(gA0 + (size_t)(c >> 2) * K + k0 + (c & 3) * 8,
                  &sA[buf][(wid * 128 + j * 64) * 8]);
      GLOAD_LDS16(gB0 + (size_t)(c >> 2) * K + k0 + (c & 3) * 8,
                  &sB[buf][(wid * 128 + j * 64) * 8]);
    }
  };

  stage(0, 0);
  const int NT = K >> 5;
  for (int t = 0; t < NT; ++t) {
    const int cb = t & 1;
    __syncthreads();
    if (t + 1 < NT) stage(cb ^ 1, (t + 1) * 32);
    bf16x8 af[4], bfr[4];
#pragma unroll
    for (int m = 0; m < 4; ++m)
      af[m] = *(const bf16x8_a*)&sA[cb][(wr * 64 + m * 16 + r15) * 32 + g * 8];
#pragma unroll
    for (int n = 0; n < 4; ++n)
      bfr[n] = *(const bf16x8_a*)&sB[cb][(wc * 64 + n * 16 + r15) * 32 + g * 8];
#pragma unroll
    for (int m = 0; m < 4; ++m)
#pragma unroll
      for (int n = 0; n < 4; ++n)
        acc[m][n] = MFMA_B16(af[m], bfr[n], acc[m][n]);
  }

#pragma unroll
  for (int m = 0; m < 4; ++m) {
    const int rbase = row0 + wr * 64 + m * 16 + g * 4;
#pragma unroll
    for (int n = 0; n < 4; ++n) {
      const int col = col0 + wc * 64 + n * 16 + r15;
      const float bb = bias[col];
#pragma unroll
      for (int r = 0; r < 4; ++r) {
        const int row = rbase + r;
        size_t idx = (size_t)row * N + col;
        outf[idx] = acc[m][n][r] + bb + addf[idx];
      }
    }
  }
}

// ---------- flash attention, SWAPPED-operand softmax ----------
// Q,K bf16 [BH,S,64], Vt bf16 [BH,64,S] -> concat bf16 [B*S,1024].
// mfma(K,Q) => scores lane-local per query (q=r15); softmax = 15 in-lane fmax
// + 2 shuffles; P-writes 4x ds_write_b64; PV = mfma(V,P) => O^T, d lane-local.
// T13 defer-max (THR=8) skips o-rescale when wave-uniformly safe.
__global__ __launch_bounds__(256) void attn_kernel(const unsigned short* __restrict__ Q,
                                                   const unsigned short* __restrict__ K,
                                                   const unsigned short* __restrict__ Vt,
                                                   unsigned short* __restrict__ out) {
  const int flat = blockIdx.y * gridDim.x + blockIdx.x;  // 0..1023
  const int xcd = flat & 7, rest = flat >> 3;
  const int bh = xcd * 4 + (rest >> 5);
  const int q0 = (rest & 31) * 64;

  const int tid = threadIdx.x, wid = tid >> 6, lane = tid & 63;
  const int g = lane >> 4, r15 = lane & 15;
  const int h = r15 & 7;
  const int s0 = ((g ^ h) * 8);
  const int s1 = (((g + 4) ^ h) * 8);

  __shared__ __align__(16) unsigned short sK[2][64 * 64];
  __shared__ __align__(16) unsigned short sV[2][64 * 64];
  __shared__ __align__(16) unsigned short sP[4][16 * 72];

  const size_t base = (size_t)bh * (2048 * 64);
  const unsigned short* Kb = K + base;
  const unsigned short* Vb = Vt + base;

  const int qrow = q0 + wid * 16 + r15;
  bf16x8 qf[2];
  qf[0] = *(const bf16x8_a*)(Q + base + (size_t)qrow * 64 + g * 8);
  qf[1] = *(const bf16x8_a*)(Q + base + (size_t)qrow * 64 + 32 + g * 8);

  const int srow = lane >> 3;
  const int schunk = ((lane & 7) ^ srow) * 8;

  union {
    unsigned short u[8];
    bf16x8 v;
  } ou;
#pragma unroll
  for (int i = 0; i < 8; ++i) ou.u[i] = 0x3F80;
  const bf16x8 onesb = ou.v;

  f32x4 o[4] = {};        // o[dt][reg]: d = dt*16 + g*4 + reg, for query q=r15
  float mrow = -1e30f, lrow = 0.f;

  auto stage = [&](int bufi, int kt0s) {
#pragma unroll
    for (int i = 0; i < 2; ++i) {
      const int inst = wid * 2 + i;
      const int row = 8 * inst + srow;
      GLOAD_LDS16(Kb + (size_t)(kt0s + row) * 64 + schunk, &sK[bufi][inst * 512]);
      GLOAD_LDS16(Vb + (size_t)row * 2048 + kt0s + schunk, &sV[bufi][inst * 512]);
    }
  };

  stage(0, 0);

  for (int t = 0; t < 32; ++t) {
    const int cur = t & 1;
    __syncthreads();
    if (t < 31) stage(cur ^ 1, (t + 1) * 64);

    // scores S^T: sc[kt][reg] = S[key=kt*16+g*4+reg][q=r15]
    f32x4 sc[4] = {};
#pragma unroll
    for (int kt = 0; kt < 4; ++kt) {
      const int rb = (kt * 16 + r15) * 64;
      bf16x8 kf0 = *(const bf16x8_a*)&sK[cur][rb + s0];
      bf16x8 kf1 = *(const bf16x8_a*)&sK[cur][rb + s1];
      sc[kt] = MFMA_B16(kf0, qf[0], sc[kt]);
      sc[kt] = MFMA_B16(kf1, qf[1], sc[kt]);
    }

    // softmax for this lane's query: in-lane max over 16 + 2 cross-g shuffles
    float pmax = sc[0][0];
#pragma unroll
    for (int kt = 0; kt < 4; ++kt)
#pragma unroll
      for (int r = 0; r < 4; ++r) pmax = fmaxf(pmax, sc[kt][r]);
    pmax = fmaxf(pmax, __shfl_xor(pmax, 16));
    pmax = fmaxf(pmax, __shfl_xor(pmax, 32));

    // defer-max: keep old max when growth <= 8 (wave-uniform skip of rescale)
    const bool allkeep = __all(pmax - mrow <= 8.0f);
    float fac;
    if (allkeep) {
      fac = 1.0f;
    } else {
      float nm = fmaxf(mrow, pmax);
      fac = __expf(mrow - nm);
      mrow = nm;
#pragma unroll
      for (int dt = 0; dt < 4; ++dt)
#pragma unroll
        for (int r = 0; r < 4; ++r) o[dt][r] *= fac;
    }

    // P = exp(S - m); write 4 contiguous keys per kt as one b64
#pragma unroll
    for (int kt = 0; kt < 4; ++kt) {
      u16x4_a pb = {f2b(__expf(sc[kt][0] - mrow)), f2b(__expf(sc[kt][1] - mrow)),
                    f2b(__expf(sc[kt][2] - mrow)), f2b(__expf(sc[kt][3] - mrow))};
      *(u16x4_a*)&sP[wid][r15 * 72 + kt * 16 + g * 4] = pb;
    }

    // P^T B-fragments (same addresses as before; in-wave DS ordering safe)
    bf16x8 pf0 = *(const bf16x8_a*)&sP[wid][r15 * 72 + g * 8];
    bf16x8 pf1 = *(const bf16x8_a*)&sP[wid][r15 * 72 + 32 + g * 8];

    // row sum via mfma(ones, P^T): every output row = colsum for query r15
    f32x4 lacc = {};
    lacc = MFMA_B16(onesb, pf0, lacc);
    lacc = MFMA_B16(onesb, pf1, lacc);
    lrow = lrow * fac + lacc[0];

    // PV: O^T[d][q] = mfma(V^T-rows as A, P^T as B)
#pragma unroll
    for (int dt = 0; dt < 4; ++dt) {
      const int rb = (dt * 16 + r15) * 64;
      bf16x8 vf0 = *(const bf16x8_a*)&sV[cur][rb + s0];
      bf16x8 vf1 = *(const bf16x8_a*)&sV[cur][rb + s1];
      o[dt] = MFMA_B16(vf0, pf0, o[dt]);
      o[dt] = MFMA_B16(vf1, pf1, o[dt]);
    }
  }

  // epilogue: lane owns query s = q0+wid*16+r15; d = dt*16+g*4+reg
  const int b = bh >> 4, hh = bh & 15;
  const int s = q0 + wid * 16 + r15;
  const float inv = 1.f / lrow;
  unsigned short* orow = out + ((size_t)(b * 2048 + s)) * 1024 + hh * 64;
#pragma unroll
  for (int dt = 0; dt < 4; ++dt) {
    u16x4_a t = {f2b(o[dt][0] * inv), f2b(o[dt][1] * inv), f2b(o[dt][2] * inv),
                 f2b(o[dt][3] * inv)};
    *(u16x4_a*)(orow + dt * 16 + g * 4) = t;
  }
}

// ---------- LayerNorm over 1024 cols; optional f32 and bf16 outputs ----------
__global__ __launch_bounds__(256) void ln_kernel(const float* __restrict__ in,
                                                 const float* __restrict__ gamma,
                                                 const float* __restrict__ beta,
                                                 float* __restrict__ outf,
                                                 unsigned short* __restrict__ outb) {
  const int row = blockIdx.x, tid = threadIdx.x;
  float4 v = ((const float4*)(in + (size_t)row * 1024))[tid];
  float s = v.x + v.y + v.z + v.w;
  float ss = v.x * v.x + v.y * v.y + v.z * v.z + v.w * v.w;
#pragma unroll
  for (int off = 32; off > 0; off >>= 1) {
    s += __shfl_down(s, off);
    ss += __shfl_down(ss, off);
  }
  __shared__ float red[8];
  const int wid = tid >> 6;
  if ((tid & 63) == 0) { red[wid] = s; red[4 + wid] = ss; }
  __syncthreads();
  float S = red[0] + red[1] + red[2] + red[3];
  float SS = red[4] + red[5] + red[6] + red[7];
  const float mean = S * (1.f / 1024.f);
  const float var = SS * (1.f / 1024.f) - mean * mean;
  const float inv = 1.f / sqrtf(var + 1e-10f);
  float4 gg = ((const float4*)gamma)[tid];
  float4 bb = ((const float4*)beta)[tid];
  float4 o;
  o.x = (v.x - mean) * inv * gg.x + bb.x;
  o.y = (v.y - mean) * inv * gg.y + bb.y;
  o.z = (v.z - mean) * inv * gg.z + bb.z;
  o.w = (v.w - mean) * inv * gg.w + bb.w;
  if (outf) ((float4*)(outf + (size_t)row * 1024))[tid] = o;
  if (outb) {
    u16x4_a t = {f2b(o.x), f2b(o.y), f2b(o.z), f2b(o.w)};
    *(u16x4_a*)(outb + (size_t)row * 1024 + tid * 4) = t;
  }
}

// ---------- launch ----------
extern "C" void kernel_launch(void* const* d_in, const int* in_sizes, int n_in,
                              void* d_out, int out_size, void* d_ws, size_t ws_size,
                              hipStream_t stream) {
  const float* x      = (const float*)d_in[0];
  const float* wq     = (const float*)d_in[1];
  const float* bq     = (const float*)d_in[2];
  const float* wk     = (const float*)d_in[3];
  const float* bk     = (const float*)d_in[4];
  const float* wv     = (const float*)d_in[5];
  const float* bv     = (const float*)d_in[6];
  const float* w_proj = (const float*)d_in[7];
  const float* b_proj = (const float*)d_in[8];
  const float* gamma1 = (const float*)d_in[9];
  const float* beta1  = (const float*)d_in[10];
  const float* w1     = (const float*)d_in[11];
  const float* b1     = (const float*)d_in[12];
  const float* w2     = (const float*)d_in[13];
  const float* b2     = (const float*)d_in[14];
  const float* gamma2 = (const float*)d_in[15];
  const float* beta2  = (const float*)d_in[16];

  char* p = (char*)d_ws;
  auto alloc = [&](size_t bytes) {
    char* r = p;
    p += (bytes + 255) & ~(size_t)255;
    return r;
  };
  unsigned short* xb      = (unsigned short*)alloc(4096ull * 1024 * 2);  // reused as concat
  unsigned short* Wqkv_t  = (unsigned short*)alloc(3072ull * 1024 * 2);
  unsigned short* Wproj_t = (unsigned short*)alloc(1024ull * 1024 * 2);
  unsigned short* W1t     = (unsigned short*)alloc(4096ull * 1024 * 2);
  unsigned short* W2t     = (unsigned short*)alloc(1024ull * 4096 * 2);
  float*          biasq   = (float*)alloc(3072 * 4);
  unsigned short* Qb      = (unsigned short*)alloc(4096ull * 1024 * 2);
  unsigned short* Kb      = (unsigned short*)alloc(4096ull * 1024 * 2);
  unsigned short* Vtb     = (unsigned short*)alloc(4096ull * 1024 * 2);  // [BH][64][2048]
  float*          resid1  = (float*)alloc(4096ull * 1024 * 4);  // reused as resid2
  float*          out1f   = (float*)alloc(4096ull * 1024 * 4);
  unsigned short* out1b   = (unsigned short*)alloc(4096ull * 1024 * 2);
  unsigned short* ffn_h   = (unsigned short*)alloc(4096ull * 4096 * 2);
  unsigned short* concat  = xb;
  float*          resid2  = resid1;

  cvt_kernel<<<4096, 256, 0, stream>>>(x, xb, 4096 * 1024 / 4);
  transpose_cvt<<<dim3(2, 32, 16), 256, 0, stream>>>(wq, Wqkv_t, 1024, 64, 0.125f);
  transpose_cvt<<<dim3(2, 32, 16), 256, 0, stream>>>(wk, Wqkv_t + 1024 * 1024, 1024, 64, 1.f);
  transpose_cvt<<<dim3(2, 32, 16), 256, 0, stream>>>(wv, Wqkv_t + 2048 * 1024, 1024, 64, 1.f);
  transpose_cvt<<<dim3(32, 32, 1), 256, 0, stream>>>(w_proj, Wproj_t, 1024, 1024, 1.f);
  transpose_cvt<<<dim3(128, 32, 1), 256, 0, stream>>>(w1, W1t, 1024, 4096, 1.f);
  transpose_cvt<<<dim3(32, 128, 1), 256, 0, stream>>>(w2, W2t, 4096, 1024, 1.f);
  build_bias_qkv<<<12, 256, 0, stream>>>(bq, bk, bv, biasq);

  gemm256_kernel<0><<<192, 512, 0, stream>>>(xb, Wqkv_t, 4096, 3072, 1024, 12, biasq,
                                             nullptr, Qb, Kb, Vtb);
  attn_kernel<<<dim3(32, 32), 256, 0, stream>>>(Qb, Kb, Vtb, concat);
  gemm_bt_kernel<1><<<dim3(8, 32), 256, 0, stream>>>(concat, Wproj_t, 4096, 1024, 1024, b_proj,
                                                     x, resid1);
  ln_kernel<<<4096, 256, 0, stream>>>(resid1, gamma1, beta1, out1f, out1b);
  gemm256_kernel<2><<<256, 512, 0, stream>>>(out1b, W1t, 4096, 4096, 1024, 16, b1,
                                             ffn_h, nullptr, nullptr, nullptr);
  gemm_bt_kernel<1><<<dim3(8, 32), 256, 0, stream>>>(ffn_h, W2t, 4096, 1024, 4096, b2, out1f,
                                                     resid2);
  ln_kernel<<<4096, 256, 0, stream>>>(resid2, gamma2, beta2, (float*)d_out, nullptr);
}

// Round 6
// 312.240 us; speedup vs baseline: 1.6621x; 1.0988x over previous
//
#include <hip/hip_runtime.h>
#include <stdint.h>

// ---------- types ----------
typedef float f32x4 __attribute__((ext_vector_type(4)));
typedef __bf16 bf16x8 __attribute__((ext_vector_type(8)));
typedef __bf16 bf16x8_a __attribute__((ext_vector_type(8), may_alias));
typedef unsigned int u32x4_a __attribute__((ext_vector_type(4), may_alias));
typedef unsigned short u16x4_a __attribute__((ext_vector_type(4), may_alias));

#define DEV __device__ __forceinline__
#define MFMA_B16(a, b, c) __builtin_amdgcn_mfma_f32_16x16x32_bf16((a), (b), (c), 0, 0, 0)

DEV unsigned short f2b(float f) {  // f32 -> bf16 RNE
  unsigned int u = __float_as_uint(f);
  u = u + 0x7FFFu + ((u >> 16) & 1u);
  return (unsigned short)(u >> 16);
}

// async global->LDS, 16B per lane; LDS dest is wave-uniform base + lane*16
#define GLOAD_LDS16(gsrc, ldst)                                                  \
  __builtin_amdgcn_global_load_lds(                                              \
      (__attribute__((address_space(1))) void*)(uintptr_t)(const void*)(gsrc),   \
      (__attribute__((address_space(3))) void*)(ldst), 16, 0, 0)

// ---------- conversion kernels ----------
__global__ __launch_bounds__(256) void cvt_kernel(const float* __restrict__ in,
                                                  unsigned short* __restrict__ out, int n4) {
  int i = blockIdx.x * 256 + threadIdx.x;
  if (i < n4) {
    float4 v = ((const float4*)in)[i];
    u16x4_a t = {f2b(v.x), f2b(v.y), f2b(v.z), f2b(v.w)};
    ((u16x4_a*)out)[i] = t;
  }
}

// in: [rows][cols] f32 (batched on z) -> out: [cols][rows] bf16 (*scale)
__global__ __launch_bounds__(256) void transpose_cvt(const float* __restrict__ in,
                                                     unsigned short* __restrict__ out,
                                                     int rows, int cols, float scale) {
  __shared__ float tile[32][33];
  const int tx = threadIdx.x & 31, ty = threadIdx.x >> 5;
  const int c0 = blockIdx.x * 32, r0 = blockIdx.y * 32;
  const float* ip = in + (size_t)blockIdx.z * rows * cols;
  unsigned short* op = out + (size_t)blockIdx.z * rows * cols;
#pragma unroll
  for (int j = 0; j < 32; j += 8)
    tile[ty + j][tx] = ip[(size_t)(r0 + ty + j) * cols + (c0 + tx)];
  __syncthreads();
#pragma unroll
  for (int j = 0; j < 32; j += 8)
    op[(size_t)(c0 + ty + j) * rows + (r0 + tx)] = f2b(tile[tx][ty + j] * scale);
}

__global__ void build_bias_qkv(const float* __restrict__ bq, const float* __restrict__ bk,
                               const float* __restrict__ bv, float* __restrict__ out) {
  int c = blockIdx.x * 256 + threadIdx.x;  // 0..3071
  int which = c >> 10, idx = c & 1023;
  float v = which == 0 ? bq[idx] : (which == 1 ? bk[idx] : bv[idx]);
  out[c] = which == 0 ? v * 0.125f : v;  // fold 1/sqrt(HD) into q
}

// ---------- 256x256 8-phase GEMM (m201 template, plain HIP) ----------
// EP 0: QKV scatter + bias. EP 2: bf16 relu(acc+bias). EP 3: f32 raw partial
// (split-K; partial buffer selected by kz, no bias).
// Block decode: wg = (by*KS + kz)*nbx + bx, XCD-swizzled (grid % 8 == 0).
template <int EP>
__global__ __launch_bounds__(512, 2) void gemm256_kernel(
    const unsigned short* __restrict__ A, const unsigned short* __restrict__ Bt,
    int M, int N, int K, int nbx, int KS,
    const float* __restrict__ bias, unsigned short* __restrict__ outb,
    unsigned short* __restrict__ q_out, unsigned short* __restrict__ k_out,
    unsigned short* __restrict__ v_out,
    float* __restrict__ pp0, float* __restrict__ pp1, float* __restrict__ pp2) {
  __shared__ __align__(16) unsigned short sA[2][256 * 64];
  __shared__ __align__(16) unsigned short sB[2][256 * 64];

  const int tid = threadIdx.x;
  const int wid = tid >> 6, lane = tid & 63;
  const int g = lane >> 4, r15 = lane & 15;
  const int wm = wid >> 2, wn = wid & 3;

  const int nwg = gridDim.x, cpx = nwg >> 3, orig = blockIdx.x;
  const int wg = (orig & 7) * cpx + (orig >> 3);
  const int bx = wg % nbx;
  const int t1 = wg / nbx;
  const int kz = t1 % KS, by = t1 / KS;
  const int row0 = by * 256, col0 = bx * 256;

  // split-K chunk in units of 64-wide K tiles
  const int tilesK = K >> 6;
  const int qT = tilesK / KS, rT = tilesK % KS;
  const int tile0 = kz * qT + (kz < rT ? kz : rT);
  const int NT = qT + (kz < rT ? 1 : 0);
  const int kbase = tile0 << 6;

  const unsigned short* gA0 = A + (size_t)row0 * K + kbase;
  const unsigned short* gB0 = Bt + (size_t)col0 * K + kbase;
  const int srow8 = lane >> 3;
  const int schunk = ((lane & 7) ^ srow8) * 8;

  f32x4 acc[8][4] = {};
  bf16x8 af[4][2], bfr[4][2];

  auto stA = [&](int buf, int k0, int i) {
    const int r = wid * 32 + i * 8;
    GLOAD_LDS16(gA0 + (size_t)(r + srow8) * K + k0 + schunk, &sA[buf][r * 64]);
  };
  auto stB = [&](int buf, int k0, int i) {
    const int r = wid * 32 + i * 8;
    GLOAD_LDS16(gB0 + (size_t)(r + srow8) * K + k0 + schunk, &sB[buf][r * 64]);
  };
  auto ldA = [&](const unsigned short* p, int m, int ks) -> bf16x8 {
    const int row = wm * 128 + m * 16 + r15;
    return *(const bf16x8_a*)&p[row * 64 + (((ks * 4 + g) ^ (r15 & 7)) * 8)];
  };
  auto ldB = [&](const unsigned short* p, int n, int ks) -> bf16x8 {
    const int row = wn * 64 + n * 16 + r15;
    return *(const bf16x8_a*)&p[row * 64 + (((ks * 4 + g) ^ (r15 & 7)) * 8)];
  };

#pragma unroll
  for (int i = 0; i < 4; ++i) { stA(0, 0, i); stB(0, 0, i); }
  asm volatile("s_waitcnt vmcnt(0)" ::: "memory");
  __builtin_amdgcn_s_barrier();

  for (int kt = 0; kt < NT; ++kt) {
    const int cb = kt & 1, nb = cb ^ 1;
    const bool pf = (kt + 1) < NT;
    const int k1 = (kt + 1) << 6;
    const unsigned short* pA = sA[cb];
    const unsigned short* pB = sB[cb];

#pragma unroll
    for (int m = 0; m < 4; ++m) { af[m][0] = ldA(pA, m, 0); af[m][1] = ldA(pA, m, 1); }
#pragma unroll
    for (int n = 0; n < 4; ++n) { bfr[n][0] = ldB(pB, n, 0); bfr[n][1] = ldB(pB, n, 1); }
    if (pf) { stA(nb, k1, 0); stA(nb, k1, 1); }
    __builtin_amdgcn_s_barrier();
    asm volatile("s_waitcnt lgkmcnt(0)" ::: "memory");
    __builtin_amdgcn_sched_barrier(0);
    __builtin_amdgcn_s_setprio(1);
#pragma unroll
    for (int m = 0; m < 4; ++m)
#pragma unroll
      for (int n = 0; n < 2; ++n) {
        acc[m][n] = MFMA_B16(af[m][0], bfr[n][0], acc[m][n]);
        acc[m][n] = MFMA_B16(af[m][1], bfr[n][1], acc[m][n]);
      }
    __builtin_amdgcn_s_setprio(0);
    __builtin_amdgcn_s_barrier();

    if (pf) { stA(nb, k1, 2); stA(nb, k1, 3); }
    __builtin_amdgcn_s_barrier();
    __builtin_amdgcn_s_setprio(1);
#pragma unroll
    for (int m = 0; m < 4; ++m)
#pragma unroll
      for (int n = 2; n < 4; ++n) {
        acc[m][n] = MFMA_B16(af[m][0], bfr[n][0], acc[m][n]);
        acc[m][n] = MFMA_B16(af[m][1], bfr[n][1], acc[m][n]);
      }
    __builtin_amdgcn_s_setprio(0);
    __builtin_amdgcn_s_barrier();

#pragma unroll
    for (int m = 0; m < 4; ++m) { af[m][0] = ldA(pA, m + 4, 0); af[m][1] = ldA(pA, m + 4, 1); }
    if (pf) { stB(nb, k1, 0); stB(nb, k1, 1); }
    __builtin_amdgcn_s_barrier();
    asm volatile("s_waitcnt lgkmcnt(0)" ::: "memory");
    __builtin_amdgcn_sched_barrier(0);
    __builtin_amdgcn_s_setprio(1);
#pragma unroll
    for (int m = 0; m < 4; ++m)
#pragma unroll
      for (int n = 0; n < 2; ++n) {
        acc[m + 4][n] = MFMA_B16(af[m][0], bfr[n][0], acc[m + 4][n]);
        acc[m + 4][n] = MFMA_B16(af[m][1], bfr[n][1], acc[m + 4][n]);
      }
    __builtin_amdgcn_s_setprio(0);
    __builtin_amdgcn_s_barrier();

    if (pf) { stB(nb, k1, 2); stB(nb, k1, 3); }
    __builtin_amdgcn_s_barrier();
    __builtin_amdgcn_s_setprio(1);
#pragma unroll
    for (int m = 0; m < 4; ++m)
#pragma unroll
      for (int n = 2; n < 4; ++n) {
        acc[m + 4][n] = MFMA_B16(af[m][0], bfr[n][0], acc[m + 4][n]);
        acc[m + 4][n] = MFMA_B16(af[m][1], bfr[n][1], acc[m + 4][n]);
      }
    __builtin_amdgcn_s_setprio(0);
    asm volatile("s_waitcnt vmcnt(0)" ::: "memory");
    __builtin_amdgcn_s_barrier();
  }

  float* pz = kz == 0 ? pp0 : (kz == 1 ? pp1 : pp2);
#pragma unroll
  for (int m = 0; m < 8; ++m) {
    const int rbase = row0 + wm * 128 + m * 16 + g * 4;
#pragma unroll
    for (int n = 0; n < 4; ++n) {
      const int col = col0 + wn * 64 + n * 16 + r15;
      const float bb = (EP == 3) ? 0.f : bias[col];
#pragma unroll
      for (int r = 0; r < 4; ++r) {
        const int row = rbase + r;
        float v = acc[m][n][r] + bb;
        if constexpr (EP == 0) {
          int which = col >> 10, cc = col & 1023;
          int h = cc >> 6, e = cc & 63;
          int b = row >> 11, s = row & 2047;
          if (which == 2) {
            v_out[(((size_t)(b * 16 + h) * 64) + e) * 2048 + s] = f2b(v);
          } else {
            unsigned short* dst = which == 0 ? q_out : k_out;
            dst[(((size_t)(b * 16 + h) * 2048) + s) * 64 + e] = f2b(v);
          }
        } else if constexpr (EP == 3) {
          pz[(size_t)row * N + col] = v;
        } else {
          outb[(size_t)row * N + col] = f2b(v > 0.f ? v : 0.f);
        }
      }
    }
  }
}

// ---------- 128x128 GEMM (m97 structure + depth-1 dbuf overlap) ----------
template <int EP>
__global__ __launch_bounds__(256) void gemm_bt_kernel(
    const unsigned short* __restrict__ A, const unsigned short* __restrict__ Bt,
    int M, int N, int K,
    const float* __restrict__ bias, const float* __restrict__ addf,
    float* __restrict__ outf) {
  __shared__ __align__(16) unsigned short sA[2][128 * 32];
  __shared__ __align__(16) unsigned short sB[2][128 * 32];
  const int tid = threadIdx.x;
  const int wid = tid >> 6, lane = tid & 63;
  const int g = lane >> 4, r15 = lane & 15;
  const int wr = wid >> 1, wc = wid & 1;
  const int row0 = blockIdx.y * 128, col0 = blockIdx.x * 128;

  f32x4 acc[4][4] = {};

  const int c0 = wid * 128 + lane;
  const unsigned short* gA0 = A + (size_t)row0 * K;
  const unsigned short* gB0 = Bt + (size_t)col0 * K;

  auto stage = [&](int buf, int k0) {
#pragma unroll
    for (int j = 0; j < 2; ++j) {
      int c = c0 + j * 64;
      GLOAD_LDS16(gA0 + (size_t)(c >> 2) * K + k0 + (c & 3) * 8,
                  &sA[buf][(wid * 128 + j * 64) * 8]);
      GLOAD_LDS16(gB0 + (size_t)(c >> 2) * K + k0 + (c & 3) * 8,
                  &sB[buf][(wid * 128 + j * 64) * 8]);
    }
  };

  stage(0, 0);
  const int NT = K >> 5;
  for (int t = 0; t < NT; ++t) {
    const int cb = t & 1;
    __syncthreads();
    if (t + 1 < NT) stage(cb ^ 1, (t + 1) * 32);
    bf16x8 af[4], bfr[4];
#pragma unroll
    for (int m = 0; m < 4; ++m)
      af[m] = *(const bf16x8_a*)&sA[cb][(wr * 64 + m * 16 + r15) * 32 + g * 8];
#pragma unroll
    for (int n = 0; n < 4; ++n)
      bfr[n] = *(const bf16x8_a*)&sB[cb][(wc * 64 + n * 16 + r15) * 32 + g * 8];
#pragma unroll
    for (int m = 0; m < 4; ++m)
#pragma unroll
      for (int n = 0; n < 4; ++n)
        acc[m][n] = MFMA_B16(af[m], bfr[n], acc[m][n]);
  }

#pragma unroll
  for (int m = 0; m < 4; ++m) {
    const int rbase = row0 + wr * 64 + m * 16 + g * 4;
#pragma unroll
    for (int n = 0; n < 4; ++n) {
      const int col = col0 + wc * 64 + n * 16 + r15;
      const float bb = bias[col];
#pragma unroll
      for (int r = 0; r < 4; ++r) {
        const int row = rbase + r;
        size_t idx = (size_t)row * N + col;
        outf[idx] = acc[m][n][r] + bb + addf[idx];
      }
    }
  }
}

// ---------- flash attention, SWAPPED-operand softmax (R5 structure) ----------
__global__ __launch_bounds__(256) void attn_kernel(const unsigned short* __restrict__ Q,
                                                   const unsigned short* __restrict__ K,
                                                   const unsigned short* __restrict__ Vt,
                                                   unsigned short* __restrict__ out) {
  const int flat = blockIdx.y * gridDim.x + blockIdx.x;  // 0..1023
  const int xcd = flat & 7, rest = flat >> 3;
  const int bh = xcd * 4 + (rest >> 5);
  const int q0 = (rest & 31) * 64;

  const int tid = threadIdx.x, wid = tid >> 6, lane = tid & 63;
  const int g = lane >> 4, r15 = lane & 15;
  const int h = r15 & 7;
  const int s0 = ((g ^ h) * 8);
  const int s1 = (((g + 4) ^ h) * 8);

  __shared__ __align__(16) unsigned short sK[2][64 * 64];
  __shared__ __align__(16) unsigned short sV[2][64 * 64];
  __shared__ __align__(16) unsigned short sP[4][16 * 72];

  const size_t base = (size_t)bh * (2048 * 64);
  const unsigned short* Kb = K + base;
  const unsigned short* Vb = Vt + base;

  const int qrow = q0 + wid * 16 + r15;
  bf16x8 qf[2];
  qf[0] = *(const bf16x8_a*)(Q + base + (size_t)qrow * 64 + g * 8);
  qf[1] = *(const bf16x8_a*)(Q + base + (size_t)qrow * 64 + 32 + g * 8);

  const int srow = lane >> 3;
  const int schunk = ((lane & 7) ^ srow) * 8;

  union {
    unsigned short u[8];
    bf16x8 v;
  } ou;
#pragma unroll
  for (int i = 0; i < 8; ++i) ou.u[i] = 0x3F80;
  const bf16x8 onesb = ou.v;

  f32x4 o[4] = {};
  float mrow = -1e30f, lrow = 0.f;

  auto stage = [&](int bufi, int kt0s) {
#pragma unroll
    for (int i = 0; i < 2; ++i) {
      const int inst = wid * 2 + i;
      const int row = 8 * inst + srow;
      GLOAD_LDS16(Kb + (size_t)(kt0s + row) * 64 + schunk, &sK[bufi][inst * 512]);
      GLOAD_LDS16(Vb + (size_t)row * 2048 + kt0s + schunk, &sV[bufi][inst * 512]);
    }
  };

  stage(0, 0);

  for (int t = 0; t < 32; ++t) {
    const int cur = t & 1;
    __syncthreads();
    if (t < 31) stage(cur ^ 1, (t + 1) * 64);

    f32x4 sc[4] = {};
#pragma unroll
    for (int kt = 0; kt < 4; ++kt) {
      const int rb = (kt * 16 + r15) * 64;
      bf16x8 kf0 = *(const bf16x8_a*)&sK[cur][rb + s0];
      bf16x8 kf1 = *(const bf16x8_a*)&sK[cur][rb + s1];
      sc[kt] = MFMA_B16(kf0, qf[0], sc[kt]);
      sc[kt] = MFMA_B16(kf1, qf[1], sc[kt]);
    }

    float pmax = sc[0][0];
#pragma unroll
    for (int kt = 0; kt < 4; ++kt)
#pragma unroll
      for (int r = 0; r < 4; ++r) pmax = fmaxf(pmax, sc[kt][r]);
    pmax = fmaxf(pmax, __shfl_xor(pmax, 16));
    pmax = fmaxf(pmax, __shfl_xor(pmax, 32));

    const bool allkeep = __all(pmax - mrow <= 8.0f);
    float fac;
    if (allkeep) {
      fac = 1.0f;
    } else {
      float nm = fmaxf(mrow, pmax);
      fac = __expf(mrow - nm);
      mrow = nm;
#pragma unroll
      for (int dt = 0; dt < 4; ++dt)
#pragma unroll
        for (int r = 0; r < 4; ++r) o[dt][r] *= fac;
    }

#pragma unroll
    for (int kt = 0; kt < 4; ++kt) {
      u16x4_a pb = {f2b(__expf(sc[kt][0] - mrow)), f2b(__expf(sc[kt][1] - mrow)),
                    f2b(__expf(sc[kt][2] - mrow)), f2b(__expf(sc[kt][3] - mrow))};
      *(u16x4_a*)&sP[wid][r15 * 72 + kt * 16 + g * 4] = pb;
    }

    bf16x8 pf0 = *(const bf16x8_a*)&sP[wid][r15 * 72 + g * 8];
    bf16x8 pf1 = *(const bf16x8_a*)&sP[wid][r15 * 72 + 32 + g * 8];

    f32x4 lacc = {};
    lacc = MFMA_B16(onesb, pf0, lacc);
    lacc = MFMA_B16(onesb, pf1, lacc);
    lrow = lrow * fac + lacc[0];

#pragma unroll
    for (int dt = 0; dt < 4; ++dt) {
      const int rb = (dt * 16 + r15) * 64;
      bf16x8 vf0 = *(const bf16x8_a*)&sV[cur][rb + s0];
      bf16x8 vf1 = *(const bf16x8_a*)&sV[cur][rb + s1];
      o[dt] = MFMA_B16(vf0, pf0, o[dt]);
      o[dt] = MFMA_B16(vf1, pf1, o[dt]);
    }
  }

  const int b = bh >> 4, hh = bh & 15;
  const int s = q0 + wid * 16 + r15;
  const float inv = 1.f / lrow;
  unsigned short* orow = out + ((size_t)(b * 2048 + s)) * 1024 + hh * 64;
#pragma unroll
  for (int dt = 0; dt < 4; ++dt) {
    u16x4_a t = {f2b(o[dt][0] * inv), f2b(o[dt][1] * inv), f2b(o[dt][2] * inv),
                 f2b(o[dt][3] * inv)};
    *(u16x4_a*)(orow + dt * 16 + g * 4) = t;
  }
}

// ---------- LayerNorm over 1024 cols; optional f32 and bf16 outputs ----------
__global__ __launch_bounds__(256) void ln_kernel(const float* __restrict__ in,
                                                 const float* __restrict__ gamma,
                                                 const float* __restrict__ beta,
                                                 float* __restrict__ outf,
                                                 unsigned short* __restrict__ outb) {
  const int row = blockIdx.x, tid = threadIdx.x;
  float4 v = ((const float4*)(in + (size_t)row * 1024))[tid];
  float s = v.x + v.y + v.z + v.w;
  float ss = v.x * v.x + v.y * v.y + v.z * v.z + v.w * v.w;
#pragma unroll
  for (int off = 32; off > 0; off >>= 1) {
    s += __shfl_down(s, off);
    ss += __shfl_down(ss, off);
  }
  __shared__ float red[8];
  const int wid = tid >> 6;
  if ((tid & 63) == 0) { red[wid] = s; red[4 + wid] = ss; }
  __syncthreads();
  float S = red[0] + red[1] + red[2] + red[3];
  float SS = red[4] + red[5] + red[6] + red[7];
  const float mean = S * (1.f / 1024.f);
  const float var = SS * (1.f / 1024.f) - mean * mean;
  const float inv = 1.f / sqrtf(var + 1e-10f);
  float4 gg = ((const float4*)gamma)[tid];
  float4 bb = ((const float4*)beta)[tid];
  float4 o;
  o.x = (v.x - mean) * inv * gg.x + bb.x;
  o.y = (v.y - mean) * inv * gg.y + bb.y;
  o.z = (v.z - mean) * inv * gg.z + bb.z;
  o.w = (v.w - mean) * inv * gg.w + bb.w;
  if (outf) ((float4*)(outf + (size_t)row * 1024))[tid] = o;
  if (outb) {
    u16x4_a t = {f2b(o.x), f2b(o.y), f2b(o.z), f2b(o.w)};
    *(u16x4_a*)(outb + (size_t)row * 1024 + tid * 4) = t;
  }
}

// ---------- fused split-K reduce + bias + residual + LayerNorm -> f32 out ----------
__global__ __launch_bounds__(256) void ln3_kernel(
    const float* __restrict__ p0, const float* __restrict__ p1, const float* __restrict__ p2,
    const float* __restrict__ bias, const float* __restrict__ resid,
    const float* __restrict__ gamma, const float* __restrict__ beta,
    float* __restrict__ outf) {
  const int row = blockIdx.x, tid = threadIdx.x;
  const size_t off = (size_t)row * 1024;
  float4 a = ((const float4*)(p0 + off))[tid];
  float4 b = ((const float4*)(p1 + off))[tid];
  float4 c = ((const float4*)(p2 + off))[tid];
  float4 bb4 = ((const float4*)bias)[tid];
  float4 rr = ((const float4*)(resid + off))[tid];
  float4 v;
  v.x = a.x + b.x + c.x + bb4.x + rr.x;
  v.y = a.y + b.y + c.y + bb4.y + rr.y;
  v.z = a.z + b.z + c.z + bb4.z + rr.z;
  v.w = a.w + b.w + c.w + bb4.w + rr.w;

  float s = v.x + v.y + v.z + v.w;
  float ss = v.x * v.x + v.y * v.y + v.z * v.z + v.w * v.w;
#pragma unroll
  for (int off2 = 32; off2 > 0; off2 >>= 1) {
    s += __shfl_down(s, off2);
    ss += __shfl_down(ss, off2);
  }
  __shared__ float red[8];
  const int wid = tid >> 6;
  if ((tid & 63) == 0) { red[wid] = s; red[4 + wid] = ss; }
  __syncthreads();
  float S = red[0] + red[1] + red[2] + red[3];
  float SS = red[4] + red[5] + red[6] + red[7];
  const float mean = S * (1.f / 1024.f);
  const float var = SS * (1.f / 1024.f) - mean * mean;
  const float inv = 1.f / sqrtf(var + 1e-10f);
  float4 gg = ((const float4*)gamma)[tid];
  float4 be = ((const float4*)beta)[tid];
  float4 o;
  o.x = (v.x - mean) * inv * gg.x + be.x;
  o.y = (v.y - mean) * inv * gg.y + be.y;
  o.z = (v.z - mean) * inv * gg.z + be.z;
  o.w = (v.w - mean) * inv * gg.w + be.w;
  ((float4*)(outf + off))[tid] = o;
}

// ---------- launch ----------
extern "C" void kernel_launch(void* const* d_in, const int* in_sizes, int n_in,
                              void* d_out, int out_size, void* d_ws, size_t ws_size,
                              hipStream_t stream) {
  const float* x      = (const float*)d_in[0];
  const float* wq     = (const float*)d_in[1];
  const float* bq     = (const float*)d_in[2];
  const float* wk     = (const float*)d_in[3];
  const float* bk     = (const float*)d_in[4];
  const float* wv     = (const float*)d_in[5];
  const float* bv     = (const float*)d_in[6];
  const float* w_proj = (const float*)d_in[7];
  const float* b_proj = (const float*)d_in[8];
  const float* gamma1 = (const float*)d_in[9];
  const float* beta1  = (const float*)d_in[10];
  const float* w1     = (const float*)d_in[11];
  const float* b1     = (const float*)d_in[12];
  const float* w2     = (const float*)d_in[13];
  const float* b2     = (const float*)d_in[14];
  const float* gamma2 = (const float*)d_in[15];
  const float* beta2  = (const float*)d_in[16];

  char* p = (char*)d_ws;
  auto alloc = [&](size_t bytes) {
    char* r = p;
    p += (bytes + 255) & ~(size_t)255;
    return r;
  };
  // NOTE: split-K partials alias dead regions (see liveness notes below).
  unsigned short* xb      = (unsigned short*)alloc(4096ull * 1024 * 2);  // dead after proj
  unsigned short* Wqkv_t  = (unsigned short*)alloc(3072ull * 1024 * 2);  // dead after QKV
  unsigned short* Wproj_t = (unsigned short*)alloc(1024ull * 1024 * 2);  // dead after proj
  unsigned short* W1t     = (unsigned short*)alloc(4096ull * 1024 * 2);  // dead after FFN1
  unsigned short* W2t     = (unsigned short*)alloc(1024ull * 4096 * 2);  // live thru FFN2
  float*          biasq   = (float*)alloc(3072 * 4);
  unsigned short* Qb      = (unsigned short*)alloc(4096ull * 1024 * 2);  // dead after attn
  unsigned short* Kb      = (unsigned short*)alloc(4096ull * 1024 * 2);  // dead after attn
  unsigned short* Vtb     = (unsigned short*)alloc(4096ull * 1024 * 2);  // dead after attn
  float*          resid1  = (float*)alloc(4096ull * 1024 * 4);           // dead after LN1
  float*          out1f   = (float*)alloc(4096ull * 1024 * 4);           // live thru ln3
  unsigned short* out1b   = (unsigned short*)alloc(4096ull * 1024 * 2);  // dead after FFN1
  unsigned short* ffn_h   = (unsigned short*)alloc(4096ull * 4096 * 2);  // live thru FFN2
  unsigned short* concat  = xb;

  // FFN2 split-K=3 partials: 3 x 16MB in regions dead by FFN2 launch time.
  float* pp0 = (float*)xb;   // xb(8MB)+Wqkv_t(6MB)+Wproj_t(2MB) = 16MB contiguous
  float* pp1 = (float*)Qb;   // Qb(8MB)+Kb(8MB) = 16MB contiguous
  float* pp2 = (float*)Vtb;  // Vtb(8MB)+resid1 first 8MB = 16MB contiguous

  cvt_kernel<<<4096, 256, 0, stream>>>(x, xb, 4096 * 1024 / 4);
  transpose_cvt<<<dim3(2, 32, 16), 256, 0, stream>>>(wq, Wqkv_t, 1024, 64, 0.125f);
  transpose_cvt<<<dim3(2, 32, 16), 256, 0, stream>>>(wk, Wqkv_t + 1024 * 1024, 1024, 64, 1.f);
  transpose_cvt<<<dim3(2, 32, 16), 256, 0, stream>>>(wv, Wqkv_t + 2048 * 1024, 1024, 64, 1.f);
  transpose_cvt<<<dim3(32, 32, 1), 256, 0, stream>>>(w_proj, Wproj_t, 1024, 1024, 1.f);
  transpose_cvt<<<dim3(128, 32, 1), 256, 0, stream>>>(w1, W1t, 1024, 4096, 1.f);
  transpose_cvt<<<dim3(32, 128, 1), 256, 0, stream>>>(w2, W2t, 4096, 1024, 1.f);
  build_bias_qkv<<<12, 256, 0, stream>>>(bq, bk, bv, biasq);

  // QKV: 256^2 8-phase, M=4096 N=3072 -> 16x12 = 192 blocks
  gemm256_kernel<0><<<192, 512, 0, stream>>>(xb, Wqkv_t, 4096, 3072, 1024, 12, 1, biasq,
                                             nullptr, Qb, Kb, Vtb, nullptr, nullptr, nullptr);
  attn_kernel<<<dim3(32, 32), 256, 0, stream>>>(Qb, Kb, Vtb, concat);
  gemm_bt_kernel<1><<<dim3(8, 32), 256, 0, stream>>>(concat, Wproj_t, 4096, 1024, 1024, b_proj,
                                                     x, resid1);
  ln_kernel<<<4096, 256, 0, stream>>>(resid1, gamma1, beta1, out1f, out1b);
  // FFN1: 256^2 8-phase, M=4096 N=4096 -> 16x16 = 256 blocks
  gemm256_kernel<2><<<256, 512, 0, stream>>>(out1b, W1t, 4096, 4096, 1024, 16, 1, b1,
                                             ffn_h, nullptr, nullptr, nullptr,
                                             nullptr, nullptr, nullptr);
  // FFN2: 256^2 8-phase split-K=3, M=4096 N=1024 K=4096 -> 16x4x3 = 192 blocks
  gemm256_kernel<3><<<192, 512, 0, stream>>>(ffn_h, W2t, 4096, 1024, 4096, 4, 3, nullptr,
                                             nullptr, nullptr, nullptr, nullptr,
                                             pp0, pp1, pp2);
  // fused reduce + b2 + residual(out1f) + LN2 -> d_out
  ln3_kernel<<<4096, 256, 0, stream>>>(pp0, pp1, pp2, b2, out1f, gamma2, beta2,
                                       (float*)d_out);
}

// Round 7
// 306.141 us; speedup vs baseline: 1.6953x; 1.0199x over previous
//
#include <hip/hip_runtime.h>
#include <stdint.h>

// ---------- types ----------
typedef float f32x4 __attribute__((ext_vector_type(4)));
typedef __bf16 bf16x8 __attribute__((ext_vector_type(8)));
typedef __bf16 bf16x8_a __attribute__((ext_vector_type(8), may_alias));
typedef __bf16 bf16x4_a __attribute__((ext_vector_type(4), may_alias));
typedef unsigned int u32x4_a __attribute__((ext_vector_type(4), may_alias));
typedef unsigned short u16x4_a __attribute__((ext_vector_type(4), may_alias));

#define DEV __device__ __forceinline__
#define MFMA_B16(a, b, c) __builtin_amdgcn_mfma_f32_16x16x32_bf16((a), (b), (c), 0, 0, 0)

#if __has_builtin(__builtin_amdgcn_exp2f)
#define EXP2(x) __builtin_amdgcn_exp2f(x)
#else
#define EXP2(x) exp2f(x)
#endif

DEV unsigned short f2b(float f) {  // f32 -> bf16 RNE
  unsigned int u = __float_as_uint(f);
  u = u + 0x7FFFu + ((u >> 16) & 1u);
  return (unsigned short)(u >> 16);
}

// async global->LDS, 16B per lane; LDS dest is wave-uniform base + lane*16
#define GLOAD_LDS16(gsrc, ldst)                                                  \
  __builtin_amdgcn_global_load_lds(                                              \
      (__attribute__((address_space(1))) void*)(uintptr_t)(const void*)(gsrc),   \
      (__attribute__((address_space(3))) void*)(ldst), 16, 0, 0)

// ---------- conversion kernels ----------
__global__ __launch_bounds__(256) void cvt_kernel(const float* __restrict__ in,
                                                  unsigned short* __restrict__ out, int n4) {
  int i = blockIdx.x * 256 + threadIdx.x;
  if (i < n4) {
    float4 v = ((const float4*)in)[i];
    u16x4_a t = {f2b(v.x), f2b(v.y), f2b(v.z), f2b(v.w)};
    ((u16x4_a*)out)[i] = t;
  }
}

// in: [rows][cols] f32 (batched on z) -> out: [cols][rows] bf16 (*scale)
__global__ __launch_bounds__(256) void transpose_cvt(const float* __restrict__ in,
                                                     unsigned short* __restrict__ out,
                                                     int rows, int cols, float scale) {
  __shared__ float tile[32][33];
  const int tx = threadIdx.x & 31, ty = threadIdx.x >> 5;
  const int c0 = blockIdx.x * 32, r0 = blockIdx.y * 32;
  const float* ip = in + (size_t)blockIdx.z * rows * cols;
  unsigned short* op = out + (size_t)blockIdx.z * rows * cols;
#pragma unroll
  for (int j = 0; j < 32; j += 8)
    tile[ty + j][tx] = ip[(size_t)(r0 + ty + j) * cols + (c0 + tx)];
  __syncthreads();
#pragma unroll
  for (int j = 0; j < 32; j += 8)
    op[(size_t)(c0 + ty + j) * rows + (r0 + tx)] = f2b(tile[tx][ty + j] * scale);
}

__global__ void build_bias_qkv(const float* __restrict__ bq, const float* __restrict__ bk,
                               const float* __restrict__ bv, float* __restrict__ out) {
  int c = blockIdx.x * 256 + threadIdx.x;  // 0..3071
  int which = c >> 10, idx = c & 1023;
  float v = which == 0 ? bq[idx] : (which == 1 ? bk[idx] : bv[idx]);
  // fold 1/sqrt(HD) * log2(e) into q (exp2-domain softmax)
  out[c] = which == 0 ? v * 0.18033688f : v;
}

// ---------- 256x256 8-phase GEMM (m201 template, plain HIP) ----------
// EP 0: QKV scatter + bias. EP 2: bf16 relu(acc+bias). EP 3: f32 raw partial
// (split-K; partial buffer selected by kz, no bias).
template <int EP>
__global__ __launch_bounds__(512, 2) void gemm256_kernel(
    const unsigned short* __restrict__ A, const unsigned short* __restrict__ Bt,
    int M, int N, int K, int nbx, int KS,
    const float* __restrict__ bias, unsigned short* __restrict__ outb,
    unsigned short* __restrict__ q_out, unsigned short* __restrict__ k_out,
    unsigned short* __restrict__ v_out,
    float* __restrict__ pp0, float* __restrict__ pp1, float* __restrict__ pp2) {
  __shared__ __align__(16) unsigned short sA[2][256 * 64];
  __shared__ __align__(16) unsigned short sB[2][256 * 64];

  const int tid = threadIdx.x;
  const int wid = tid >> 6, lane = tid & 63;
  const int g = lane >> 4, r15 = lane & 15;
  const int wm = wid >> 2, wn = wid & 3;

  const int nwg = gridDim.x, cpx = nwg >> 3, orig = blockIdx.x;
  const int wg = (orig & 7) * cpx + (orig >> 3);
  const int bx = wg % nbx;
  const int t1 = wg / nbx;
  const int kz = t1 % KS, by = t1 / KS;
  const int row0 = by * 256, col0 = bx * 256;

  const int tilesK = K >> 6;
  const int qT = tilesK / KS, rT = tilesK % KS;
  const int tile0 = kz * qT + (kz < rT ? kz : rT);
  const int NT = qT + (kz < rT ? 1 : 0);
  const int kbase = tile0 << 6;

  const unsigned short* gA0 = A + (size_t)row0 * K + kbase;
  const unsigned short* gB0 = Bt + (size_t)col0 * K + kbase;
  const int srow8 = lane >> 3;
  const int schunk = ((lane & 7) ^ srow8) * 8;

  f32x4 acc[8][4] = {};
  bf16x8 af[4][2], bfr[4][2];

  auto stA = [&](int buf, int k0, int i) {
    const int r = wid * 32 + i * 8;
    GLOAD_LDS16(gA0 + (size_t)(r + srow8) * K + k0 + schunk, &sA[buf][r * 64]);
  };
  auto stB = [&](int buf, int k0, int i) {
    const int r = wid * 32 + i * 8;
    GLOAD_LDS16(gB0 + (size_t)(r + srow8) * K + k0 + schunk, &sB[buf][r * 64]);
  };
  auto ldA = [&](const unsigned short* p, int m, int ks) -> bf16x8 {
    const int row = wm * 128 + m * 16 + r15;
    return *(const bf16x8_a*)&p[row * 64 + (((ks * 4 + g) ^ (r15 & 7)) * 8)];
  };
  auto ldB = [&](const unsigned short* p, int n, int ks) -> bf16x8 {
    const int row = wn * 64 + n * 16 + r15;
    return *(const bf16x8_a*)&p[row * 64 + (((ks * 4 + g) ^ (r15 & 7)) * 8)];
  };

#pragma unroll
  for (int i = 0; i < 4; ++i) { stA(0, 0, i); stB(0, 0, i); }
  asm volatile("s_waitcnt vmcnt(0)" ::: "memory");
  __builtin_amdgcn_s_barrier();

  for (int kt = 0; kt < NT; ++kt) {
    const int cb = kt & 1, nb = cb ^ 1;
    const bool pf = (kt + 1) < NT;
    const int k1 = (kt + 1) << 6;
    const unsigned short* pA = sA[cb];
    const unsigned short* pB = sB[cb];

#pragma unroll
    for (int m = 0; m < 4; ++m) { af[m][0] = ldA(pA, m, 0); af[m][1] = ldA(pA, m, 1); }
#pragma unroll
    for (int n = 0; n < 4; ++n) { bfr[n][0] = ldB(pB, n, 0); bfr[n][1] = ldB(pB, n, 1); }
    if (pf) { stA(nb, k1, 0); stA(nb, k1, 1); }
    __builtin_amdgcn_s_barrier();
    asm volatile("s_waitcnt lgkmcnt(0)" ::: "memory");
    __builtin_amdgcn_sched_barrier(0);
    __builtin_amdgcn_s_setprio(1);
#pragma unroll
    for (int m = 0; m < 4; ++m)
#pragma unroll
      for (int n = 0; n < 2; ++n) {
        acc[m][n] = MFMA_B16(af[m][0], bfr[n][0], acc[m][n]);
        acc[m][n] = MFMA_B16(af[m][1], bfr[n][1], acc[m][n]);
      }
    __builtin_amdgcn_s_setprio(0);
    __builtin_amdgcn_s_barrier();

    if (pf) { stA(nb, k1, 2); stA(nb, k1, 3); }
    __builtin_amdgcn_s_barrier();
    __builtin_amdgcn_s_setprio(1);
#pragma unroll
    for (int m = 0; m < 4; ++m)
#pragma unroll
      for (int n = 2; n < 4; ++n) {
        acc[m][n] = MFMA_B16(af[m][0], bfr[n][0], acc[m][n]);
        acc[m][n] = MFMA_B16(af[m][1], bfr[n][1], acc[m][n]);
      }
    __builtin_amdgcn_s_setprio(0);
    __builtin_amdgcn_s_barrier();

#pragma unroll
    for (int m = 0; m < 4; ++m) { af[m][0] = ldA(pA, m + 4, 0); af[m][1] = ldA(pA, m + 4, 1); }
    if (pf) { stB(nb, k1, 0); stB(nb, k1, 1); }
    __builtin_amdgcn_s_barrier();
    asm volatile("s_waitcnt lgkmcnt(0)" ::: "memory");
    __builtin_amdgcn_sched_barrier(0);
    __builtin_amdgcn_s_setprio(1);
#pragma unroll
    for (int m = 0; m < 4; ++m)
#pragma unroll
      for (int n = 0; n < 2; ++n) {
        acc[m + 4][n] = MFMA_B16(af[m][0], bfr[n][0], acc[m + 4][n]);
        acc[m + 4][n] = MFMA_B16(af[m][1], bfr[n][1], acc[m + 4][n]);
      }
    __builtin_amdgcn_s_setprio(0);
    __builtin_amdgcn_s_barrier();

    if (pf) { stB(nb, k1, 2); stB(nb, k1, 3); }
    __builtin_amdgcn_s_barrier();
    __builtin_amdgcn_s_setprio(1);
#pragma unroll
    for (int m = 0; m < 4; ++m)
#pragma unroll
      for (int n = 2; n < 4; ++n) {
        acc[m + 4][n] = MFMA_B16(af[m][0], bfr[n][0], acc[m + 4][n]);
        acc[m + 4][n] = MFMA_B16(af[m][1], bfr[n][1], acc[m + 4][n]);
      }
    __builtin_amdgcn_s_setprio(0);
    asm volatile("s_waitcnt vmcnt(0)" ::: "memory");
    __builtin_amdgcn_s_barrier();
  }

  float* pz = kz == 0 ? pp0 : (kz == 1 ? pp1 : pp2);
#pragma unroll
  for (int m = 0; m < 8; ++m) {
    const int rbase = row0 + wm * 128 + m * 16 + g * 4;
#pragma unroll
    for (int n = 0; n < 4; ++n) {
      const int col = col0 + wn * 64 + n * 16 + r15;
      const float bb = (EP == 3) ? 0.f : bias[col];
#pragma unroll
      for (int r = 0; r < 4; ++r) {
        const int row = rbase + r;
        float v = acc[m][n][r] + bb;
        if constexpr (EP == 0) {
          int which = col >> 10, cc = col & 1023;
          int h = cc >> 6, e = cc & 63;
          int b = row >> 11, s = row & 2047;
          if (which == 2) {
            v_out[(((size_t)(b * 16 + h) * 64) + e) * 2048 + s] = f2b(v);
          } else {
            unsigned short* dst = which == 0 ? q_out : k_out;
            dst[(((size_t)(b * 16 + h) * 2048) + s) * 64 + e] = f2b(v);
          }
        } else if constexpr (EP == 3) {
          pz[(size_t)row * N + col] = v;
        } else {
          outb[(size_t)row * N + col] = f2b(v > 0.f ? v : 0.f);
        }
      }
    }
  }
}

// ---------- 128x128 GEMM (m97 structure + depth-1 dbuf overlap) ----------
template <int EP>
__global__ __launch_bounds__(256) void gemm_bt_kernel(
    const unsigned short* __restrict__ A, const unsigned short* __restrict__ Bt,
    int M, int N, int K,
    const float* __restrict__ bias, const float* __restrict__ addf,
    float* __restrict__ outf) {
  __shared__ __align__(16) unsigned short sA[2][128 * 32];
  __shared__ __align__(16) unsigned short sB[2][128 * 32];
  const int tid = threadIdx.x;
  const int wid = tid >> 6, lane = tid & 63;
  const int g = lane >> 4, r15 = lane & 15;
  const int wr = wid >> 1, wc = wid & 1;
  const int row0 = blockIdx.y * 128, col0 = blockIdx.x * 128;

  f32x4 acc[4][4] = {};

  const int c0 = wid * 128 + lane;
  const unsigned short* gA0 = A + (size_t)row0 * K;
  const unsigned short* gB0 = Bt + (size_t)col0 * K;

  auto stage = [&](int buf, int k0) {
#pragma unroll
    for (int j = 0; j < 2; ++j) {
      int c = c0 + j * 64;
      GLOAD_LDS16(gA0 + (size_t)(c >> 2) * K + k0 + (c & 3) * 8,
                  &sA[buf][(wid * 128 + j * 64) * 8]);
      GLOAD_LDS16(gB0 + (size_t)(c >> 2) * K + k0 + (c & 3) * 8,
                  &sB[buf][(wid * 128 + j * 64) * 8]);
    }
  };

  stage(0, 0);
  const int NT = K >> 5;
  for (int t = 0; t < NT; ++t) {
    const int cb = t & 1;
    __syncthreads();
    if (t + 1 < NT) stage(cb ^ 1, (t + 1) * 32);
    bf16x8 af[4], bfr[4];
#pragma unroll
    for (int m = 0; m < 4; ++m)
      af[m] = *(const bf16x8_a*)&sA[cb][(wr * 64 + m * 16 + r15) * 32 + g * 8];
#pragma unroll
    for (int n = 0; n < 4; ++n)
      bfr[n] = *(const bf16x8_a*)&sB[cb][(wc * 64 + n * 16 + r15) * 32 + g * 8];
#pragma unroll
    for (int m = 0; m < 4; ++m)
#pragma unroll
      for (int n = 0; n < 4; ++n)
        acc[m][n] = MFMA_B16(af[m], bfr[n], acc[m][n]);
  }

#pragma unroll
  for (int m = 0; m < 4; ++m) {
    const int rbase = row0 + wr * 64 + m * 16 + g * 4;
#pragma unroll
    for (int n = 0; n < 4; ++n) {
      const int col = col0 + wc * 64 + n * 16 + r15;
      const float bb = bias[col];
#pragma unroll
      for (int r = 0; r < 4; ++r) {
        const int row = rbase + r;
        size_t idx = (size_t)row * N + col;
        outf[idx] = acc[m][n][r] + bb + addf[idx];
      }
    }
  }
}

// ---------- flash attention, swapped-operand softmax, exp2 domain ----------
__global__ __launch_bounds__(256) void attn_kernel(const unsigned short* __restrict__ Q,
                                                   const unsigned short* __restrict__ K,
                                                   const unsigned short* __restrict__ Vt,
                                                   unsigned short* __restrict__ out) {
  const int flat = blockIdx.y * gridDim.x + blockIdx.x;  // 0..1023
  const int xcd = flat & 7, rest = flat >> 3;
  const int bh = xcd * 4 + (rest >> 5);
  const int q0 = (rest & 31) * 64;

  const int tid = threadIdx.x, wid = tid >> 6, lane = tid & 63;
  const int g = lane >> 4, r15 = lane & 15;
  const int h = r15 & 7;
  const int s0 = ((g ^ h) * 8);
  const int s1 = (((g + 4) ^ h) * 8);

  __shared__ __align__(16) unsigned short sK[2][64 * 64];
  __shared__ __align__(16) unsigned short sV[2][64 * 64];
  __shared__ __align__(16) unsigned short sP[4][16 * 72];

  const size_t base = (size_t)bh * (2048 * 64);
  const unsigned short* Kb = K + base;
  const unsigned short* Vb = Vt + base;

  const int qrow = q0 + wid * 16 + r15;
  bf16x8 qf[2];
  qf[0] = *(const bf16x8_a*)(Q + base + (size_t)qrow * 64 + g * 8);
  qf[1] = *(const bf16x8_a*)(Q + base + (size_t)qrow * 64 + 32 + g * 8);

  const int srow = lane >> 3;
  const int schunk = ((lane & 7) ^ srow) * 8;

  union {
    unsigned short u[8];
    bf16x8 v;
  } ou;
#pragma unroll
  for (int i = 0; i < 8; ++i) ou.u[i] = 0x3F80;
  const bf16x8 onesb = ou.v;

  f32x4 o[4] = {};
  float mrow = -1e30f, lrow = 0.f;

  auto stage = [&](int bufi, int kt0s) {
#pragma unroll
    for (int i = 0; i < 2; ++i) {
      const int inst = wid * 2 + i;
      const int row = 8 * inst + srow;
      GLOAD_LDS16(Kb + (size_t)(kt0s + row) * 64 + schunk, &sK[bufi][inst * 512]);
      GLOAD_LDS16(Vb + (size_t)row * 2048 + kt0s + schunk, &sV[bufi][inst * 512]);
    }
  };

  stage(0, 0);

  for (int t = 0; t < 32; ++t) {
    const int cur = t & 1;
    __syncthreads();
    if (t < 31) stage(cur ^ 1, (t + 1) * 64);

    // scores (exp2-domain: log2e/sqrt(HD) folded into Q)
    f32x4 sc[4] = {};
#pragma unroll
    for (int kt = 0; kt < 4; ++kt) {
      const int rb = (kt * 16 + r15) * 64;
      bf16x8 kf0 = *(const bf16x8_a*)&sK[cur][rb + s0];
      bf16x8 kf1 = *(const bf16x8_a*)&sK[cur][rb + s1];
      sc[kt] = MFMA_B16(kf0, qf[0], sc[kt]);
      sc[kt] = MFMA_B16(kf1, qf[1], sc[kt]);
    }

    // tree max (depth 4) + 2 cross-group shuffles
    float t0 = fmaxf(fmaxf(sc[0][0], sc[0][1]), fmaxf(sc[0][2], sc[0][3]));
    float t1 = fmaxf(fmaxf(sc[1][0], sc[1][1]), fmaxf(sc[1][2], sc[1][3]));
    float t2 = fmaxf(fmaxf(sc[2][0], sc[2][1]), fmaxf(sc[2][2], sc[2][3]));
    float t3 = fmaxf(fmaxf(sc[3][0], sc[3][1]), fmaxf(sc[3][2], sc[3][3]));
    float pmax = fmaxf(fmaxf(t0, t1), fmaxf(t2, t3));
    pmax = fmaxf(pmax, __shfl_xor(pmax, 16));
    pmax = fmaxf(pmax, __shfl_xor(pmax, 32));

    // defer-max: bound 2^11.544 = e^8
    const bool allkeep = __all(pmax - mrow <= 11.5441f);
    float fac;
    if (allkeep) {
      fac = 1.0f;
    } else {
      float nm = fmaxf(mrow, pmax);
      fac = EXP2(mrow - nm);
      mrow = nm;
#pragma unroll
      for (int dt = 0; dt < 4; ++dt)
#pragma unroll
        for (int r = 0; r < 4; ++r) o[dt][r] *= fac;
    }

    // P = exp2(S - m); native casts -> compiler emits v_cvt_pk_bf16_f32
#pragma unroll
    for (int kt = 0; kt < 4; ++kt) {
      bf16x4_a pb;
      pb[0] = (__bf16)EXP2(sc[kt][0] - mrow);
      pb[1] = (__bf16)EXP2(sc[kt][1] - mrow);
      pb[2] = (__bf16)EXP2(sc[kt][2] - mrow);
      pb[3] = (__bf16)EXP2(sc[kt][3] - mrow);
      *(bf16x4_a*)&sP[wid][r15 * 72 + kt * 16 + g * 4] = pb;
    }

    bf16x8 pf0 = *(const bf16x8_a*)&sP[wid][r15 * 72 + g * 8];
    bf16x8 pf1 = *(const bf16x8_a*)&sP[wid][r15 * 72 + 32 + g * 8];

    f32x4 lacc = {};
    lacc = MFMA_B16(onesb, pf0, lacc);
    lacc = MFMA_B16(onesb, pf1, lacc);
    lrow = lrow * fac + lacc[0];

#pragma unroll
    for (int dt = 0; dt < 4; ++dt) {
      const int rb = (dt * 16 + r15) * 64;
      bf16x8 vf0 = *(const bf16x8_a*)&sV[cur][rb + s0];
      bf16x8 vf1 = *(const bf16x8_a*)&sV[cur][rb + s1];
      o[dt] = MFMA_B16(vf0, pf0, o[dt]);
      o[dt] = MFMA_B16(vf1, pf1, o[dt]);
    }
  }

  const int b = bh >> 4, hh = bh & 15;
  const int s = q0 + wid * 16 + r15;
  const float inv = 1.f / lrow;
  unsigned short* orow = out + ((size_t)(b * 2048 + s)) * 1024 + hh * 64;
#pragma unroll
  for (int dt = 0; dt < 4; ++dt) {
    bf16x4_a tq;
    tq[0] = (__bf16)(o[dt][0] * inv);
    tq[1] = (__bf16)(o[dt][1] * inv);
    tq[2] = (__bf16)(o[dt][2] * inv);
    tq[3] = (__bf16)(o[dt][3] * inv);
    *(bf16x4_a*)(orow + dt * 16 + g * 4) = tq;
  }
}

// ---------- LayerNorm over 1024 cols; optional f32 and bf16 outputs ----------
__global__ __launch_bounds__(256) void ln_kernel(const float* __restrict__ in,
                                                 const float* __restrict__ gamma,
                                                 const float* __restrict__ beta,
                                                 float* __restrict__ outf,
                                                 unsigned short* __restrict__ outb) {
  const int row = blockIdx.x, tid = threadIdx.x;
  float4 v = ((const float4*)(in + (size_t)row * 1024))[tid];
  float s = v.x + v.y + v.z + v.w;
  float ss = v.x * v.x + v.y * v.y + v.z * v.z + v.w * v.w;
#pragma unroll
  for (int off = 32; off > 0; off >>= 1) {
    s += __shfl_down(s, off);
    ss += __shfl_down(ss, off);
  }
  __shared__ float red[8];
  const int wid = tid >> 6;
  if ((tid & 63) == 0) { red[wid] = s; red[4 + wid] = ss; }
  __syncthreads();
  float S = red[0] + red[1] + red[2] + red[3];
  float SS = red[4] + red[5] + red[6] + red[7];
  const float mean = S * (1.f / 1024.f);
  const float var = SS * (1.f / 1024.f) - mean * mean;
  const float inv = 1.f / sqrtf(var + 1e-10f);
  float4 gg = ((const float4*)gamma)[tid];
  float4 bb = ((const float4*)beta)[tid];
  float4 o;
  o.x = (v.x - mean) * inv * gg.x + bb.x;
  o.y = (v.y - mean) * inv * gg.y + bb.y;
  o.z = (v.z - mean) * inv * gg.z + bb.z;
  o.w = (v.w - mean) * inv * gg.w + bb.w;
  if (outf) ((float4*)(outf + (size_t)row * 1024))[tid] = o;
  if (outb) {
    u16x4_a t = {f2b(o.x), f2b(o.y), f2b(o.z), f2b(o.w)};
    *(u16x4_a*)(outb + (size_t)row * 1024 + tid * 4) = t;
  }
}

// ---------- fused split-K reduce + bias + residual + LayerNorm -> f32 out ----------
__global__ __launch_bounds__(256) void ln3_kernel(
    const float* __restrict__ p0, const float* __restrict__ p1, const float* __restrict__ p2,
    const float* __restrict__ bias, const float* __restrict__ resid,
    const float* __restrict__ gamma, const float* __restrict__ beta,
    float* __restrict__ outf) {
  const int row = blockIdx.x, tid = threadIdx.x;
  const size_t off = (size_t)row * 1024;
  float4 a = ((const float4*)(p0 + off))[tid];
  float4 b = ((const float4*)(p1 + off))[tid];
  float4 c = ((const float4*)(p2 + off))[tid];
  float4 bb4 = ((const float4*)bias)[tid];
  float4 rr = ((const float4*)(resid + off))[tid];
  float4 v;
  v.x = a.x + b.x + c.x + bb4.x + rr.x;
  v.y = a.y + b.y + c.y + bb4.y + rr.y;
  v.z = a.z + b.z + c.z + bb4.z + rr.z;
  v.w = a.w + b.w + c.w + bb4.w + rr.w;

  float s = v.x + v.y + v.z + v.w;
  float ss = v.x * v.x + v.y * v.y + v.z * v.z + v.w * v.w;
#pragma unroll
  for (int off2 = 32; off2 > 0; off2 >>= 1) {
    s += __shfl_down(s, off2);
    ss += __shfl_down(ss, off2);
  }
  __shared__ float red[8];
  const int wid = tid >> 6;
  if ((tid & 63) == 0) { red[wid] = s; red[4 + wid] = ss; }
  __syncthreads();
  float S = red[0] + red[1] + red[2] + red[3];
  float SS = red[4] + red[5] + red[6] + red[7];
  const float mean = S * (1.f / 1024.f);
  const float var = SS * (1.f / 1024.f) - mean * mean;
  const float inv = 1.f / sqrtf(var + 1e-10f);
  float4 gg = ((const float4*)gamma)[tid];
  float4 be = ((const float4*)beta)[tid];
  float4 o;
  o.x = (v.x - mean) * inv * gg.x + be.x;
  o.y = (v.y - mean) * inv * gg.y + be.y;
  o.z = (v.z - mean) * inv * gg.z + be.z;
  o.w = (v.w - mean) * inv * gg.w + be.w;
  ((float4*)(outf + off))[tid] = o;
}

// ---------- launch ----------
extern "C" void kernel_launch(void* const* d_in, const int* in_sizes, int n_in,
                              void* d_out, int out_size, void* d_ws, size_t ws_size,
                              hipStream_t stream) {
  const float* x      = (const float*)d_in[0];
  const float* wq     = (const float*)d_in[1];
  const float* bq     = (const float*)d_in[2];
  const float* wk     = (const float*)d_in[3];
  const float* bk     = (const float*)d_in[4];
  const float* wv     = (const float*)d_in[5];
  const float* bv     = (const float*)d_in[6];
  const float* w_proj = (const float*)d_in[7];
  const float* b_proj = (const float*)d_in[8];
  const float* gamma1 = (const float*)d_in[9];
  const float* beta1  = (const float*)d_in[10];
  const float* w1     = (const float*)d_in[11];
  const float* b1     = (const float*)d_in[12];
  const float* w2     = (const float*)d_in[13];
  const float* b2     = (const float*)d_in[14];
  const float* gamma2 = (const float*)d_in[15];
  const float* beta2  = (const float*)d_in[16];

  char* p = (char*)d_ws;
  auto alloc = [&](size_t bytes) {
    char* r = p;
    p += (bytes + 255) & ~(size_t)255;
    return r;
  };
  unsigned short* xb      = (unsigned short*)alloc(4096ull * 1024 * 2);  // dead after proj
  unsigned short* Wqkv_t  = (unsigned short*)alloc(3072ull * 1024 * 2);  // dead after QKV
  unsigned short* Wproj_t = (unsigned short*)alloc(1024ull * 1024 * 2);  // dead after proj
  unsigned short* W1t     = (unsigned short*)alloc(4096ull * 1024 * 2);  // dead after FFN1
  unsigned short* W2t     = (unsigned short*)alloc(1024ull * 4096 * 2);  // live thru FFN2
  float*          biasq   = (float*)alloc(3072 * 4);
  unsigned short* Qb      = (unsigned short*)alloc(4096ull * 1024 * 2);  // dead after attn
  unsigned short* Kb      = (unsigned short*)alloc(4096ull * 1024 * 2);  // dead after attn
  unsigned short* Vtb     = (unsigned short*)alloc(4096ull * 1024 * 2);  // dead after attn
  float*          resid1  = (float*)alloc(4096ull * 1024 * 4);           // dead after LN1
  float*          out1f   = (float*)alloc(4096ull * 1024 * 4);           // live thru ln3
  unsigned short* out1b   = (unsigned short*)alloc(4096ull * 1024 * 2);  // dead after FFN1
  unsigned short* ffn_h   = (unsigned short*)alloc(4096ull * 4096 * 2);  // live thru FFN2
  unsigned short* concat  = xb;

  // FFN2 split-K=3 partials: 3 x 16MB in regions dead by FFN2 launch time.
  float* pp0 = (float*)xb;   // xb+Wqkv_t+Wproj_t = 16MB contiguous
  float* pp1 = (float*)Qb;   // Qb+Kb = 16MB contiguous
  float* pp2 = (float*)Vtb;  // Vtb+resid1 first 8MB = 16MB contiguous

  cvt_kernel<<<4096, 256, 0, stream>>>(x, xb, 4096 * 1024 / 4);
  // q weights carry 1/sqrt(HD)*log2(e) for exp2-domain softmax
  transpose_cvt<<<dim3(2, 32, 16), 256, 0, stream>>>(wq, Wqkv_t, 1024, 64, 0.18033688f);
  transpose_cvt<<<dim3(2, 32, 16), 256, 0, stream>>>(wk, Wqkv_t + 1024 * 1024, 1024, 64, 1.f);
  transpose_cvt<<<dim3(2, 32, 16), 256, 0, stream>>>(wv, Wqkv_t + 2048 * 1024, 1024, 64, 1.f);
  transpose_cvt<<<dim3(32, 32, 1), 256, 0, stream>>>(w_proj, Wproj_t, 1024, 1024, 1.f);
  transpose_cvt<<<dim3(128, 32, 1), 256, 0, stream>>>(w1, W1t, 1024, 4096, 1.f);
  transpose_cvt<<<dim3(32, 128, 1), 256, 0, stream>>>(w2, W2t, 4096, 1024, 1.f);
  build_bias_qkv<<<12, 256, 0, stream>>>(bq, bk, bv, biasq);

  gemm256_kernel<0><<<192, 512, 0, stream>>>(xb, Wqkv_t, 4096, 3072, 1024, 12, 1, biasq,
                                             nullptr, Qb, Kb, Vtb, nullptr, nullptr, nullptr);
  attn_kernel<<<dim3(32, 32), 256, 0, stream>>>(Qb, Kb, Vtb, concat);
  gemm_bt_kernel<1><<<dim3(8, 32), 256, 0, stream>>>(concat, Wproj_t, 4096, 1024, 1024, b_proj,
                                                     x, resid1);
  ln_kernel<<<4096, 256, 0, stream>>>(resid1, gamma1, beta1, out1f, out1b);
  gemm256_kernel<2><<<256, 512, 0, stream>>>(out1b, W1t, 4096, 4096, 1024, 16, 1, b1,
                                             ffn_h, nullptr, nullptr, nullptr,
                                             nullptr, nullptr, nullptr);
  gemm256_kernel<3><<<192, 512, 0, stream>>>(ffn_h, W2t, 4096, 1024, 4096, 4, 3, nullptr,
                                             nullptr, nullptr, nullptr, nullptr,
                                             pp0, pp1, pp2);
  ln3_kernel<<<4096, 256, 0, stream>>>(pp0, pp1, pp2, b2, out1f, gamma2, beta2,
                                       (float*)d_out);
}

// Round 8
// 269.139 us; speedup vs baseline: 1.9283x; 1.1375x over previous
//
#include <hip/hip_runtime.h>
#include <stdint.h>

// ---------- types ----------
typedef float f32x4 __attribute__((ext_vector_type(4)));
typedef __bf16 bf16x8 __attribute__((ext_vector_type(8)));
typedef __bf16 bf16x8_a __attribute__((ext_vector_type(8), may_alias));
typedef __bf16 bf16x4_a __attribute__((ext_vector_type(4), may_alias));
typedef unsigned int u32x4_a __attribute__((ext_vector_type(4), may_alias));
typedef unsigned short u16x4_a __attribute__((ext_vector_type(4), may_alias));

#define DEV __device__ __forceinline__
#define MFMA_B16(a, b, c) __builtin_amdgcn_mfma_f32_16x16x32_bf16((a), (b), (c), 0, 0, 0)

#if __has_builtin(__builtin_amdgcn_exp2f)
#define EXP2(x) __builtin_amdgcn_exp2f(x)
#else
#define EXP2(x) exp2f(x)
#endif

DEV unsigned short f2b(float f) {  // f32 -> bf16 RNE
  unsigned int u = __float_as_uint(f);
  u = u + 0x7FFFu + ((u >> 16) & 1u);
  return (unsigned short)(u >> 16);
}

// async global->LDS, 16B per lane; LDS dest is wave-uniform base + lane*16
#define GLOAD_LDS16(gsrc, ldst)                                                  \
  __builtin_amdgcn_global_load_lds(                                              \
      (__attribute__((address_space(1))) void*)(uintptr_t)(const void*)(gsrc),   \
      (__attribute__((address_space(3))) void*)(ldst), 16, 0, 0)

// ---------- conversion kernels ----------
__global__ __launch_bounds__(256) void cvt_kernel(const float* __restrict__ in,
                                                  unsigned short* __restrict__ out, int n4) {
  int i = blockIdx.x * 256 + threadIdx.x;
  if (i < n4) {
    float4 v = ((const float4*)in)[i];
    u16x4_a t = {f2b(v.x), f2b(v.y), f2b(v.z), f2b(v.w)};
    ((u16x4_a*)out)[i] = t;
  }
}

// in: [rows][cols] f32 (batched on z) -> out: [cols][rows] bf16 (*scale)
__global__ __launch_bounds__(256) void transpose_cvt(const float* __restrict__ in,
                                                     unsigned short* __restrict__ out,
                                                     int rows, int cols, float scale) {
  __shared__ float tile[32][33];
  const int tx = threadIdx.x & 31, ty = threadIdx.x >> 5;
  const int c0 = blockIdx.x * 32, r0 = blockIdx.y * 32;
  const float* ip = in + (size_t)blockIdx.z * rows * cols;
  unsigned short* op = out + (size_t)blockIdx.z * rows * cols;
#pragma unroll
  for (int j = 0; j < 32; j += 8)
    tile[ty + j][tx] = ip[(size_t)(r0 + ty + j) * cols + (c0 + tx)];
  __syncthreads();
#pragma unroll
  for (int j = 0; j < 32; j += 8)
    op[(size_t)(c0 + ty + j) * rows + (r0 + tx)] = f2b(tile[tx][ty + j] * scale);
}

__global__ void build_bias_qkv(const float* __restrict__ bq, const float* __restrict__ bk,
                               const float* __restrict__ bv, float* __restrict__ out) {
  int c = blockIdx.x * 256 + threadIdx.x;  // 0..3071
  int which = c >> 10, idx = c & 1023;
  float v = which == 0 ? bq[idx] : (which == 1 ? bk[idx] : bv[idx]);
  // fold 1/sqrt(HD) * log2(e) into q (exp2-domain softmax)
  out[c] = which == 0 ? v * 0.18033688f : v;
}

// ---------- 256x256 8-phase GEMM (m201 template, plain HIP) ----------
// EP 0: QKV scatter + bias (V transposed, packed 8B stores). EP 2: bf16 relu.
// EP 3: f32 raw partial (split-K).
template <int EP>
__global__ __launch_bounds__(512, 2) void gemm256_kernel(
    const unsigned short* __restrict__ A, const unsigned short* __restrict__ Bt,
    int M, int N, int K, int nbx, int KS,
    const float* __restrict__ bias, unsigned short* __restrict__ outb,
    unsigned short* __restrict__ q_out, unsigned short* __restrict__ k_out,
    unsigned short* __restrict__ v_out,
    float* __restrict__ pp0, float* __restrict__ pp1, float* __restrict__ pp2) {
  __shared__ __align__(16) unsigned short sA[2][256 * 64];
  __shared__ __align__(16) unsigned short sB[2][256 * 64];

  const int tid = threadIdx.x;
  const int wid = tid >> 6, lane = tid & 63;
  const int g = lane >> 4, r15 = lane & 15;
  const int wm = wid >> 2, wn = wid & 3;

  const int nwg = gridDim.x, cpx = nwg >> 3, orig = blockIdx.x;
  const int wg = (orig & 7) * cpx + (orig >> 3);
  const int bx = wg % nbx;
  const int t1 = wg / nbx;
  const int kz = t1 % KS, by = t1 / KS;
  const int row0 = by * 256, col0 = bx * 256;

  const int tilesK = K >> 6;
  const int qT = tilesK / KS, rT = tilesK % KS;
  const int tile0 = kz * qT + (kz < rT ? kz : rT);
  const int NT = qT + (kz < rT ? 1 : 0);
  const int kbase = tile0 << 6;

  const unsigned short* gA0 = A + (size_t)row0 * K + kbase;
  const unsigned short* gB0 = Bt + (size_t)col0 * K + kbase;
  const int srow8 = lane >> 3;
  const int schunk = ((lane & 7) ^ srow8) * 8;

  f32x4 acc[8][4] = {};
  bf16x8 af[4][2], bfr[4][2];

  auto stA = [&](int buf, int k0, int i) {
    const int r = wid * 32 + i * 8;
    GLOAD_LDS16(gA0 + (size_t)(r + srow8) * K + k0 + schunk, &sA[buf][r * 64]);
  };
  auto stB = [&](int buf, int k0, int i) {
    const int r = wid * 32 + i * 8;
    GLOAD_LDS16(gB0 + (size_t)(r + srow8) * K + k0 + schunk, &sB[buf][r * 64]);
  };
  auto ldA = [&](const unsigned short* p, int m, int ks) -> bf16x8 {
    const int row = wm * 128 + m * 16 + r15;
    return *(const bf16x8_a*)&p[row * 64 + (((ks * 4 + g) ^ (r15 & 7)) * 8)];
  };
  auto ldB = [&](const unsigned short* p, int n, int ks) -> bf16x8 {
    const int row = wn * 64 + n * 16 + r15;
    return *(const bf16x8_a*)&p[row * 64 + (((ks * 4 + g) ^ (r15 & 7)) * 8)];
  };

#pragma unroll
  for (int i = 0; i < 4; ++i) { stA(0, 0, i); stB(0, 0, i); }
  asm volatile("s_waitcnt vmcnt(0)" ::: "memory");
  __builtin_amdgcn_s_barrier();

  for (int kt = 0; kt < NT; ++kt) {
    const int cb = kt & 1, nb = cb ^ 1;
    const bool pf = (kt + 1) < NT;
    const int k1 = (kt + 1) << 6;
    const unsigned short* pA = sA[cb];
    const unsigned short* pB = sB[cb];

#pragma unroll
    for (int m = 0; m < 4; ++m) { af[m][0] = ldA(pA, m, 0); af[m][1] = ldA(pA, m, 1); }
#pragma unroll
    for (int n = 0; n < 4; ++n) { bfr[n][0] = ldB(pB, n, 0); bfr[n][1] = ldB(pB, n, 1); }
    if (pf) { stA(nb, k1, 0); stA(nb, k1, 1); }
    __builtin_amdgcn_s_barrier();
    asm volatile("s_waitcnt lgkmcnt(0)" ::: "memory");
    __builtin_amdgcn_sched_barrier(0);
    __builtin_amdgcn_s_setprio(1);
#pragma unroll
    for (int m = 0; m < 4; ++m)
#pragma unroll
      for (int n = 0; n < 2; ++n) {
        acc[m][n] = MFMA_B16(af[m][0], bfr[n][0], acc[m][n]);
        acc[m][n] = MFMA_B16(af[m][1], bfr[n][1], acc[m][n]);
      }
    __builtin_amdgcn_s_setprio(0);
    __builtin_amdgcn_s_barrier();

    if (pf) { stA(nb, k1, 2); stA(nb, k1, 3); }
    __builtin_amdgcn_s_barrier();
    __builtin_amdgcn_s_setprio(1);
#pragma unroll
    for (int m = 0; m < 4; ++m)
#pragma unroll
      for (int n = 2; n < 4; ++n) {
        acc[m][n] = MFMA_B16(af[m][0], bfr[n][0], acc[m][n]);
        acc[m][n] = MFMA_B16(af[m][1], bfr[n][1], acc[m][n]);
      }
    __builtin_amdgcn_s_setprio(0);
    __builtin_amdgcn_s_barrier();

#pragma unroll
    for (int m = 0; m < 4; ++m) { af[m][0] = ldA(pA, m + 4, 0); af[m][1] = ldA(pA, m + 4, 1); }
    if (pf) { stB(nb, k1, 0); stB(nb, k1, 1); }
    __builtin_amdgcn_s_barrier();
    asm volatile("s_waitcnt lgkmcnt(0)" ::: "memory");
    __builtin_amdgcn_sched_barrier(0);
    __builtin_amdgcn_s_setprio(1);
#pragma unroll
    for (int m = 0; m < 4; ++m)
#pragma unroll
      for (int n = 0; n < 2; ++n) {
        acc[m + 4][n] = MFMA_B16(af[m][0], bfr[n][0], acc[m + 4][n]);
        acc[m + 4][n] = MFMA_B16(af[m][1], bfr[n][1], acc[m + 4][n]);
      }
    __builtin_amdgcn_s_setprio(0);
    __builtin_amdgcn_s_barrier();

    if (pf) { stB(nb, k1, 2); stB(nb, k1, 3); }
    __builtin_amdgcn_s_barrier();
    __builtin_amdgcn_s_setprio(1);
#pragma unroll
    for (int m = 0; m < 4; ++m)
#pragma unroll
      for (int n = 2; n < 4; ++n) {
        acc[m + 4][n] = MFMA_B16(af[m][0], bfr[n][0], acc[m + 4][n]);
        acc[m + 4][n] = MFMA_B16(af[m][1], bfr[n][1], acc[m + 4][n]);
      }
    __builtin_amdgcn_s_setprio(0);
    asm volatile("s_waitcnt vmcnt(0)" ::: "memory");
    __builtin_amdgcn_s_barrier();
  }

  float* pz = kz == 0 ? pp0 : (kz == 1 ? pp1 : pp2);
#pragma unroll
  for (int m = 0; m < 8; ++m) {
    const int rbase = row0 + wm * 128 + m * 16 + g * 4;
#pragma unroll
    for (int n = 0; n < 4; ++n) {
      const int col = col0 + wn * 64 + n * 16 + r15;
      const float bb = (EP == 3) ? 0.f : bias[col];
      if constexpr (EP == 0) {
        const int which = col >> 10, cc = col & 1023;
        const int hh = cc >> 6, e = cc & 63;
        const int b = rbase >> 11, s0v = rbase & 2047;  // 4 consecutive s, same b
        if (which == 2) {
          // V transposed [bh][e][s]: pack 4 consecutive s -> one 8B store
          bf16x4_a pk;
#pragma unroll
          for (int r = 0; r < 4; ++r) pk[r] = (__bf16)(acc[m][n][r] + bb);
          *(bf16x4_a*)(v_out + (((size_t)(b * 16 + hh) * 64) + e) * 2048 + s0v) = pk;
        } else {
          unsigned short* dst = which == 0 ? q_out : k_out;
#pragma unroll
          for (int r = 0; r < 4; ++r)
            dst[(((size_t)(b * 16 + hh) * 2048) + s0v + r) * 64 + e] =
                f2b(acc[m][n][r] + bb);
        }
      } else {
#pragma unroll
        for (int r = 0; r < 4; ++r) {
          const int row = rbase + r;
          float v = acc[m][n][r] + bb;
          if constexpr (EP == 3) {
            pz[(size_t)row * N + col] = v;
          } else {
            outb[(size_t)row * N + col] = f2b(v > 0.f ? v : 0.f);
          }
        }
      }
    }
  }
}

// ---------- 128x128 GEMM (m97 structure + depth-1 dbuf overlap) ----------
template <int EP>
__global__ __launch_bounds__(256) void gemm_bt_kernel(
    const unsigned short* __restrict__ A, const unsigned short* __restrict__ Bt,
    int M, int N, int K,
    const float* __restrict__ bias, const float* __restrict__ addf,
    float* __restrict__ outf) {
  __shared__ __align__(16) unsigned short sA[2][128 * 32];
  __shared__ __align__(16) unsigned short sB[2][128 * 32];
  const int tid = threadIdx.x;
  const int wid = tid >> 6, lane = tid & 63;
  const int g = lane >> 4, r15 = lane & 15;
  const int wr = wid >> 1, wc = wid & 1;
  const int row0 = blockIdx.y * 128, col0 = blockIdx.x * 128;

  f32x4 acc[4][4] = {};

  const int c0 = wid * 128 + lane;
  const unsigned short* gA0 = A + (size_t)row0 * K;
  const unsigned short* gB0 = Bt + (size_t)col0 * K;

  auto stage = [&](int buf, int k0) {
#pragma unroll
    for (int j = 0; j < 2; ++j) {
      int c = c0 + j * 64;
      GLOAD_LDS16(gA0 + (size_t)(c >> 2) * K + k0 + (c & 3) * 8,
                  &sA[buf][(wid * 128 + j * 64) * 8]);
      GLOAD_LDS16(gB0 + (size_t)(c >> 2) * K + k0 + (c & 3) * 8,
                  &sB[buf][(wid * 128 + j * 64) * 8]);
    }
  };

  stage(0, 0);
  const int NT = K >> 5;
  for (int t = 0; t < NT; ++t) {
    const int cb = t & 1;
    __syncthreads();
    if (t + 1 < NT) stage(cb ^ 1, (t + 1) * 32);
    bf16x8 af[4], bfr[4];
#pragma unroll
    for (int m = 0; m < 4; ++m)
      af[m] = *(const bf16x8_a*)&sA[cb][(wr * 64 + m * 16 + r15) * 32 + g * 8];
#pragma unroll
    for (int n = 0; n < 4; ++n)
      bfr[n] = *(const bf16x8_a*)&sB[cb][(wc * 64 + n * 16 + r15) * 32 + g * 8];
#pragma unroll
    for (int m = 0; m < 4; ++m)
#pragma unroll
      for (int n = 0; n < 4; ++n)
        acc[m][n] = MFMA_B16(af[m], bfr[n], acc[m][n]);
  }

#pragma unroll
  for (int m = 0; m < 4; ++m) {
    const int rbase = row0 + wr * 64 + m * 16 + g * 4;
#pragma unroll
    for (int n = 0; n < 4; ++n) {
      const int col = col0 + wc * 64 + n * 16 + r15;
      const float bb = bias[col];
#pragma unroll
      for (int r = 0; r < 4; ++r) {
        const int row = rbase + r;
        size_t idx = (size_t)row * N + col;
        outf[idx] = acc[m][n][r] + bb + addf[idx];
      }
    }
  }
}

// ---------- flash attention, swapped-operand softmax, exp2 domain ----------
// sP: stride 64 ushorts (128B rows) with 8B-slot XOR swizzle (slot ^= r15&14);
// LDS total 40960B -> 4 blocks/CU.
__global__ __launch_bounds__(256) void attn_kernel(const unsigned short* __restrict__ Q,
                                                   const unsigned short* __restrict__ K,
                                                   const unsigned short* __restrict__ Vt,
                                                   unsigned short* __restrict__ out) {
  const int flat = blockIdx.y * gridDim.x + blockIdx.x;  // 0..1023
  const int xcd = flat & 7, rest = flat >> 3;
  const int bh = xcd * 4 + (rest >> 5);
  const int q0 = (rest & 31) * 64;

  const int tid = threadIdx.x, wid = tid >> 6, lane = tid & 63;
  const int g = lane >> 4, r15 = lane & 15;
  const int h = r15 & 7;
  const int s0 = ((g ^ h) * 8);
  const int s1 = (((g + 4) ^ h) * 8);
  const int pswz = r15 & 14;  // even XOR keeps 16B pairs aligned & ordered

  __shared__ __align__(16) unsigned short sK[2][64 * 64];
  __shared__ __align__(16) unsigned short sV[2][64 * 64];
  __shared__ __align__(16) unsigned short sP[4][16 * 64];

  const size_t base = (size_t)bh * (2048 * 64);
  const unsigned short* Kb = K + base;
  const unsigned short* Vb = Vt + base;

  const int qrow = q0 + wid * 16 + r15;
  bf16x8 qf[2];
  qf[0] = *(const bf16x8_a*)(Q + base + (size_t)qrow * 64 + g * 8);
  qf[1] = *(const bf16x8_a*)(Q + base + (size_t)qrow * 64 + 32 + g * 8);

  const int srow = lane >> 3;
  const int schunk = ((lane & 7) ^ srow) * 8;

  union {
    unsigned short u[8];
    bf16x8 v;
  } ou;
#pragma unroll
  for (int i = 0; i < 8; ++i) ou.u[i] = 0x3F80;
  const bf16x8 onesb = ou.v;

  f32x4 o[4] = {};
  float mrow = -1e30f, lrow = 0.f;

  auto stage = [&](int bufi, int kt0s) {
#pragma unroll
    for (int i = 0; i < 2; ++i) {
      const int inst = wid * 2 + i;
      const int row = 8 * inst + srow;
      GLOAD_LDS16(Kb + (size_t)(kt0s + row) * 64 + schunk, &sK[bufi][inst * 512]);
      GLOAD_LDS16(Vb + (size_t)row * 2048 + kt0s + schunk, &sV[bufi][inst * 512]);
    }
  };

  stage(0, 0);

  for (int t = 0; t < 32; ++t) {
    const int cur = t & 1;
    __syncthreads();
    if (t < 31) stage(cur ^ 1, (t + 1) * 64);

    // scores (exp2-domain: log2e/sqrt(HD) folded into Q)
    f32x4 sc[4] = {};
#pragma unroll
    for (int kt = 0; kt < 4; ++kt) {
      const int rb = (kt * 16 + r15) * 64;
      bf16x8 kf0 = *(const bf16x8_a*)&sK[cur][rb + s0];
      bf16x8 kf1 = *(const bf16x8_a*)&sK[cur][rb + s1];
      sc[kt] = MFMA_B16(kf0, qf[0], sc[kt]);
      sc[kt] = MFMA_B16(kf1, qf[1], sc[kt]);
    }

    // tree max (depth 4) + 2 cross-group shuffles
    float t0 = fmaxf(fmaxf(sc[0][0], sc[0][1]), fmaxf(sc[0][2], sc[0][3]));
    float t1 = fmaxf(fmaxf(sc[1][0], sc[1][1]), fmaxf(sc[1][2], sc[1][3]));
    float t2 = fmaxf(fmaxf(sc[2][0], sc[2][1]), fmaxf(sc[2][2], sc[2][3]));
    float t3 = fmaxf(fmaxf(sc[3][0], sc[3][1]), fmaxf(sc[3][2], sc[3][3]));
    float pmax = fmaxf(fmaxf(t0, t1), fmaxf(t2, t3));
    pmax = fmaxf(pmax, __shfl_xor(pmax, 16));
    pmax = fmaxf(pmax, __shfl_xor(pmax, 32));

    // defer-max: bound 2^11.544 = e^8
    const bool allkeep = __all(pmax - mrow <= 11.5441f);
    float fac;
    if (allkeep) {
      fac = 1.0f;
    } else {
      float nm = fmaxf(mrow, pmax);
      fac = EXP2(mrow - nm);
      mrow = nm;
#pragma unroll
      for (int dt = 0; dt < 4; ++dt)
#pragma unroll
        for (int r = 0; r < 4; ++r) o[dt][r] *= fac;
    }

    // P = exp2(S - m); 8B store to swizzled slot (4kt+g)^pswz
#pragma unroll
    for (int kt = 0; kt < 4; ++kt) {
      bf16x4_a pb;
      pb[0] = (__bf16)EXP2(sc[kt][0] - mrow);
      pb[1] = (__bf16)EXP2(sc[kt][1] - mrow);
      pb[2] = (__bf16)EXP2(sc[kt][2] - mrow);
      pb[3] = (__bf16)EXP2(sc[kt][3] - mrow);
      *(bf16x4_a*)&sP[wid][r15 * 64 + (((4 * kt + g) ^ pswz) << 2)] = pb;
    }

    // P^T B-fragments: slots {2g,2g+1}^pswz and {8+2g,8+2g+1}^pswz (16B aligned)
    bf16x8 pf0 = *(const bf16x8_a*)&sP[wid][r15 * 64 + (((2 * g) ^ pswz) << 2)];
    bf16x8 pf1 = *(const bf16x8_a*)&sP[wid][r15 * 64 + (((8 + 2 * g) ^ pswz) << 2)];

    f32x4 lacc = {};
    lacc = MFMA_B16(onesb, pf0, lacc);
    lacc = MFMA_B16(onesb, pf1, lacc);
    lrow = lrow * fac + lacc[0];

#pragma unroll
    for (int dt = 0; dt < 4; ++dt) {
      const int rb = (dt * 16 + r15) * 64;
      bf16x8 vf0 = *(const bf16x8_a*)&sV[cur][rb + s0];
      bf16x8 vf1 = *(const bf16x8_a*)&sV[cur][rb + s1];
      o[dt] = MFMA_B16(vf0, pf0, o[dt]);
      o[dt] = MFMA_B16(vf1, pf1, o[dt]);
    }
  }

  const int b = bh >> 4, hh = bh & 15;
  const int s = q0 + wid * 16 + r15;
  const float inv = 1.f / lrow;
  unsigned short* orow = out + ((size_t)(b * 2048 + s)) * 1024 + hh * 64;
#pragma unroll
  for (int dt = 0; dt < 4; ++dt) {
    bf16x4_a tq;
    tq[0] = (__bf16)(o[dt][0] * inv);
    tq[1] = (__bf16)(o[dt][1] * inv);
    tq[2] = (__bf16)(o[dt][2] * inv);
    tq[3] = (__bf16)(o[dt][3] * inv);
    *(bf16x4_a*)(orow + dt * 16 + g * 4) = tq;
  }
}

// ---------- LayerNorm over 1024 cols; optional f32 and bf16 outputs ----------
__global__ __launch_bounds__(256) void ln_kernel(const float* __restrict__ in,
                                                 const float* __restrict__ gamma,
                                                 const float* __restrict__ beta,
                                                 float* __restrict__ outf,
                                                 unsigned short* __restrict__ outb) {
  const int row = blockIdx.x, tid = threadIdx.x;
  float4 v = ((const float4*)(in + (size_t)row * 1024))[tid];
  float s = v.x + v.y + v.z + v.w;
  float ss = v.x * v.x + v.y * v.y + v.z * v.z + v.w * v.w;
#pragma unroll
  for (int off = 32; off > 0; off >>= 1) {
    s += __shfl_down(s, off);
    ss += __shfl_down(ss, off);
  }
  __shared__ float red[8];
  const int wid = tid >> 6;
  if ((tid & 63) == 0) { red[wid] = s; red[4 + wid] = ss; }
  __syncthreads();
  float S = red[0] + red[1] + red[2] + red[3];
  float SS = red[4] + red[5] + red[6] + red[7];
  const float mean = S * (1.f / 1024.f);
  const float var = SS * (1.f / 1024.f) - mean * mean;
  const float inv = 1.f / sqrtf(var + 1e-10f);
  float4 gg = ((const float4*)gamma)[tid];
  float4 bb = ((const float4*)beta)[tid];
  float4 o;
  o.x = (v.x - mean) * inv * gg.x + bb.x;
  o.y = (v.y - mean) * inv * gg.y + bb.y;
  o.z = (v.z - mean) * inv * gg.z + bb.z;
  o.w = (v.w - mean) * inv * gg.w + bb.w;
  if (outf) ((float4*)(outf + (size_t)row * 1024))[tid] = o;
  if (outb) {
    u16x4_a t = {f2b(o.x), f2b(o.y), f2b(o.z), f2b(o.w)};
    *(u16x4_a*)(outb + (size_t)row * 1024 + tid * 4) = t;
  }
}

// ---------- fused split-K reduce + bias + residual + LayerNorm -> f32 out ----------
__global__ __launch_bounds__(256) void ln3_kernel(
    const float* __restrict__ p0, const float* __restrict__ p1, const float* __restrict__ p2,
    const float* __restrict__ bias, const float* __restrict__ resid,
    const float* __restrict__ gamma, const float* __restrict__ beta,
    float* __restrict__ outf) {
  const int row = blockIdx.x, tid = threadIdx.x;
  const size_t off = (size_t)row * 1024;
  float4 a = ((const float4*)(p0 + off))[tid];
  float4 b = ((const float4*)(p1 + off))[tid];
  float4 c = ((const float4*)(p2 + off))[tid];
  float4 bb4 = ((const float4*)bias)[tid];
  float4 rr = ((const float4*)(resid + off))[tid];
  float4 v;
  v.x = a.x + b.x + c.x + bb4.x + rr.x;
  v.y = a.y + b.y + c.y + bb4.y + rr.y;
  v.z = a.z + b.z + c.z + bb4.z + rr.z;
  v.w = a.w + b.w + c.w + bb4.w + rr.w;

  float s = v.x + v.y + v.z + v.w;
  float ss = v.x * v.x + v.y * v.y + v.z * v.z + v.w * v.w;
#pragma unroll
  for (int off2 = 32; off2 > 0; off2 >>= 1) {
    s += __shfl_down(s, off2);
    ss += __shfl_down(ss, off2);
  }
  __shared__ float red[8];
  const int wid = tid >> 6;
  if ((tid & 63) == 0) { red[wid] = s; red[4 + wid] = ss; }
  __syncthreads();
  float S = red[0] + red[1] + red[2] + red[3];
  float SS = red[4] + red[5] + red[6] + red[7];
  const float mean = S * (1.f / 1024.f);
  const float var = SS * (1.f / 1024.f) - mean * mean;
  const float inv = 1.f / sqrtf(var + 1e-10f);
  float4 gg = ((const float4*)gamma)[tid];
  float4 be = ((const float4*)beta)[tid];
  float4 o;
  o.x = (v.x - mean) * inv * gg.x + be.x;
  o.y = (v.y - mean) * inv * gg.y + be.y;
  o.z = (v.z - mean) * inv * gg.z + be.z;
  o.w = (v.w - mean) * inv * gg.w + be.w;
  ((float4*)(outf + off))[tid] = o;
}

// ---------- launch ----------
extern "C" void kernel_launch(void* const* d_in, const int* in_sizes, int n_in,
                              void* d_out, int out_size, void* d_ws, size_t ws_size,
                              hipStream_t stream) {
  const float* x      = (const float*)d_in[0];
  const float* wq     = (const float*)d_in[1];
  const float* bq     = (const float*)d_in[2];
  const float* wk     = (const float*)d_in[3];
  const float* bk     = (const float*)d_in[4];
  const float* wv     = (const float*)d_in[5];
  const float* bv     = (const float*)d_in[6];
  const float* w_proj = (const float*)d_in[7];
  const float* b_proj = (const float*)d_in[8];
  const float* gamma1 = (const float*)d_in[9];
  const float* beta1  = (const float*)d_in[10];
  const float* w1     = (const float*)d_in[11];
  const float* b1     = (const float*)d_in[12];
  const float* w2     = (const float*)d_in[13];
  const float* b2     = (const float*)d_in[14];
  const float* gamma2 = (const float*)d_in[15];
  const float* beta2  = (const float*)d_in[16];

  char* p = (char*)d_ws;
  auto alloc = [&](size_t bytes) {
    char* r = p;
    p += (bytes + 255) & ~(size_t)255;
    return r;
  };
  unsigned short* xb      = (unsigned short*)alloc(4096ull * 1024 * 2);  // dead after proj
  unsigned short* Wqkv_t  = (unsigned short*)alloc(3072ull * 1024 * 2);  // dead after QKV
  unsigned short* Wproj_t = (unsigned short*)alloc(1024ull * 1024 * 2);  // dead after proj
  unsigned short* W1t     = (unsigned short*)alloc(4096ull * 1024 * 2);  // dead after FFN1
  unsigned short* W2t     = (unsigned short*)alloc(1024ull * 4096 * 2);  // live thru FFN2
  float*          biasq   = (float*)alloc(3072 * 4);
  unsigned short* Qb      = (unsigned short*)alloc(4096ull * 1024 * 2);  // dead after attn
  unsigned short* Kb      = (unsigned short*)alloc(4096ull * 1024 * 2);  // dead after attn
  unsigned short* Vtb     = (unsigned short*)alloc(4096ull * 1024 * 2);  // dead after attn
  float*          resid1  = (float*)alloc(4096ull * 1024 * 4);           // dead after LN1
  float*          out1f   = (float*)alloc(4096ull * 1024 * 4);           // live thru ln3
  unsigned short* out1b   = (unsigned short*)alloc(4096ull * 1024 * 2);  // dead after FFN1
  unsigned short* ffn_h   = (unsigned short*)alloc(4096ull * 4096 * 2);  // live thru FFN2
  unsigned short* concat  = xb;

  // FFN2 split-K=3 partials: 3 x 16MB in regions dead by FFN2 launch time.
  float* pp0 = (float*)xb;   // xb+Wqkv_t+Wproj_t = 16MB contiguous
  float* pp1 = (float*)Qb;   // Qb+Kb = 16MB contiguous
  float* pp2 = (float*)Vtb;  // Vtb+resid1 first 8MB = 16MB contiguous

  cvt_kernel<<<4096, 256, 0, stream>>>(x, xb, 4096 * 1024 / 4);
  // q weights carry 1/sqrt(HD)*log2(e) for exp2-domain softmax
  transpose_cvt<<<dim3(2, 32, 16), 256, 0, stream>>>(wq, Wqkv_t, 1024, 64, 0.18033688f);
  transpose_cvt<<<dim3(2, 32, 16), 256, 0, stream>>>(wk, Wqkv_t + 1024 * 1024, 1024, 64, 1.f);
  transpose_cvt<<<dim3(2, 32, 16), 256, 0, stream>>>(wv, Wqkv_t + 2048 * 1024, 1024, 64, 1.f);
  transpose_cvt<<<dim3(32, 32, 1), 256, 0, stream>>>(w_proj, Wproj_t, 1024, 1024, 1.f);
  transpose_cvt<<<dim3(128, 32, 1), 256, 0, stream>>>(w1, W1t, 1024, 4096, 1.f);
  transpose_cvt<<<dim3(32, 128, 1), 256, 0, stream>>>(w2, W2t, 4096, 1024, 1.f);
  build_bias_qkv<<<12, 256, 0, stream>>>(bq, bk, bv, biasq);

  gemm256_kernel<0><<<192, 512, 0, stream>>>(xb, Wqkv_t, 4096, 3072, 1024, 12, 1, biasq,
                                             nullptr, Qb, Kb, Vtb, nullptr, nullptr, nullptr);
  attn_kernel<<<dim3(32, 32), 256, 0, stream>>>(Qb, Kb, Vtb, concat);
  gemm_bt_kernel<1><<<dim3(8, 32), 256, 0, stream>>>(concat, Wproj_t, 4096, 1024, 1024, b_proj,
                                                     x, resid1);
  ln_kernel<<<4096, 256, 0, stream>>>(resid1, gamma1, beta1, out1f, out1b);
  gemm256_kernel<2><<<256, 512, 0, stream>>>(out1b, W1t, 4096, 4096, 1024, 16, 1, b1,
                                             ffn_h, nullptr, nullptr, nullptr,
                                             nullptr, nullptr, nullptr);
  gemm256_kernel<3><<<192, 512, 0, stream>>>(ffn_h, W2t, 4096, 1024, 4096, 4, 3, nullptr,
                                             nullptr, nullptr, nullptr, nullptr,
                                             pp0, pp1, pp2);
  ln3_kernel<<<4096, 256, 0, stream>>>(pp0, pp1, pp2, b2, out1f, gamma2, beta2,
                                       (float*)d_out);
}

// Round 9
// 263.617 us; speedup vs baseline: 1.9687x; 1.0209x over previous
//
#include <hip/hip_runtime.h>
#include <stdint.h>

// ---------- types ----------
typedef float f32x4 __attribute__((ext_vector_type(4)));
typedef __bf16 bf16x8 __attribute__((ext_vector_type(8)));
typedef __bf16 bf16x8_a __attribute__((ext_vector_type(8), may_alias));
typedef __bf16 bf16x4_a __attribute__((ext_vector_type(4), may_alias));
typedef unsigned int u32x4_a __attribute__((ext_vector_type(4), may_alias));
typedef unsigned short u16x4_a __attribute__((ext_vector_type(4), may_alias));

#define DEV __device__ __forceinline__
#define MFMA_B16(a, b, c) __builtin_amdgcn_mfma_f32_16x16x32_bf16((a), (b), (c), 0, 0, 0)

#if __has_builtin(__builtin_amdgcn_exp2f)
#define EXP2(x) __builtin_amdgcn_exp2f(x)
#else
#define EXP2(x) exp2f(x)
#endif

DEV unsigned short f2b(float f) {  // f32 -> bf16 RNE
  unsigned int u = __float_as_uint(f);
  u = u + 0x7FFFu + ((u >> 16) & 1u);
  return (unsigned short)(u >> 16);
}

// async global->LDS, 16B per lane; LDS dest is wave-uniform base + lane*16
#define GLOAD_LDS16(gsrc, ldst)                                                  \
  __builtin_amdgcn_global_load_lds(                                              \
      (__attribute__((address_space(1))) void*)(uintptr_t)(const void*)(gsrc),   \
      (__attribute__((address_space(3))) void*)(ldst), 16, 0, 0)

// ---------- conversion kernels ----------
__global__ __launch_bounds__(256) void cvt_kernel(const float* __restrict__ in,
                                                  unsigned short* __restrict__ out, int n4) {
  int i = blockIdx.x * 256 + threadIdx.x;
  if (i < n4) {
    float4 v = ((const float4*)in)[i];
    u16x4_a t = {f2b(v.x), f2b(v.y), f2b(v.z), f2b(v.w)};
    ((u16x4_a*)out)[i] = t;
  }
}

// in: [rows][cols] f32 (batched on z) -> out: [cols][rows] bf16 (*scale)
__global__ __launch_bounds__(256) void transpose_cvt(const float* __restrict__ in,
                                                     unsigned short* __restrict__ out,
                                                     int rows, int cols, float scale) {
  __shared__ float tile[32][33];
  const int tx = threadIdx.x & 31, ty = threadIdx.x >> 5;
  const int c0 = blockIdx.x * 32, r0 = blockIdx.y * 32;
  const float* ip = in + (size_t)blockIdx.z * rows * cols;
  unsigned short* op = out + (size_t)blockIdx.z * rows * cols;
#pragma unroll
  for (int j = 0; j < 32; j += 8)
    tile[ty + j][tx] = ip[(size_t)(r0 + ty + j) * cols + (c0 + tx)];
  __syncthreads();
#pragma unroll
  for (int j = 0; j < 32; j += 8)
    op[(size_t)(c0 + ty + j) * rows + (r0 + tx)] = f2b(tile[tx][ty + j] * scale);
}

__global__ void build_bias_qkv(const float* __restrict__ bq, const float* __restrict__ bk,
                               const float* __restrict__ bv, float* __restrict__ out) {
  int c = blockIdx.x * 256 + threadIdx.x;  // 0..3071
  int which = c >> 10, idx = c & 1023;
  float v = which == 0 ? bq[idx] : (which == 1 ? bk[idx] : bv[idx]);
  // fold 1/sqrt(HD) * log2(e) into q (exp2-domain softmax)
  out[c] = which == 0 ? v * 0.18033688f : v;
}

// ---------- 256x256 8-phase GEMM (m201 template, plain HIP) ----------
// EP 0: QKV scatter + bias (V transposed, packed 8B stores). EP 2: bf16 relu.
// EP 3: f32 raw partial (split-K, buffer by kz).
template <int EP>
__global__ __launch_bounds__(512, 2) void gemm256_kernel(
    const unsigned short* __restrict__ A, const unsigned short* __restrict__ Bt,
    int M, int N, int K, int nbx, int KS,
    const float* __restrict__ bias, unsigned short* __restrict__ outb,
    unsigned short* __restrict__ q_out, unsigned short* __restrict__ k_out,
    unsigned short* __restrict__ v_out,
    float* __restrict__ pp0, float* __restrict__ pp1, float* __restrict__ pp2,
    float* __restrict__ pp3) {
  __shared__ __align__(16) unsigned short sA[2][256 * 64];
  __shared__ __align__(16) unsigned short sB[2][256 * 64];

  const int tid = threadIdx.x;
  const int wid = tid >> 6, lane = tid & 63;
  const int g = lane >> 4, r15 = lane & 15;
  const int wm = wid >> 2, wn = wid & 3;

  const int nwg = gridDim.x, cpx = nwg >> 3, orig = blockIdx.x;
  const int wg = (orig & 7) * cpx + (orig >> 3);
  const int bx = wg % nbx;
  const int t1 = wg / nbx;
  const int kz = t1 % KS, by = t1 / KS;
  const int row0 = by * 256, col0 = bx * 256;

  const int tilesK = K >> 6;
  const int qT = tilesK / KS, rT = tilesK % KS;
  const int tile0 = kz * qT + (kz < rT ? kz : rT);
  const int NT = qT + (kz < rT ? 1 : 0);
  const int kbase = tile0 << 6;

  const unsigned short* gA0 = A + (size_t)row0 * K + kbase;
  const unsigned short* gB0 = Bt + (size_t)col0 * K + kbase;
  const int srow8 = lane >> 3;
  const int schunk = ((lane & 7) ^ srow8) * 8;

  f32x4 acc[8][4] = {};
  bf16x8 af[4][2], bfr[4][2];

  auto stA = [&](int buf, int k0, int i) {
    const int r = wid * 32 + i * 8;
    GLOAD_LDS16(gA0 + (size_t)(r + srow8) * K + k0 + schunk, &sA[buf][r * 64]);
  };
  auto stB = [&](int buf, int k0, int i) {
    const int r = wid * 32 + i * 8;
    GLOAD_LDS16(gB0 + (size_t)(r + srow8) * K + k0 + schunk, &sB[buf][r * 64]);
  };
  auto ldA = [&](const unsigned short* p, int m, int ks) -> bf16x8 {
    const int row = wm * 128 + m * 16 + r15;
    return *(const bf16x8_a*)&p[row * 64 + (((ks * 4 + g) ^ (r15 & 7)) * 8)];
  };
  auto ldB = [&](const unsigned short* p, int n, int ks) -> bf16x8 {
    const int row = wn * 64 + n * 16 + r15;
    return *(const bf16x8_a*)&p[row * 64 + (((ks * 4 + g) ^ (r15 & 7)) * 8)];
  };

#pragma unroll
  for (int i = 0; i < 4; ++i) { stA(0, 0, i); stB(0, 0, i); }
  asm volatile("s_waitcnt vmcnt(0)" ::: "memory");
  __builtin_amdgcn_s_barrier();

  for (int kt = 0; kt < NT; ++kt) {
    const int cb = kt & 1, nb = cb ^ 1;
    const bool pf = (kt + 1) < NT;
    const int k1 = (kt + 1) << 6;
    const unsigned short* pA = sA[cb];
    const unsigned short* pB = sB[cb];

#pragma unroll
    for (int m = 0; m < 4; ++m) { af[m][0] = ldA(pA, m, 0); af[m][1] = ldA(pA, m, 1); }
#pragma unroll
    for (int n = 0; n < 4; ++n) { bfr[n][0] = ldB(pB, n, 0); bfr[n][1] = ldB(pB, n, 1); }
    if (pf) { stA(nb, k1, 0); stA(nb, k1, 1); }
    __builtin_amdgcn_s_barrier();
    asm volatile("s_waitcnt lgkmcnt(0)" ::: "memory");
    __builtin_amdgcn_sched_barrier(0);
    __builtin_amdgcn_s_setprio(1);
#pragma unroll
    for (int m = 0; m < 4; ++m)
#pragma unroll
      for (int n = 0; n < 2; ++n) {
        acc[m][n] = MFMA_B16(af[m][0], bfr[n][0], acc[m][n]);
        acc[m][n] = MFMA_B16(af[m][1], bfr[n][1], acc[m][n]);
      }
    __builtin_amdgcn_s_setprio(0);
    __builtin_amdgcn_s_barrier();

    if (pf) { stA(nb, k1, 2); stA(nb, k1, 3); }
    __builtin_amdgcn_s_barrier();
    __builtin_amdgcn_s_setprio(1);
#pragma unroll
    for (int m = 0; m < 4; ++m)
#pragma unroll
      for (int n = 2; n < 4; ++n) {
        acc[m][n] = MFMA_B16(af[m][0], bfr[n][0], acc[m][n]);
        acc[m][n] = MFMA_B16(af[m][1], bfr[n][1], acc[m][n]);
      }
    __builtin_amdgcn_s_setprio(0);
    __builtin_amdgcn_s_barrier();

#pragma unroll
    for (int m = 0; m < 4; ++m) { af[m][0] = ldA(pA, m + 4, 0); af[m][1] = ldA(pA, m + 4, 1); }
    if (pf) { stB(nb, k1, 0); stB(nb, k1, 1); }
    __builtin_amdgcn_s_barrier();
    asm volatile("s_waitcnt lgkmcnt(0)" ::: "memory");
    __builtin_amdgcn_sched_barrier(0);
    __builtin_amdgcn_s_setprio(1);
#pragma unroll
    for (int m = 0; m < 4; ++m)
#pragma unroll
      for (int n = 0; n < 2; ++n) {
        acc[m + 4][n] = MFMA_B16(af[m][0], bfr[n][0], acc[m + 4][n]);
        acc[m + 4][n] = MFMA_B16(af[m][1], bfr[n][1], acc[m + 4][n]);
      }
    __builtin_amdgcn_s_setprio(0);
    __builtin_amdgcn_s_barrier();

    if (pf) { stB(nb, k1, 2); stB(nb, k1, 3); }
    __builtin_amdgcn_s_barrier();
    __builtin_amdgcn_s_setprio(1);
#pragma unroll
    for (int m = 0; m < 4; ++m)
#pragma unroll
      for (int n = 2; n < 4; ++n) {
        acc[m + 4][n] = MFMA_B16(af[m][0], bfr[n][0], acc[m + 4][n]);
        acc[m + 4][n] = MFMA_B16(af[m][1], bfr[n][1], acc[m + 4][n]);
      }
    __builtin_amdgcn_s_setprio(0);
    asm volatile("s_waitcnt vmcnt(0)" ::: "memory");
    __builtin_amdgcn_s_barrier();
  }

  float* pz = kz == 0 ? pp0 : (kz == 1 ? pp1 : (kz == 2 ? pp2 : pp3));
#pragma unroll
  for (int m = 0; m < 8; ++m) {
    const int rbase = row0 + wm * 128 + m * 16 + g * 4;
#pragma unroll
    for (int n = 0; n < 4; ++n) {
      const int col = col0 + wn * 64 + n * 16 + r15;
      const float bb = (EP == 3) ? 0.f : bias[col];
      if constexpr (EP == 0) {
        const int which = col >> 10, cc = col & 1023;
        const int hh = cc >> 6, e = cc & 63;
        const int b = rbase >> 11, s0v = rbase & 2047;  // 4 consecutive s, same b
        if (which == 2) {
          bf16x4_a pk;
#pragma unroll
          for (int r = 0; r < 4; ++r) pk[r] = (__bf16)(acc[m][n][r] + bb);
          *(bf16x4_a*)(v_out + (((size_t)(b * 16 + hh) * 64) + e) * 2048 + s0v) = pk;
        } else {
          unsigned short* dst = which == 0 ? q_out : k_out;
#pragma unroll
          for (int r = 0; r < 4; ++r)
            dst[(((size_t)(b * 16 + hh) * 2048) + s0v + r) * 64 + e] =
                f2b(acc[m][n][r] + bb);
        }
      } else {
#pragma unroll
        for (int r = 0; r < 4; ++r) {
          const int row = rbase + r;
          float v = acc[m][n][r] + bb;
          if constexpr (EP == 3) {
            pz[(size_t)row * N + col] = v;
          } else {
            outb[(size_t)row * N + col] = f2b(v > 0.f ? v : 0.f);
          }
        }
      }
    }
  }
}

// ---------- 128x128 GEMM, split-K over blockIdx.z, raw f32 partial out ----------
__global__ __launch_bounds__(256) void gemm_bt_kernel(
    const unsigned short* __restrict__ A, const unsigned short* __restrict__ Bt,
    int M, int N, int Kchunk, int Kstride,
    float* __restrict__ pp0, float* __restrict__ pp1) {
  __shared__ __align__(16) unsigned short sA[2][128 * 32];
  __shared__ __align__(16) unsigned short sB[2][128 * 32];
  const int tid = threadIdx.x;
  const int wid = tid >> 6, lane = tid & 63;
  const int g = lane >> 4, r15 = lane & 15;
  const int wr = wid >> 1, wc = wid & 1;
  const int row0 = blockIdx.y * 128, col0 = blockIdx.x * 128;
  const int kz = blockIdx.z;

  f32x4 acc[4][4] = {};

  const int c0 = wid * 128 + lane;
  const unsigned short* gA0 = A + (size_t)row0 * Kstride + (size_t)kz * Kchunk;
  const unsigned short* gB0 = Bt + (size_t)col0 * Kstride + (size_t)kz * Kchunk;

  auto stage = [&](int buf, int k0) {
#pragma unroll
    for (int j = 0; j < 2; ++j) {
      int c = c0 + j * 64;
      GLOAD_LDS16(gA0 + (size_t)(c >> 2) * Kstride + k0 + (c & 3) * 8,
                  &sA[buf][(wid * 128 + j * 64) * 8]);
      GLOAD_LDS16(gB0 + (size_t)(c >> 2) * Kstride + k0 + (c & 3) * 8,
                  &sB[buf][(wid * 128 + j * 64) * 8]);
    }
  };

  stage(0, 0);
  const int NT = Kchunk >> 5;
  for (int t = 0; t < NT; ++t) {
    const int cb = t & 1;
    __syncthreads();
    if (t + 1 < NT) stage(cb ^ 1, (t + 1) * 32);
    bf16x8 af[4], bfr[4];
#pragma unroll
    for (int m = 0; m < 4; ++m)
      af[m] = *(const bf16x8_a*)&sA[cb][(wr * 64 + m * 16 + r15) * 32 + g * 8];
#pragma unroll
    for (int n = 0; n < 4; ++n)
      bfr[n] = *(const bf16x8_a*)&sB[cb][(wc * 64 + n * 16 + r15) * 32 + g * 8];
#pragma unroll
    for (int m = 0; m < 4; ++m)
#pragma unroll
      for (int n = 0; n < 4; ++n)
        acc[m][n] = MFMA_B16(af[m], bfr[n], acc[m][n]);
  }

  float* pz = kz == 0 ? pp0 : pp1;
#pragma unroll
  for (int m = 0; m < 4; ++m) {
    const int rbase = row0 + wr * 64 + m * 16 + g * 4;
#pragma unroll
    for (int n = 0; n < 4; ++n) {
      const int col = col0 + wc * 64 + n * 16 + r15;
#pragma unroll
      for (int r = 0; r < 4; ++r)
        pz[(size_t)(rbase + r) * N + col] = acc[m][n][r];
    }
  }
}

// ---------- flash attention, swapped-operand softmax, exp2 domain ----------
__global__ __launch_bounds__(256) void attn_kernel(const unsigned short* __restrict__ Q,
                                                   const unsigned short* __restrict__ K,
                                                   const unsigned short* __restrict__ Vt,
                                                   unsigned short* __restrict__ out) {
  const int flat = blockIdx.y * gridDim.x + blockIdx.x;  // 0..1023
  const int xcd = flat & 7, rest = flat >> 3;
  const int bh = xcd * 4 + (rest >> 5);
  const int q0 = (rest & 31) * 64;

  const int tid = threadIdx.x, wid = tid >> 6, lane = tid & 63;
  const int g = lane >> 4, r15 = lane & 15;
  const int h = r15 & 7;
  const int s0 = ((g ^ h) * 8);
  const int s1 = (((g + 4) ^ h) * 8);
  const int pswz = r15 & 14;

  __shared__ __align__(16) unsigned short sK[2][64 * 64];
  __shared__ __align__(16) unsigned short sV[2][64 * 64];
  __shared__ __align__(16) unsigned short sP[4][16 * 64];

  const size_t base = (size_t)bh * (2048 * 64);
  const unsigned short* Kb = K + base;
  const unsigned short* Vb = Vt + base;

  const int qrow = q0 + wid * 16 + r15;
  bf16x8 qf[2];
  qf[0] = *(const bf16x8_a*)(Q + base + (size_t)qrow * 64 + g * 8);
  qf[1] = *(const bf16x8_a*)(Q + base + (size_t)qrow * 64 + 32 + g * 8);

  const int srow = lane >> 3;
  const int schunk = ((lane & 7) ^ srow) * 8;

  union {
    unsigned short u[8];
    bf16x8 v;
  } ou;
#pragma unroll
  for (int i = 0; i < 8; ++i) ou.u[i] = 0x3F80;
  const bf16x8 onesb = ou.v;

  f32x4 o[4] = {};
  float mrow = -1e30f, lrow = 0.f;

  auto stage = [&](int bufi, int kt0s) {
#pragma unroll
    for (int i = 0; i < 2; ++i) {
      const int inst = wid * 2 + i;
      const int row = 8 * inst + srow;
      GLOAD_LDS16(Kb + (size_t)(kt0s + row) * 64 + schunk, &sK[bufi][inst * 512]);
      GLOAD_LDS16(Vb + (size_t)row * 2048 + kt0s + schunk, &sV[bufi][inst * 512]);
    }
  };

  stage(0, 0);

  for (int t = 0; t < 32; ++t) {
    const int cur = t & 1;
    __syncthreads();
    if (t < 31) stage(cur ^ 1, (t + 1) * 64);

    f32x4 sc[4] = {};
#pragma unroll
    for (int kt = 0; kt < 4; ++kt) {
      const int rb = (kt * 16 + r15) * 64;
      bf16x8 kf0 = *(const bf16x8_a*)&sK[cur][rb + s0];
      bf16x8 kf1 = *(const bf16x8_a*)&sK[cur][rb + s1];
      sc[kt] = MFMA_B16(kf0, qf[0], sc[kt]);
      sc[kt] = MFMA_B16(kf1, qf[1], sc[kt]);
    }

    // max via nested triples (clang fuses to v_max3): 8 ops, depth 3
    float a0 = fmaxf(fmaxf(sc[0][0], sc[0][1]), sc[0][2]);
    float a1 = fmaxf(fmaxf(sc[0][3], sc[1][0]), sc[1][1]);
    float a2 = fmaxf(fmaxf(sc[1][2], sc[1][3]), sc[2][0]);
    float a3 = fmaxf(fmaxf(sc[2][1], sc[2][2]), sc[2][3]);
    float a4 = fmaxf(fmaxf(sc[3][0], sc[3][1]), sc[3][2]);
    float b0 = fmaxf(fmaxf(a0, a1), a2);
    float b1 = fmaxf(fmaxf(a3, a4), sc[3][3]);
    float pmax = fmaxf(b0, b1);
    pmax = fmaxf(pmax, __shfl_xor(pmax, 16));
    pmax = fmaxf(pmax, __shfl_xor(pmax, 32));

    const bool allkeep = __all(pmax - mrow <= 11.5441f);
    float fac;
    if (allkeep) {
      fac = 1.0f;
    } else {
      float nm = fmaxf(mrow, pmax);
      fac = EXP2(mrow - nm);
      mrow = nm;
#pragma unroll
      for (int dt = 0; dt < 4; ++dt)
#pragma unroll
        for (int r = 0; r < 4; ++r) o[dt][r] *= fac;
    }

#pragma unroll
    for (int kt = 0; kt < 4; ++kt) {
      bf16x4_a pb;
      pb[0] = (__bf16)EXP2(sc[kt][0] - mrow);
      pb[1] = (__bf16)EXP2(sc[kt][1] - mrow);
      pb[2] = (__bf16)EXP2(sc[kt][2] - mrow);
      pb[3] = (__bf16)EXP2(sc[kt][3] - mrow);
      *(bf16x4_a*)&sP[wid][r15 * 64 + (((4 * kt + g) ^ pswz) << 2)] = pb;
    }

    bf16x8 pf0 = *(const bf16x8_a*)&sP[wid][r15 * 64 + (((2 * g) ^ pswz) << 2)];
    bf16x8 pf1 = *(const bf16x8_a*)&sP[wid][r15 * 64 + (((8 + 2 * g) ^ pswz) << 2)];

    f32x4 lacc = {};
    lacc = MFMA_B16(onesb, pf0, lacc);
    lacc = MFMA_B16(onesb, pf1, lacc);
    lrow = lrow * fac + lacc[0];

#pragma unroll
    for (int dt = 0; dt < 4; ++dt) {
      const int rb = (dt * 16 + r15) * 64;
      bf16x8 vf0 = *(const bf16x8_a*)&sV[cur][rb + s0];
      bf16x8 vf1 = *(const bf16x8_a*)&sV[cur][rb + s1];
      o[dt] = MFMA_B16(vf0, pf0, o[dt]);
      o[dt] = MFMA_B16(vf1, pf1, o[dt]);
    }
  }

  const int b = bh >> 4, hh = bh & 15;
  const int s = q0 + wid * 16 + r15;
  const float inv = 1.f / lrow;
  unsigned short* orow = out + ((size_t)(b * 2048 + s)) * 1024 + hh * 64;
#pragma unroll
  for (int dt = 0; dt < 4; ++dt) {
    bf16x4_a tq;
    tq[0] = (__bf16)(o[dt][0] * inv);
    tq[1] = (__bf16)(o[dt][1] * inv);
    tq[2] = (__bf16)(o[dt][2] * inv);
    tq[3] = (__bf16)(o[dt][3] * inv);
    *(bf16x4_a*)(orow + dt * 16 + g * 4) = tq;
  }
}

// ---------- fused 2-partial reduce + bias + residual + LN -> f32 + bf16 ----------
__global__ __launch_bounds__(256) void ln2p_kernel(
    const float* __restrict__ p0, const float* __restrict__ p1,
    const float* __restrict__ bias, const float* __restrict__ resid,
    const float* __restrict__ gamma, const float* __restrict__ beta,
    float* __restrict__ outf, unsigned short* __restrict__ outb) {
  const int row = blockIdx.x, tid = threadIdx.x;
  const size_t off = (size_t)row * 1024;
  float4 a = ((const float4*)(p0 + off))[tid];
  float4 b = ((const float4*)(p1 + off))[tid];
  float4 bb4 = ((const float4*)bias)[tid];
  float4 rr = ((const float4*)(resid + off))[tid];
  float4 v;
  v.x = a.x + b.x + bb4.x + rr.x;
  v.y = a.y + b.y + bb4.y + rr.y;
  v.z = a.z + b.z + bb4.z + rr.z;
  v.w = a.w + b.w + bb4.w + rr.w;

  float s = v.x + v.y + v.z + v.w;
  float ss = v.x * v.x + v.y * v.y + v.z * v.z + v.w * v.w;
#pragma unroll
  for (int o2 = 32; o2 > 0; o2 >>= 1) {
    s += __shfl_down(s, o2);
    ss += __shfl_down(ss, o2);
  }
  __shared__ float red[8];
  const int wid = tid >> 6;
  if ((tid & 63) == 0) { red[wid] = s; red[4 + wid] = ss; }
  __syncthreads();
  float S = red[0] + red[1] + red[2] + red[3];
  float SS = red[4] + red[5] + red[6] + red[7];
  const float mean = S * (1.f / 1024.f);
  const float var = SS * (1.f / 1024.f) - mean * mean;
  const float inv = 1.f / sqrtf(var + 1e-10f);
  float4 gg = ((const float4*)gamma)[tid];
  float4 be = ((const float4*)beta)[tid];
  float4 o;
  o.x = (v.x - mean) * inv * gg.x + be.x;
  o.y = (v.y - mean) * inv * gg.y + be.y;
  o.z = (v.z - mean) * inv * gg.z + be.z;
  o.w = (v.w - mean) * inv * gg.w + be.w;
  ((float4*)(outf + off))[tid] = o;
  u16x4_a t = {f2b(o.x), f2b(o.y), f2b(o.z), f2b(o.w)};
  *(u16x4_a*)(outb + off + tid * 4) = t;
}

// ---------- fused 4-partial reduce + bias + residual + LN -> f32 ----------
__global__ __launch_bounds__(256) void ln4p_kernel(
    const float* __restrict__ p0, const float* __restrict__ p1,
    const float* __restrict__ p2, const float* __restrict__ p3,
    const float* __restrict__ bias, const float* __restrict__ resid,
    const float* __restrict__ gamma, const float* __restrict__ beta,
    float* __restrict__ outf) {
  const int row = blockIdx.x, tid = threadIdx.x;
  const size_t off = (size_t)row * 1024;
  float4 a = ((const float4*)(p0 + off))[tid];
  float4 b = ((const float4*)(p1 + off))[tid];
  float4 c = ((const float4*)(p2 + off))[tid];
  float4 d = ((const float4*)(p3 + off))[tid];
  float4 bb4 = ((const float4*)bias)[tid];
  float4 rr = ((const float4*)(resid + off))[tid];
  float4 v;
  v.x = (a.x + b.x) + (c.x + d.x) + bb4.x + rr.x;
  v.y = (a.y + b.y) + (c.y + d.y) + bb4.y + rr.y;
  v.z = (a.z + b.z) + (c.z + d.z) + bb4.z + rr.z;
  v.w = (a.w + b.w) + (c.w + d.w) + bb4.w + rr.w;

  float s = v.x + v.y + v.z + v.w;
  float ss = v.x * v.x + v.y * v.y + v.z * v.z + v.w * v.w;
#pragma unroll
  for (int o2 = 32; o2 > 0; o2 >>= 1) {
    s += __shfl_down(s, o2);
    ss += __shfl_down(ss, o2);
  }
  __shared__ float red[8];
  const int wid = tid >> 6;
  if ((tid & 63) == 0) { red[wid] = s; red[4 + wid] = ss; }
  __syncthreads();
  float S = red[0] + red[1] + red[2] + red[3];
  float SS = red[4] + red[5] + red[6] + red[7];
  const float mean = S * (1.f / 1024.f);
  const float var = SS * (1.f / 1024.f) - mean * mean;
  const float inv = 1.f / sqrtf(var + 1e-10f);
  float4 gg = ((const float4*)gamma)[tid];
  float4 be = ((const float4*)beta)[tid];
  float4 o;
  o.x = (v.x - mean) * inv * gg.x + be.x;
  o.y = (v.y - mean) * inv * gg.y + be.y;
  o.z = (v.z - mean) * inv * gg.z + be.z;
  o.w = (v.w - mean) * inv * gg.w + be.w;
  ((float4*)(outf + off))[tid] = o;
}

// ---------- launch ----------
extern "C" void kernel_launch(void* const* d_in, const int* in_sizes, int n_in,
                              void* d_out, int out_size, void* d_ws, size_t ws_size,
                              hipStream_t stream) {
  const float* x      = (const float*)d_in[0];
  const float* wq     = (const float*)d_in[1];
  const float* bq     = (const float*)d_in[2];
  const float* wk     = (const float*)d_in[3];
  const float* bk     = (const float*)d_in[4];
  const float* wv     = (const float*)d_in[5];
  const float* bv     = (const float*)d_in[6];
  const float* w_proj = (const float*)d_in[7];
  const float* b_proj = (const float*)d_in[8];
  const float* gamma1 = (const float*)d_in[9];
  const float* beta1  = (const float*)d_in[10];
  const float* w1     = (const float*)d_in[11];
  const float* b1     = (const float*)d_in[12];
  const float* w2     = (const float*)d_in[13];
  const float* b2     = (const float*)d_in[14];
  const float* gamma2 = (const float*)d_in[15];
  const float* beta2  = (const float*)d_in[16];

  char* p = (char*)d_ws;
  auto alloc = [&](size_t bytes) {
    char* r = p;
    p += (bytes + 255) & ~(size_t)255;
    return r;
  };
  // Order chosen so 4 contiguous 16MB dead regions exist at FFN2 time.
  unsigned short* xb      = (unsigned short*)alloc(4096ull * 1024 * 2);  // 8MB; dead after proj
  unsigned short* Wqkv_t  = (unsigned short*)alloc(3072ull * 1024 * 2);  // 6MB; dead after QKV
  unsigned short* Wproj_t = (unsigned short*)alloc(1024ull * 1024 * 2);  // 2MB; dead after proj
  unsigned short* W2t     = (unsigned short*)alloc(1024ull * 4096 * 2);  // 8MB; live thru FFN2
  float*          biasq   = (float*)alloc(3072 * 4);
  unsigned short* Qb      = (unsigned short*)alloc(4096ull * 1024 * 2);  // 8MB; dead after attn
  unsigned short* Kb      = (unsigned short*)alloc(4096ull * 1024 * 2);  // 8MB; dead after attn
  unsigned short* Vtb     = (unsigned short*)alloc(4096ull * 1024 * 2);  // 8MB; dead after attn
  unsigned short* W1t     = (unsigned short*)alloc(4096ull * 1024 * 2);  // 8MB; dead after FFN1
  float*          resid1  = (float*)alloc(4096ull * 1024 * 4);           // 16MB; pure scratch
  float*          out1f   = (float*)alloc(4096ull * 1024 * 4);           // live thru ln4p
  unsigned short* out1b   = (unsigned short*)alloc(4096ull * 1024 * 2);  // dead after FFN1
  unsigned short* ffn_h   = (unsigned short*)alloc(4096ull * 4096 * 2);  // live thru FFN2
  unsigned short* concat  = xb;

  // proj split-K=2 partials (dead regions at proj time):
  float* prA = (float*)Qb;      // Qb+Kb = 16MB contiguous
  float* prB = resid1;          // 16MB scratch
  // FFN2 split-K=4 partials (dead at FFN2 time):
  float* pp0 = (float*)xb;      // xb+Wqkv_t+Wproj_t = 16MB
  float* pp1 = (float*)Qb;      // Qb+Kb = 16MB
  float* pp2 = (float*)Vtb;     // Vtb+W1t = 16MB
  float* pp3 = resid1;          // 16MB

  cvt_kernel<<<4096, 256, 0, stream>>>(x, xb, 4096 * 1024 / 4);
  transpose_cvt<<<dim3(2, 32, 16), 256, 0, stream>>>(wq, Wqkv_t, 1024, 64, 0.18033688f);
  transpose_cvt<<<dim3(2, 32, 16), 256, 0, stream>>>(wk, Wqkv_t + 1024 * 1024, 1024, 64, 1.f);
  transpose_cvt<<<dim3(2, 32, 16), 256, 0, stream>>>(wv, Wqkv_t + 2048 * 1024, 1024, 64, 1.f);
  transpose_cvt<<<dim3(32, 32, 1), 256, 0, stream>>>(w_proj, Wproj_t, 1024, 1024, 1.f);
  transpose_cvt<<<dim3(128, 32, 1), 256, 0, stream>>>(w1, W1t, 1024, 4096, 1.f);
  transpose_cvt<<<dim3(32, 128, 1), 256, 0, stream>>>(w2, W2t, 4096, 1024, 1.f);
  build_bias_qkv<<<12, 256, 0, stream>>>(bq, bk, bv, biasq);

  // QKV: 256^2 8-phase, M=4096 N=3072 -> 192 blocks
  gemm256_kernel<0><<<192, 512, 0, stream>>>(xb, Wqkv_t, 4096, 3072, 1024, 12, 1, biasq,
                                             nullptr, Qb, Kb, Vtb, nullptr, nullptr,
                                             nullptr, nullptr);
  attn_kernel<<<dim3(32, 32), 256, 0, stream>>>(Qb, Kb, Vtb, concat);
  // proj: 128^2, split-K=2 -> 512 blocks (2/CU); fused reduce+LN1
  gemm_bt_kernel<<<dim3(8, 32, 2), 256, 0, stream>>>(concat, Wproj_t, 4096, 1024, 512, 1024,
                                                     prA, prB);
  ln2p_kernel<<<4096, 256, 0, stream>>>(prA, prB, b_proj, x, gamma1, beta1, out1f, out1b);
  // FFN1: 256^2 8-phase, M=4096 N=4096 -> 256 blocks
  gemm256_kernel<2><<<256, 512, 0, stream>>>(out1b, W1t, 4096, 4096, 1024, 16, 1, b1,
                                             ffn_h, nullptr, nullptr, nullptr,
                                             nullptr, nullptr, nullptr, nullptr);
  // FFN2: 256^2 8-phase split-K=4 -> 16x4x4 = 256 blocks (1/CU, 100% coverage)
  gemm256_kernel<3><<<256, 512, 0, stream>>>(ffn_h, W2t, 4096, 1024, 4096, 4, 4, nullptr,
                                             nullptr, nullptr, nullptr, nullptr,
                                             pp0, pp1, pp2, pp3);
  ln4p_kernel<<<4096, 256, 0, stream>>>(pp0, pp1, pp2, pp3, b2, out1f, gamma2, beta2,
                                        (float*)d_out);
}

// Round 10
// 250.842 us; speedup vs baseline: 2.0690x; 1.0509x over previous
//
#include <hip/hip_runtime.h>
#include <stdint.h>

// ---------- types ----------
typedef float f32x4 __attribute__((ext_vector_type(4)));
typedef __bf16 bf16x8 __attribute__((ext_vector_type(8)));
typedef __bf16 bf16x8_a __attribute__((ext_vector_type(8), may_alias));
typedef __bf16 bf16x4_a __attribute__((ext_vector_type(4), may_alias));
typedef unsigned int u32x4_a __attribute__((ext_vector_type(4), may_alias));
typedef unsigned short u16x4_a __attribute__((ext_vector_type(4), may_alias));

#define DEV __device__ __forceinline__
#define MFMA_B16(a, b, c) __builtin_amdgcn_mfma_f32_16x16x32_bf16((a), (b), (c), 0, 0, 0)

#if __has_builtin(__builtin_amdgcn_exp2f)
#define EXP2(x) __builtin_amdgcn_exp2f(x)
#else
#define EXP2(x) exp2f(x)
#endif

DEV unsigned short f2b(float f) {  // f32 -> bf16 RNE
  unsigned int u = __float_as_uint(f);
  u = u + 0x7FFFu + ((u >> 16) & 1u);
  return (unsigned short)(u >> 16);
}

// async global->LDS, 16B per lane; LDS dest is wave-uniform base + lane*16
#define GLOAD_LDS16(gsrc, ldst)                                                  \
  __builtin_amdgcn_global_load_lds(                                              \
      (__attribute__((address_space(1))) void*)(uintptr_t)(const void*)(gsrc),   \
      (__attribute__((address_space(3))) void*)(ldst), 16, 0, 0)

// ---------- conversion kernels ----------
__global__ __launch_bounds__(256) void cvt_kernel(const float* __restrict__ in,
                                                  unsigned short* __restrict__ out, int n4) {
  int i = blockIdx.x * 256 + threadIdx.x;
  if (i < n4) {
    float4 v = ((const float4*)in)[i];
    u16x4_a t = {f2b(v.x), f2b(v.y), f2b(v.z), f2b(v.w)};
    ((u16x4_a*)out)[i] = t;
  }
}

// merged wq/wk/wv transpose: z in [0,48); 16 head-slices each of [1024][64]
__global__ __launch_bounds__(256) void tqkv_kernel(const float* __restrict__ wq,
                                                   const float* __restrict__ wk,
                                                   const float* __restrict__ wv,
                                                   unsigned short* __restrict__ out) {
  __shared__ float tile[32][33];
  const int tx = threadIdx.x & 31, ty = threadIdx.x >> 5;
  const int zz = blockIdx.z, sel = zz >> 4, zh = zz & 15;
  const float scale = sel == 0 ? 0.18033688f : 1.f;  // q: 1/sqrt(HD)*log2(e)
  const float* ip = (sel == 0 ? wq : (sel == 1 ? wk : wv)) + (size_t)zh * 1024 * 64;
  unsigned short* op = out + (size_t)sel * 1024 * 1024 + (size_t)zh * 1024 * 64;
  const int c0 = blockIdx.x * 32, r0 = blockIdx.y * 32;
#pragma unroll
  for (int j = 0; j < 32; j += 8)
    tile[ty + j][tx] = ip[(size_t)(r0 + ty + j) * 64 + (c0 + tx)];
  __syncthreads();
#pragma unroll
  for (int j = 0; j < 32; j += 8)
    op[(size_t)(c0 + ty + j) * 1024 + (r0 + tx)] = f2b(tile[tx][ty + j] * scale);
}

// merged w_proj/w1/w2 transpose: flat grid 9216 blocks of 32x32 tiles
__global__ __launch_bounds__(256) void tw_kernel(const float* __restrict__ w_proj,
                                                 const float* __restrict__ w1,
                                                 const float* __restrict__ w2,
                                                 unsigned short* __restrict__ o_proj,
                                                 unsigned short* __restrict__ o1,
                                                 unsigned short* __restrict__ o2) {
  __shared__ float tile[32][33];
  const int tx = threadIdx.x & 31, ty = threadIdx.x >> 5;
  int bid = blockIdx.x;
  const float* in;
  unsigned short* out;
  int rows, cols, bx, by;
  if (bid < 1024) {  // w_proj 1024x1024, nbx=32
    in = w_proj; out = o_proj; rows = 1024; cols = 1024; bx = bid & 31; by = bid >> 5;
  } else if (bid < 5120) {  // w1 1024x4096, nbx=128
    bid -= 1024; in = w1; out = o1; rows = 1024; cols = 4096; bx = bid & 127; by = bid >> 7;
  } else {  // w2 4096x1024, nbx=32
    bid -= 5120; in = w2; out = o2; rows = 4096; cols = 1024; bx = bid & 31; by = bid >> 5;
  }
  const int c0 = bx * 32, r0 = by * 32;
#pragma unroll
  for (int j = 0; j < 32; j += 8)
    tile[ty + j][tx] = in[(size_t)(r0 + ty + j) * cols + (c0 + tx)];
  __syncthreads();
#pragma unroll
  for (int j = 0; j < 32; j += 8)
    out[(size_t)(c0 + ty + j) * rows + (r0 + tx)] = f2b(tile[tx][ty + j]);
}

__global__ void build_bias_qkv(const float* __restrict__ bq, const float* __restrict__ bk,
                               const float* __restrict__ bv, float* __restrict__ out) {
  int c = blockIdx.x * 256 + threadIdx.x;  // 0..3071
  int which = c >> 10, idx = c & 1023;
  float v = which == 0 ? bq[idx] : (which == 1 ? bk[idx] : bv[idx]);
  out[c] = which == 0 ? v * 0.18033688f : v;
}

// ---------- 256x256 8-phase GEMM (m201 template, plain HIP) ----------
template <int EP>
__global__ __launch_bounds__(512, 2) void gemm256_kernel(
    const unsigned short* __restrict__ A, const unsigned short* __restrict__ Bt,
    int M, int N, int K, int nbx, int KS,
    const float* __restrict__ bias, unsigned short* __restrict__ outb,
    unsigned short* __restrict__ q_out, unsigned short* __restrict__ k_out,
    unsigned short* __restrict__ v_out,
    float* __restrict__ pp0, float* __restrict__ pp1, float* __restrict__ pp2,
    float* __restrict__ pp3) {
  __shared__ __align__(16) unsigned short sA[2][256 * 64];
  __shared__ __align__(16) unsigned short sB[2][256 * 64];

  const int tid = threadIdx.x;
  const int wid = tid >> 6, lane = tid & 63;
  const int g = lane >> 4, r15 = lane & 15;
  const int wm = wid >> 2, wn = wid & 3;

  const int nwg = gridDim.x, cpx = nwg >> 3, orig = blockIdx.x;
  const int wg = (orig & 7) * cpx + (orig >> 3);
  const int bx = wg % nbx;
  const int t1 = wg / nbx;
  const int kz = t1 % KS, by = t1 / KS;
  const int row0 = by * 256, col0 = bx * 256;

  const int tilesK = K >> 6;
  const int qT = tilesK / KS, rT = tilesK % KS;
  const int tile0 = kz * qT + (kz < rT ? kz : rT);
  const int NT = qT + (kz < rT ? 1 : 0);
  const int kbase = tile0 << 6;

  const unsigned short* gA0 = A + (size_t)row0 * K + kbase;
  const unsigned short* gB0 = Bt + (size_t)col0 * K + kbase;
  const int srow8 = lane >> 3;
  const int schunk = ((lane & 7) ^ srow8) * 8;

  f32x4 acc[8][4] = {};
  bf16x8 af[4][2], bfr[4][2];

  auto stA = [&](int buf, int k0, int i) {
    const int r = wid * 32 + i * 8;
    GLOAD_LDS16(gA0 + (size_t)(r + srow8) * K + k0 + schunk, &sA[buf][r * 64]);
  };
  auto stB = [&](int buf, int k0, int i) {
    const int r = wid * 32 + i * 8;
    GLOAD_LDS16(gB0 + (size_t)(r + srow8) * K + k0 + schunk, &sB[buf][r * 64]);
  };
  auto ldA = [&](const unsigned short* p, int m, int ks) -> bf16x8 {
    const int row = wm * 128 + m * 16 + r15;
    return *(const bf16x8_a*)&p[row * 64 + (((ks * 4 + g) ^ (r15 & 7)) * 8)];
  };
  auto ldB = [&](const unsigned short* p, int n, int ks) -> bf16x8 {
    const int row = wn * 64 + n * 16 + r15;
    return *(const bf16x8_a*)&p[row * 64 + (((ks * 4 + g) ^ (r15 & 7)) * 8)];
  };

#pragma unroll
  for (int i = 0; i < 4; ++i) { stA(0, 0, i); stB(0, 0, i); }
  asm volatile("s_waitcnt vmcnt(0)" ::: "memory");
  __builtin_amdgcn_s_barrier();

  for (int kt = 0; kt < NT; ++kt) {
    const int cb = kt & 1, nb = cb ^ 1;
    const bool pf = (kt + 1) < NT;
    const int k1 = (kt + 1) << 6;
    const unsigned short* pA = sA[cb];
    const unsigned short* pB = sB[cb];

#pragma unroll
    for (int m = 0; m < 4; ++m) { af[m][0] = ldA(pA, m, 0); af[m][1] = ldA(pA, m, 1); }
#pragma unroll
    for (int n = 0; n < 4; ++n) { bfr[n][0] = ldB(pB, n, 0); bfr[n][1] = ldB(pB, n, 1); }
    if (pf) { stA(nb, k1, 0); stA(nb, k1, 1); }
    __builtin_amdgcn_s_barrier();
    asm volatile("s_waitcnt lgkmcnt(0)" ::: "memory");
    __builtin_amdgcn_sched_barrier(0);
    __builtin_amdgcn_s_setprio(1);
#pragma unroll
    for (int m = 0; m < 4; ++m)
#pragma unroll
      for (int n = 0; n < 2; ++n) {
        acc[m][n] = MFMA_B16(af[m][0], bfr[n][0], acc[m][n]);
        acc[m][n] = MFMA_B16(af[m][1], bfr[n][1], acc[m][n]);
      }
    __builtin_amdgcn_s_setprio(0);
    __builtin_amdgcn_s_barrier();

    if (pf) { stA(nb, k1, 2); stA(nb, k1, 3); }
    __builtin_amdgcn_s_barrier();
    __builtin_amdgcn_s_setprio(1);
#pragma unroll
    for (int m = 0; m < 4; ++m)
#pragma unroll
      for (int n = 2; n < 4; ++n) {
        acc[m][n] = MFMA_B16(af[m][0], bfr[n][0], acc[m][n]);
        acc[m][n] = MFMA_B16(af[m][1], bfr[n][1], acc[m][n]);
      }
    __builtin_amdgcn_s_setprio(0);
    __builtin_amdgcn_s_barrier();

#pragma unroll
    for (int m = 0; m < 4; ++m) { af[m][0] = ldA(pA, m + 4, 0); af[m][1] = ldA(pA, m + 4, 1); }
    if (pf) { stB(nb, k1, 0); stB(nb, k1, 1); }
    __builtin_amdgcn_s_barrier();
    asm volatile("s_waitcnt lgkmcnt(0)" ::: "memory");
    __builtin_amdgcn_sched_barrier(0);
    __builtin_amdgcn_s_setprio(1);
#pragma unroll
    for (int m = 0; m < 4; ++m)
#pragma unroll
      for (int n = 0; n < 2; ++n) {
        acc[m + 4][n] = MFMA_B16(af[m][0], bfr[n][0], acc[m + 4][n]);
        acc[m + 4][n] = MFMA_B16(af[m][1], bfr[n][1], acc[m + 4][n]);
      }
    __builtin_amdgcn_s_setprio(0);
    __builtin_amdgcn_s_barrier();

    if (pf) { stB(nb, k1, 2); stB(nb, k1, 3); }
    __builtin_amdgcn_s_barrier();
    __builtin_amdgcn_s_setprio(1);
#pragma unroll
    for (int m = 0; m < 4; ++m)
#pragma unroll
      for (int n = 2; n < 4; ++n) {
        acc[m + 4][n] = MFMA_B16(af[m][0], bfr[n][0], acc[m + 4][n]);
        acc[m + 4][n] = MFMA_B16(af[m][1], bfr[n][1], acc[m + 4][n]);
      }
    __builtin_amdgcn_s_setprio(0);
    asm volatile("s_waitcnt vmcnt(0)" ::: "memory");
    __builtin_amdgcn_s_barrier();
  }

  float* pz = kz == 0 ? pp0 : (kz == 1 ? pp1 : (kz == 2 ? pp2 : pp3));
#pragma unroll
  for (int m = 0; m < 8; ++m) {
    const int rbase = row0 + wm * 128 + m * 16 + g * 4;
#pragma unroll
    for (int n = 0; n < 4; ++n) {
      const int col = col0 + wn * 64 + n * 16 + r15;
      const float bb = (EP == 3) ? 0.f : bias[col];
      if constexpr (EP == 0) {
        const int which = col >> 10, cc = col & 1023;
        const int hh = cc >> 6, e = cc & 63;
        const int b = rbase >> 11, s0v = rbase & 2047;
        if (which == 2) {
          bf16x4_a pk;
#pragma unroll
          for (int r = 0; r < 4; ++r) pk[r] = (__bf16)(acc[m][n][r] + bb);
          *(bf16x4_a*)(v_out + (((size_t)(b * 16 + hh) * 64) + e) * 2048 + s0v) = pk;
        } else {
          unsigned short* dst = which == 0 ? q_out : k_out;
#pragma unroll
          for (int r = 0; r < 4; ++r)
            dst[(((size_t)(b * 16 + hh) * 2048) + s0v + r) * 64 + e] =
                f2b(acc[m][n][r] + bb);
        }
      } else {
#pragma unroll
        for (int r = 0; r < 4; ++r) {
          const int row = rbase + r;
          float v = acc[m][n][r] + bb;
          if constexpr (EP == 3) {
            pz[(size_t)row * N + col] = v;
          } else {
            outb[(size_t)row * N + col] = f2b(v > 0.f ? v : 0.f);
          }
        }
      }
    }
  }
}

// ---------- 128x128 GEMM, split-K over blockIdx.z, raw f32 partial out ----------
__global__ __launch_bounds__(256) void gemm_bt_kernel(
    const unsigned short* __restrict__ A, const unsigned short* __restrict__ Bt,
    int M, int N, int Kchunk, int Kstride,
    float* __restrict__ pp0, float* __restrict__ pp1) {
  __shared__ __align__(16) unsigned short sA[2][128 * 32];
  __shared__ __align__(16) unsigned short sB[2][128 * 32];
  const int tid = threadIdx.x;
  const int wid = tid >> 6, lane = tid & 63;
  const int g = lane >> 4, r15 = lane & 15;
  const int wr = wid >> 1, wc = wid & 1;
  const int row0 = blockIdx.y * 128, col0 = blockIdx.x * 128;
  const int kz = blockIdx.z;

  f32x4 acc[4][4] = {};

  const int c0 = wid * 128 + lane;
  const unsigned short* gA0 = A + (size_t)row0 * Kstride + (size_t)kz * Kchunk;
  const unsigned short* gB0 = Bt + (size_t)col0 * Kstride + (size_t)kz * Kchunk;

  auto stage = [&](int buf, int k0) {
#pragma unroll
    for (int j = 0; j < 2; ++j) {
      int c = c0 + j * 64;
      GLOAD_LDS16(gA0 + (size_t)(c >> 2) * Kstride + k0 + (c & 3) * 8,
                  &sA[buf][(wid * 128 + j * 64) * 8]);
      GLOAD_LDS16(gB0 + (size_t)(c >> 2) * Kstride + k0 + (c & 3) * 8,
                  &sB[buf][(wid * 128 + j * 64) * 8]);
    }
  };

  stage(0, 0);
  const int NT = Kchunk >> 5;
  for (int t = 0; t < NT; ++t) {
    const int cb = t & 1;
    __syncthreads();
    if (t + 1 < NT) stage(cb ^ 1, (t + 1) * 32);
    bf16x8 af[4], bfr[4];
#pragma unroll
    for (int m = 0; m < 4; ++m)
      af[m] = *(const bf16x8_a*)&sA[cb][(wr * 64 + m * 16 + r15) * 32 + g * 8];
#pragma unroll
    for (int n = 0; n < 4; ++n)
      bfr[n] = *(const bf16x8_a*)&sB[cb][(wc * 64 + n * 16 + r15) * 32 + g * 8];
#pragma unroll
    for (int m = 0; m < 4; ++m)
#pragma unroll
      for (int n = 0; n < 4; ++n)
        acc[m][n] = MFMA_B16(af[m], bfr[n], acc[m][n]);
  }

  float* pz = kz == 0 ? pp0 : pp1;
#pragma unroll
  for (int m = 0; m < 4; ++m) {
    const int rbase = row0 + wr * 64 + m * 16 + g * 4;
#pragma unroll
    for (int n = 0; n < 4; ++n) {
      const int col = col0 + wc * 64 + n * 16 + r15;
#pragma unroll
      for (int r = 0; r < 4; ++r)
        pz[(size_t)(rbase + r) * N + col] = acc[m][n][r];
    }
  }
}

// ---------- flash attention, swapped softmax, exp2, 2x-unrolled (const bufs) ----------
__global__ __launch_bounds__(256) void attn_kernel(const unsigned short* __restrict__ Q,
                                                   const unsigned short* __restrict__ K,
                                                   const unsigned short* __restrict__ Vt,
                                                   unsigned short* __restrict__ out) {
  const int flat = blockIdx.y * gridDim.x + blockIdx.x;  // 0..1023
  const int xcd = flat & 7, rest = flat >> 3;
  const int bh = xcd * 4 + (rest >> 5);
  const int q0 = (rest & 31) * 64;

  const int tid = threadIdx.x, wid = tid >> 6, lane = tid & 63;
  const int g = lane >> 4, r15 = lane & 15;
  const int h = r15 & 7;
  const int s0 = ((g ^ h) * 8);
  const int s1 = (((g + 4) ^ h) * 8);
  const int pswz = r15 & 14;

  __shared__ __align__(16) unsigned short sK[2][64 * 64];
  __shared__ __align__(16) unsigned short sV[2][64 * 64];
  __shared__ __align__(16) unsigned short sP[4][16 * 64];

  const size_t base = (size_t)bh * (2048 * 64);
  const unsigned short* Kb = K + base;
  const unsigned short* Vb = Vt + base;

  const int qrow = q0 + wid * 16 + r15;
  bf16x8 qf[2];
  qf[0] = *(const bf16x8_a*)(Q + base + (size_t)qrow * 64 + g * 8);
  qf[1] = *(const bf16x8_a*)(Q + base + (size_t)qrow * 64 + 32 + g * 8);

  const int srow = lane >> 3;
  const int schunk = ((lane & 7) ^ srow) * 8;

  union {
    unsigned short u[8];
    bf16x8 v;
  } ou;
#pragma unroll
  for (int i = 0; i < 8; ++i) ou.u[i] = 0x3F80;
  const bf16x8 onesb = ou.v;

  f32x4 o[4] = {};
  float mrow = -1e30f, lrow = 0.f;

  // hoisted, loop-invariant LDS offsets (ushort units)
  const int krd0 = r15 * 64 + s0;           // + kt*1024
  const int krd1 = r15 * 64 + s1;
  unsigned short* const pw = &sP[wid][r15 * 64];
  const int pwr0 = ((2 * g) ^ pswz) << 2;
  const int pwr1 = ((8 + 2 * g) ^ pswz) << 2;

  auto stage = [&](int bufi, int kt0s) {
#pragma unroll
    for (int i = 0; i < 2; ++i) {
      const int inst = wid * 2 + i;
      const int row = 8 * inst + srow;
      GLOAD_LDS16(Kb + (size_t)(kt0s + row) * 64 + schunk, &sK[bufi][inst * 512]);
      GLOAD_LDS16(Vb + (size_t)row * 2048 + kt0s + schunk, &sV[bufi][inst * 512]);
    }
  };

  // tile body with compile-time-constant buffer pointers
  auto do_tile = [&](const unsigned short* kbuf, const unsigned short* vbuf) {
    f32x4 sc[4] = {};
#pragma unroll
    for (int kt = 0; kt < 4; ++kt) {
      bf16x8 kf0 = *(const bf16x8_a*)&kbuf[kt * 1024 + krd0];
      bf16x8 kf1 = *(const bf16x8_a*)&kbuf[kt * 1024 + krd1];
      sc[kt] = MFMA_B16(kf0, qf[0], sc[kt]);
      sc[kt] = MFMA_B16(kf1, qf[1], sc[kt]);
    }

    float a0 = fmaxf(fmaxf(sc[0][0], sc[0][1]), sc[0][2]);
    float a1 = fmaxf(fmaxf(sc[0][3], sc[1][0]), sc[1][1]);
    float a2 = fmaxf(fmaxf(sc[1][2], sc[1][3]), sc[2][0]);
    float a3 = fmaxf(fmaxf(sc[2][1], sc[2][2]), sc[2][3]);
    float a4 = fmaxf(fmaxf(sc[3][0], sc[3][1]), sc[3][2]);
    float b0 = fmaxf(fmaxf(a0, a1), a2);
    float b1 = fmaxf(fmaxf(a3, a4), sc[3][3]);
    float pmax = fmaxf(b0, b1);
    pmax = fmaxf(pmax, __shfl_xor(pmax, 16));
    pmax = fmaxf(pmax, __shfl_xor(pmax, 32));

    const bool allkeep = __all(pmax - mrow <= 11.5441f);
    float fac;
    if (allkeep) {
      fac = 1.0f;
    } else {
      float nm = fmaxf(mrow, pmax);
      fac = EXP2(mrow - nm);
      mrow = nm;
#pragma unroll
      for (int dt = 0; dt < 4; ++dt)
#pragma unroll
        for (int r = 0; r < 4; ++r) o[dt][r] *= fac;
    }

#pragma unroll
    for (int kt = 0; kt < 4; ++kt) {
      bf16x4_a pb;
      pb[0] = (__bf16)EXP2(sc[kt][0] - mrow);
      pb[1] = (__bf16)EXP2(sc[kt][1] - mrow);
      pb[2] = (__bf16)EXP2(sc[kt][2] - mrow);
      pb[3] = (__bf16)EXP2(sc[kt][3] - mrow);
      *(bf16x4_a*)&pw[((4 * kt + g) ^ pswz) << 2] = pb;
    }

    bf16x8 pf0 = *(const bf16x8_a*)&pw[pwr0];
    bf16x8 pf1 = *(const bf16x8_a*)&pw[pwr1];

    f32x4 lacc = {};
    lacc = MFMA_B16(onesb, pf0, lacc);
    lacc = MFMA_B16(onesb, pf1, lacc);
    lrow = lrow * fac + lacc[0];

#pragma unroll
    for (int dt = 0; dt < 4; ++dt) {
      bf16x8 vf0 = *(const bf16x8_a*)&vbuf[dt * 1024 + krd0];
      bf16x8 vf1 = *(const bf16x8_a*)&vbuf[dt * 1024 + krd1];
      o[dt] = MFMA_B16(vf0, pf0, o[dt]);
      o[dt] = MFMA_B16(vf1, pf1, o[dt]);
    }
  };

  stage(0, 0);
#pragma unroll 1
  for (int t = 0; t < 32; t += 2) {
    __syncthreads();
    stage(1, (t + 1) * 64);
    do_tile(&sK[0][0], &sV[0][0]);
    __syncthreads();
    if (t + 2 < 32) stage(0, (t + 2) * 64);
    do_tile(&sK[1][0], &sV[1][0]);
  }

  const int b = bh >> 4, hh = bh & 15;
  const int s = q0 + wid * 16 + r15;
  const float inv = 1.f / lrow;
  unsigned short* orow = out + ((size_t)(b * 2048 + s)) * 1024 + hh * 64;
#pragma unroll
  for (int dt = 0; dt < 4; ++dt) {
    bf16x4_a tq;
    tq[0] = (__bf16)(o[dt][0] * inv);
    tq[1] = (__bf16)(o[dt][1] * inv);
    tq[2] = (__bf16)(o[dt][2] * inv);
    tq[3] = (__bf16)(o[dt][3] * inv);
    *(bf16x4_a*)(orow + dt * 16 + g * 4) = tq;
  }
}

// ---------- fused 2-partial reduce + bias + residual + LN -> f32 + bf16 ----------
__global__ __launch_bounds__(256) void ln2p_kernel(
    const float* __restrict__ p0, const float* __restrict__ p1,
    const float* __restrict__ bias, const float* __restrict__ resid,
    const float* __restrict__ gamma, const float* __restrict__ beta,
    float* __restrict__ outf, unsigned short* __restrict__ outb) {
  const int row = blockIdx.x, tid = threadIdx.x;
  const size_t off = (size_t)row * 1024;
  float4 a = ((const float4*)(p0 + off))[tid];
  float4 b = ((const float4*)(p1 + off))[tid];
  float4 bb4 = ((const float4*)bias)[tid];
  float4 rr = ((const float4*)(resid + off))[tid];
  float4 v;
  v.x = a.x + b.x + bb4.x + rr.x;
  v.y = a.y + b.y + bb4.y + rr.y;
  v.z = a.z + b.z + bb4.z + rr.z;
  v.w = a.w + b.w + bb4.w + rr.w;

  float s = v.x + v.y + v.z + v.w;
  float ss = v.x * v.x + v.y * v.y + v.z * v.z + v.w * v.w;
#pragma unroll
  for (int o2 = 32; o2 > 0; o2 >>= 1) {
    s += __shfl_down(s, o2);
    ss += __shfl_down(ss, o2);
  }
  __shared__ float red[8];
  const int wid = tid >> 6;
  if ((tid & 63) == 0) { red[wid] = s; red[4 + wid] = ss; }
  __syncthreads();
  float S = red[0] + red[1] + red[2] + red[3];
  float SS = red[4] + red[5] + red[6] + red[7];
  const float mean = S * (1.f / 1024.f);
  const float var = SS * (1.f / 1024.f) - mean * mean;
  const float inv = 1.f / sqrtf(var + 1e-10f);
  float4 gg = ((const float4*)gamma)[tid];
  float4 be = ((const float4*)beta)[tid];
  float4 o;
  o.x = (v.x - mean) * inv * gg.x + be.x;
  o.y = (v.y - mean) * inv * gg.y + be.y;
  o.z = (v.z - mean) * inv * gg.z + be.z;
  o.w = (v.w - mean) * inv * gg.w + be.w;
  ((float4*)(outf + off))[tid] = o;
  u16x4_a t = {f2b(o.x), f2b(o.y), f2b(o.z), f2b(o.w)};
  *(u16x4_a*)(outb + off + tid * 4) = t;
}

// ---------- fused 4-partial reduce + bias + residual + LN -> f32 ----------
__global__ __launch_bounds__(256) void ln4p_kernel(
    const float* __restrict__ p0, const float* __restrict__ p1,
    const float* __restrict__ p2, const float* __restrict__ p3,
    const float* __restrict__ bias, const float* __restrict__ resid,
    const float* __restrict__ gamma, const float* __restrict__ beta,
    float* __restrict__ outf) {
  const int row = blockIdx.x, tid = threadIdx.x;
  const size_t off = (size_t)row * 1024;
  float4 a = ((const float4*)(p0 + off))[tid];
  float4 b = ((const float4*)(p1 + off))[tid];
  float4 c = ((const float4*)(p2 + off))[tid];
  float4 d = ((const float4*)(p3 + off))[tid];
  float4 bb4 = ((const float4*)bias)[tid];
  float4 rr = ((const float4*)(resid + off))[tid];
  float4 v;
  v.x = (a.x + b.x) + (c.x + d.x) + bb4.x + rr.x;
  v.y = (a.y + b.y) + (c.y + d.y) + bb4.y + rr.y;
  v.z = (a.z + b.z) + (c.z + d.z) + bb4.z + rr.z;
  v.w = (a.w + b.w) + (c.w + d.w) + bb4.w + rr.w;

  float s = v.x + v.y + v.z + v.w;
  float ss = v.x * v.x + v.y * v.y + v.z * v.z + v.w * v.w;
#pragma unroll
  for (int o2 = 32; o2 > 0; o2 >>= 1) {
    s += __shfl_down(s, o2);
    ss += __shfl_down(ss, o2);
  }
  __shared__ float red[8];
  const int wid = tid >> 6;
  if ((tid & 63) == 0) { red[wid] = s; red[4 + wid] = ss; }
  __syncthreads();
  float S = red[0] + red[1] + red[2] + red[3];
  float SS = red[4] + red[5] + red[6] + red[7];
  const float mean = S * (1.f / 1024.f);
  const float var = SS * (1.f / 1024.f) - mean * mean;
  const float inv = 1.f / sqrtf(var + 1e-10f);
  float4 gg = ((const float4*)gamma)[tid];
  float4 be = ((const float4*)beta)[tid];
  float4 o;
  o.x = (v.x - mean) * inv * gg.x + be.x;
  o.y = (v.y - mean) * inv * gg.y + be.y;
  o.z = (v.z - mean) * inv * gg.z + be.z;
  o.w = (v.w - mean) * inv * gg.w + be.w;
  ((float4*)(outf + off))[tid] = o;
}

// ---------- launch ----------
extern "C" void kernel_launch(void* const* d_in, const int* in_sizes, int n_in,
                              void* d_out, int out_size, void* d_ws, size_t ws_size,
                              hipStream_t stream) {
  const float* x      = (const float*)d_in[0];
  const float* wq     = (const float*)d_in[1];
  const float* bq     = (const float*)d_in[2];
  const float* wk     = (const float*)d_in[3];
  const float* bk     = (const float*)d_in[4];
  const float* wv     = (const float*)d_in[5];
  const float* bv     = (const float*)d_in[6];
  const float* w_proj = (const float*)d_in[7];
  const float* b_proj = (const float*)d_in[8];
  const float* gamma1 = (const float*)d_in[9];
  const float* beta1  = (const float*)d_in[10];
  const float* w1     = (const float*)d_in[11];
  const float* b1     = (const float*)d_in[12];
  const float* w2     = (const float*)d_in[13];
  const float* b2     = (const float*)d_in[14];
  const float* gamma2 = (const float*)d_in[15];
  const float* beta2  = (const float*)d_in[16];

  char* p = (char*)d_ws;
  auto alloc = [&](size_t bytes) {
    char* r = p;
    p += (bytes + 255) & ~(size_t)255;
    return r;
  };
  unsigned short* xb      = (unsigned short*)alloc(4096ull * 1024 * 2);  // 8MB
  unsigned short* Wqkv_t  = (unsigned short*)alloc(3072ull * 1024 * 2);  // 6MB
  unsigned short* Wproj_t = (unsigned short*)alloc(1024ull * 1024 * 2);  // 2MB
  unsigned short* W2t     = (unsigned short*)alloc(1024ull * 4096 * 2);  // 8MB
  float*          biasq   = (float*)alloc(3072 * 4);
  unsigned short* Qb      = (unsigned short*)alloc(4096ull * 1024 * 2);  // 8MB
  unsigned short* Kb      = (unsigned short*)alloc(4096ull * 1024 * 2);  // 8MB
  unsigned short* Vtb     = (unsigned short*)alloc(4096ull * 1024 * 2);  // 8MB
  unsigned short* W1t     = (unsigned short*)alloc(4096ull * 1024 * 2);  // 8MB
  float*          resid1  = (float*)alloc(4096ull * 1024 * 4);           // 16MB scratch
  float*          out1f   = (float*)alloc(4096ull * 1024 * 4);
  unsigned short* out1b   = (unsigned short*)alloc(4096ull * 1024 * 2);
  unsigned short* ffn_h   = (unsigned short*)alloc(4096ull * 4096 * 2);
  unsigned short* concat  = xb;

  float* prA = (float*)Qb;
  float* prB = resid1;
  float* pp0 = (float*)xb;
  float* pp1 = (float*)Qb;
  float* pp2 = (float*)Vtb;
  float* pp3 = resid1;

  cvt_kernel<<<4096, 256, 0, stream>>>(x, xb, 4096 * 1024 / 4);
  tqkv_kernel<<<dim3(2, 32, 48), 256, 0, stream>>>(wq, wk, wv, Wqkv_t);
  tw_kernel<<<9216, 256, 0, stream>>>(w_proj, w1, w2, Wproj_t, W1t, W2t);
  build_bias_qkv<<<12, 256, 0, stream>>>(bq, bk, bv, biasq);

  gemm256_kernel<0><<<192, 512, 0, stream>>>(xb, Wqkv_t, 4096, 3072, 1024, 12, 1, biasq,
                                             nullptr, Qb, Kb, Vtb, nullptr, nullptr,
                                             nullptr, nullptr);
  attn_kernel<<<dim3(32, 32), 256, 0, stream>>>(Qb, Kb, Vtb, concat);
  gemm_bt_kernel<<<dim3(8, 32, 2), 256, 0, stream>>>(concat, Wproj_t, 4096, 1024, 512, 1024,
                                                     prA, prB);
  ln2p_kernel<<<4096, 256, 0, stream>>>(prA, prB, b_proj, x, gamma1, beta1, out1f, out1b);
  gemm256_kernel<2><<<256, 512, 0, stream>>>(out1b, W1t, 4096, 4096, 1024, 16, 1, b1,
                                             ffn_h, nullptr, nullptr, nullptr,
                                             nullptr, nullptr, nullptr, nullptr);
  gemm256_kernel<3><<<256, 512, 0, stream>>>(ffn_h, W2t, 4096, 1024, 4096, 4, 4, nullptr,
                                             nullptr, nullptr, nullptr, nullptr,
                                             pp0, pp1, pp2, pp3);
  ln4p_kernel<<<4096, 256, 0, stream>>>(pp0, pp1, pp2, pp3, b2, out1f, gamma2, beta2,
                                        (float*)d_out);
}

// Round 11
// 236.645 us; speedup vs baseline: 2.1931x; 1.0600x over previous
//
#include <hip/hip_runtime.h>
#include <stdint.h>

// ---------- types ----------
typedef float f32x4 __attribute__((ext_vector_type(4)));
typedef __bf16 bf16x8 __attribute__((ext_vector_type(8)));
typedef __bf16 bf16x8_a __attribute__((ext_vector_type(8), may_alias));
typedef __bf16 bf16x4_a __attribute__((ext_vector_type(4), may_alias));
typedef unsigned int u32x4_a __attribute__((ext_vector_type(4), may_alias));
typedef unsigned short u16x4_a __attribute__((ext_vector_type(4), may_alias));

#define DEV __device__ __forceinline__
#define MFMA_B16(a, b, c) __builtin_amdgcn_mfma_f32_16x16x32_bf16((a), (b), (c), 0, 0, 0)

#if __has_builtin(__builtin_amdgcn_exp2f)
#define EXP2(x) __builtin_amdgcn_exp2f(x)
#else
#define EXP2(x) exp2f(x)
#endif

DEV unsigned short f2b(float f) {  // f32 -> bf16 RNE
  unsigned int u = __float_as_uint(f);
  u = u + 0x7FFFu + ((u >> 16) & 1u);
  return (unsigned short)(u >> 16);
}
DEV float b2f(unsigned short u) { return __uint_as_float(((unsigned int)u) << 16); }

// async global->LDS, 16B per lane; LDS dest is wave-uniform base + lane*16
#define GLOAD_LDS16(gsrc, ldst)                                                  \
  __builtin_amdgcn_global_load_lds(                                              \
      (__attribute__((address_space(1))) void*)(uintptr_t)(const void*)(gsrc),   \
      (__attribute__((address_space(3))) void*)(ldst), 16, 0, 0)

// ---------- fused prepass: cvt x | transpose wq/wk/wv | transpose w_proj/w1/w2 | bias ----------
// flat grid: [0,4096) cvt; [4096,7168) tqkv; [7168,16384) tw; [16384,16396) bias
__global__ __launch_bounds__(256) void prepass_kernel(
    const float* __restrict__ x, const float* __restrict__ wq,
    const float* __restrict__ wk, const float* __restrict__ wv,
    const float* __restrict__ w_proj, const float* __restrict__ w1,
    const float* __restrict__ w2, const float* __restrict__ bq,
    const float* __restrict__ bk, const float* __restrict__ bv,
    unsigned short* __restrict__ xb, unsigned short* __restrict__ Wqkv_t,
    unsigned short* __restrict__ o_proj, unsigned short* __restrict__ o1,
    unsigned short* __restrict__ o2, float* __restrict__ biasq) {
  __shared__ float tile[32][33];
  int bid = blockIdx.x;
  if (bid < 4096) {  // cvt: x f32 -> bf16
    int i = bid * 256 + threadIdx.x;
    float4 v = ((const float4*)x)[i];
    u16x4_a t = {f2b(v.x), f2b(v.y), f2b(v.z), f2b(v.w)};
    ((u16x4_a*)xb)[i] = t;
    return;
  }
  bid -= 4096;
  if (bid < 3072) {  // tqkv: [1024][64] head-slices -> [64..][1024] (x48)
    const int bx = bid & 1, by = (bid >> 1) & 31, zz = bid >> 6;
    const int sel = zz >> 4, zh = zz & 15;
    const float scale = sel == 0 ? 0.18033688f : 1.f;  // q: 1/sqrt(HD)*log2(e)
    const float* ip = (sel == 0 ? wq : (sel == 1 ? wk : wv)) + (size_t)zh * 1024 * 64;
    unsigned short* op = Wqkv_t + (size_t)sel * 1024 * 1024 + (size_t)zh * 1024 * 64;
    const int tx = threadIdx.x & 31, ty = threadIdx.x >> 5;
    const int c0 = bx * 32, r0 = by * 32;
#pragma unroll
    for (int j = 0; j < 32; j += 8)
      tile[ty + j][tx] = ip[(size_t)(r0 + ty + j) * 64 + (c0 + tx)];
    __syncthreads();
#pragma unroll
    for (int j = 0; j < 32; j += 8)
      op[(size_t)(c0 + ty + j) * 1024 + (r0 + tx)] = f2b(tile[tx][ty + j] * scale);
    return;
  }
  bid -= 3072;
  if (bid < 9216) {  // tw: w_proj/w1/w2 transposes
    const float* in;
    unsigned short* out;
    int rows, cols, bx, by;
    if (bid < 1024) {
      in = w_proj; out = o_proj; rows = 1024; cols = 1024; bx = bid & 31; by = bid >> 5;
    } else if (bid < 5120) {
      bid -= 1024; in = w1; out = o1; rows = 1024; cols = 4096; bx = bid & 127; by = bid >> 7;
    } else {
      bid -= 5120; in = w2; out = o2; rows = 4096; cols = 1024; bx = bid & 31; by = bid >> 5;
    }
    const int tx = threadIdx.x & 31, ty = threadIdx.x >> 5;
    const int c0 = bx * 32, r0 = by * 32;
#pragma unroll
    for (int j = 0; j < 32; j += 8)
      tile[ty + j][tx] = in[(size_t)(r0 + ty + j) * cols + (c0 + tx)];
    __syncthreads();
#pragma unroll
    for (int j = 0; j < 32; j += 8)
      out[(size_t)(c0 + ty + j) * rows + (r0 + tx)] = f2b(tile[tx][ty + j]);
    return;
  }
  bid -= 9216;  // bias: 12 blocks
  int c = bid * 256 + threadIdx.x;  // 0..3071
  int which = c >> 10, idx = c & 1023;
  float v = which == 0 ? bq[idx] : (which == 1 ? bk[idx] : bv[idx]);
  biasq[c] = which == 0 ? v * 0.18033688f : v;
}

// ---------- 256x256 8-phase GEMM (m201 template, plain HIP) ----------
// EP 0: QKV scatter + bias. EP 2: bf16 relu. EP 3: bf16 raw partial (split-K).
template <int EP>
__global__ __launch_bounds__(512, 2) void gemm256_kernel(
    const unsigned short* __restrict__ A, const unsigned short* __restrict__ Bt,
    int M, int N, int K, int nbx, int KS,
    const float* __restrict__ bias, unsigned short* __restrict__ outb,
    unsigned short* __restrict__ q_out, unsigned short* __restrict__ k_out,
    unsigned short* __restrict__ v_out,
    unsigned short* __restrict__ pp0, unsigned short* __restrict__ pp1,
    unsigned short* __restrict__ pp2, unsigned short* __restrict__ pp3) {
  __shared__ __align__(16) unsigned short sA[2][256 * 64];
  __shared__ __align__(16) unsigned short sB[2][256 * 64];

  const int tid = threadIdx.x;
  const int wid = tid >> 6, lane = tid & 63;
  const int g = lane >> 4, r15 = lane & 15;
  const int wm = wid >> 2, wn = wid & 3;

  const int nwg = gridDim.x, cpx = nwg >> 3, orig = blockIdx.x;
  const int wg = (orig & 7) * cpx + (orig >> 3);
  const int bx = wg % nbx;
  const int t1 = wg / nbx;
  const int kz = t1 % KS, by = t1 / KS;
  const int row0 = by * 256, col0 = bx * 256;

  const int tilesK = K >> 6;
  const int qT = tilesK / KS, rT = tilesK % KS;
  const int tile0 = kz * qT + (kz < rT ? kz : rT);
  const int NT = qT + (kz < rT ? 1 : 0);
  const int kbase = tile0 << 6;

  const unsigned short* gA0 = A + (size_t)row0 * K + kbase;
  const unsigned short* gB0 = Bt + (size_t)col0 * K + kbase;
  const int srow8 = lane >> 3;
  const int schunk = ((lane & 7) ^ srow8) * 8;

  f32x4 acc[8][4] = {};
  bf16x8 af[4][2], bfr[4][2];

  auto stA = [&](int buf, int k0, int i) {
    const int r = wid * 32 + i * 8;
    GLOAD_LDS16(gA0 + (size_t)(r + srow8) * K + k0 + schunk, &sA[buf][r * 64]);
  };
  auto stB = [&](int buf, int k0, int i) {
    const int r = wid * 32 + i * 8;
    GLOAD_LDS16(gB0 + (size_t)(r + srow8) * K + k0 + schunk, &sB[buf][r * 64]);
  };
  auto ldA = [&](const unsigned short* p, int m, int ks) -> bf16x8 {
    const int row = wm * 128 + m * 16 + r15;
    return *(const bf16x8_a*)&p[row * 64 + (((ks * 4 + g) ^ (r15 & 7)) * 8)];
  };
  auto ldB = [&](const unsigned short* p, int n, int ks) -> bf16x8 {
    const int row = wn * 64 + n * 16 + r15;
    return *(const bf16x8_a*)&p[row * 64 + (((ks * 4 + g) ^ (r15 & 7)) * 8)];
  };

#pragma unroll
  for (int i = 0; i < 4; ++i) { stA(0, 0, i); stB(0, 0, i); }
  asm volatile("s_waitcnt vmcnt(0)" ::: "memory");
  __builtin_amdgcn_s_barrier();

  for (int kt = 0; kt < NT; ++kt) {
    const int cb = kt & 1, nb = cb ^ 1;
    const bool pf = (kt + 1) < NT;
    const int k1 = (kt + 1) << 6;
    const unsigned short* pA = sA[cb];
    const unsigned short* pB = sB[cb];

#pragma unroll
    for (int m = 0; m < 4; ++m) { af[m][0] = ldA(pA, m, 0); af[m][1] = ldA(pA, m, 1); }
#pragma unroll
    for (int n = 0; n < 4; ++n) { bfr[n][0] = ldB(pB, n, 0); bfr[n][1] = ldB(pB, n, 1); }
    if (pf) { stA(nb, k1, 0); stA(nb, k1, 1); }
    __builtin_amdgcn_s_barrier();
    asm volatile("s_waitcnt lgkmcnt(0)" ::: "memory");
    __builtin_amdgcn_sched_barrier(0);
    __builtin_amdgcn_s_setprio(1);
#pragma unroll
    for (int m = 0; m < 4; ++m)
#pragma unroll
      for (int n = 0; n < 2; ++n) {
        acc[m][n] = MFMA_B16(af[m][0], bfr[n][0], acc[m][n]);
        acc[m][n] = MFMA_B16(af[m][1], bfr[n][1], acc[m][n]);
      }
    __builtin_amdgcn_s_setprio(0);
    __builtin_amdgcn_s_barrier();

    if (pf) { stA(nb, k1, 2); stA(nb, k1, 3); }
    __builtin_amdgcn_s_barrier();
    __builtin_amdgcn_s_setprio(1);
#pragma unroll
    for (int m = 0; m < 4; ++m)
#pragma unroll
      for (int n = 2; n < 4; ++n) {
        acc[m][n] = MFMA_B16(af[m][0], bfr[n][0], acc[m][n]);
        acc[m][n] = MFMA_B16(af[m][1], bfr[n][1], acc[m][n]);
      }
    __builtin_amdgcn_s_setprio(0);
    __builtin_amdgcn_s_barrier();

#pragma unroll
    for (int m = 0; m < 4; ++m) { af[m][0] = ldA(pA, m + 4, 0); af[m][1] = ldA(pA, m + 4, 1); }
    if (pf) { stB(nb, k1, 0); stB(nb, k1, 1); }
    __builtin_amdgcn_s_barrier();
    asm volatile("s_waitcnt lgkmcnt(0)" ::: "memory");
    __builtin_amdgcn_sched_barrier(0);
    __builtin_amdgcn_s_setprio(1);
#pragma unroll
    for (int m = 0; m < 4; ++m)
#pragma unroll
      for (int n = 0; n < 2; ++n) {
        acc[m + 4][n] = MFMA_B16(af[m][0], bfr[n][0], acc[m + 4][n]);
        acc[m + 4][n] = MFMA_B16(af[m][1], bfr[n][1], acc[m + 4][n]);
      }
    __builtin_amdgcn_s_setprio(0);
    __builtin_amdgcn_s_barrier();

    if (pf) { stB(nb, k1, 2); stB(nb, k1, 3); }
    __builtin_amdgcn_s_barrier();
    __builtin_amdgcn_s_setprio(1);
#pragma unroll
    for (int m = 0; m < 4; ++m)
#pragma unroll
      for (int n = 2; n < 4; ++n) {
        acc[m + 4][n] = MFMA_B16(af[m][0], bfr[n][0], acc[m + 4][n]);
        acc[m + 4][n] = MFMA_B16(af[m][1], bfr[n][1], acc[m + 4][n]);
      }
    __builtin_amdgcn_s_setprio(0);
    asm volatile("s_waitcnt vmcnt(0)" ::: "memory");
    __builtin_amdgcn_s_barrier();
  }

  unsigned short* pz = kz == 0 ? pp0 : (kz == 1 ? pp1 : (kz == 2 ? pp2 : pp3));
#pragma unroll
  for (int m = 0; m < 8; ++m) {
    const int rbase = row0 + wm * 128 + m * 16 + g * 4;
#pragma unroll
    for (int n = 0; n < 4; ++n) {
      const int col = col0 + wn * 64 + n * 16 + r15;
      const float bb = (EP == 3) ? 0.f : bias[col];
      if constexpr (EP == 0) {
        const int which = col >> 10, cc = col & 1023;
        const int hh = cc >> 6, e = cc & 63;
        const int b = rbase >> 11, s0v = rbase & 2047;
        if (which == 2) {
          bf16x4_a pk;
#pragma unroll
          for (int r = 0; r < 4; ++r) pk[r] = (__bf16)(acc[m][n][r] + bb);
          *(bf16x4_a*)(v_out + (((size_t)(b * 16 + hh) * 64) + e) * 2048 + s0v) = pk;
        } else {
          unsigned short* dst = which == 0 ? q_out : k_out;
#pragma unroll
          for (int r = 0; r < 4; ++r)
            dst[(((size_t)(b * 16 + hh) * 2048) + s0v + r) * 64 + e] =
                f2b(acc[m][n][r] + bb);
        }
      } else {
#pragma unroll
        for (int r = 0; r < 4; ++r) {
          const int row = rbase + r;
          float v = acc[m][n][r] + bb;
          if constexpr (EP == 3) {
            pz[(size_t)row * N + col] = f2b(v);
          } else {
            outb[(size_t)row * N + col] = f2b(v > 0.f ? v : 0.f);
          }
        }
      }
    }
  }
}

// ---------- 128x128 GEMM, split-K over blockIdx.z, bf16 partial out ----------
__global__ __launch_bounds__(256) void gemm_bt_kernel(
    const unsigned short* __restrict__ A, const unsigned short* __restrict__ Bt,
    int M, int N, int Kchunk, int Kstride,
    unsigned short* __restrict__ pp0, unsigned short* __restrict__ pp1) {
  __shared__ __align__(16) unsigned short sA[2][128 * 32];
  __shared__ __align__(16) unsigned short sB[2][128 * 32];
  const int tid = threadIdx.x;
  const int wid = tid >> 6, lane = tid & 63;
  const int g = lane >> 4, r15 = lane & 15;
  const int wr = wid >> 1, wc = wid & 1;
  const int row0 = blockIdx.y * 128, col0 = blockIdx.x * 128;
  const int kz = blockIdx.z;

  f32x4 acc[4][4] = {};

  const int c0 = wid * 128 + lane;
  const unsigned short* gA0 = A + (size_t)row0 * Kstride + (size_t)kz * Kchunk;
  const unsigned short* gB0 = Bt + (size_t)col0 * Kstride + (size_t)kz * Kchunk;

  auto stage = [&](int buf, int k0) {
#pragma unroll
    for (int j = 0; j < 2; ++j) {
      int c = c0 + j * 64;
      GLOAD_LDS16(gA0 + (size_t)(c >> 2) * Kstride + k0 + (c & 3) * 8,
                  &sA[buf][(wid * 128 + j * 64) * 8]);
      GLOAD_LDS16(gB0 + (size_t)(c >> 2) * Kstride + k0 + (c & 3) * 8,
                  &sB[buf][(wid * 128 + j * 64) * 8]);
    }
  };

  stage(0, 0);
  const int NT = Kchunk >> 5;
  for (int t = 0; t < NT; ++t) {
    const int cb = t & 1;
    __syncthreads();
    if (t + 1 < NT) stage(cb ^ 1, (t + 1) * 32);
    bf16x8 af[4], bfr[4];
#pragma unroll
    for (int m = 0; m < 4; ++m)
      af[m] = *(const bf16x8_a*)&sA[cb][(wr * 64 + m * 16 + r15) * 32 + g * 8];
#pragma unroll
    for (int n = 0; n < 4; ++n)
      bfr[n] = *(const bf16x8_a*)&sB[cb][(wc * 64 + n * 16 + r15) * 32 + g * 8];
#pragma unroll
    for (int m = 0; m < 4; ++m)
#pragma unroll
      for (int n = 0; n < 4; ++n)
        acc[m][n] = MFMA_B16(af[m], bfr[n], acc[m][n]);
  }

  unsigned short* pz = kz == 0 ? pp0 : pp1;
#pragma unroll
  for (int m = 0; m < 4; ++m) {
    const int rbase = row0 + wr * 64 + m * 16 + g * 4;
#pragma unroll
    for (int n = 0; n < 4; ++n) {
      const int col = col0 + wc * 64 + n * 16 + r15;
#pragma unroll
      for (int r = 0; r < 4; ++r)
        pz[(size_t)(rbase + r) * N + col] = f2b(acc[m][n][r]);
    }
  }
}

// ---------- flash attention, swapped softmax, exp2, 2x-unrolled (frozen R10) ----------
__global__ __launch_bounds__(256) void attn_kernel(const unsigned short* __restrict__ Q,
                                                   const unsigned short* __restrict__ K,
                                                   const unsigned short* __restrict__ Vt,
                                                   unsigned short* __restrict__ out) {
  const int flat = blockIdx.y * gridDim.x + blockIdx.x;  // 0..1023
  const int xcd = flat & 7, rest = flat >> 3;
  const int bh = xcd * 4 + (rest >> 5);
  const int q0 = (rest & 31) * 64;

  const int tid = threadIdx.x, wid = tid >> 6, lane = tid & 63;
  const int g = lane >> 4, r15 = lane & 15;
  const int h = r15 & 7;
  const int s0 = ((g ^ h) * 8);
  const int s1 = (((g + 4) ^ h) * 8);
  const int pswz = r15 & 14;

  __shared__ __align__(16) unsigned short sK[2][64 * 64];
  __shared__ __align__(16) unsigned short sV[2][64 * 64];
  __shared__ __align__(16) unsigned short sP[4][16 * 64];

  const size_t base = (size_t)bh * (2048 * 64);
  const unsigned short* Kb = K + base;
  const unsigned short* Vb = Vt + base;

  const int qrow = q0 + wid * 16 + r15;
  bf16x8 qf[2];
  qf[0] = *(const bf16x8_a*)(Q + base + (size_t)qrow * 64 + g * 8);
  qf[1] = *(const bf16x8_a*)(Q + base + (size_t)qrow * 64 + 32 + g * 8);

  const int srow = lane >> 3;
  const int schunk = ((lane & 7) ^ srow) * 8;

  union {
    unsigned short u[8];
    bf16x8 v;
  } ou;
#pragma unroll
  for (int i = 0; i < 8; ++i) ou.u[i] = 0x3F80;
  const bf16x8 onesb = ou.v;

  f32x4 o[4] = {};
  float mrow = -1e30f, lrow = 0.f;

  const int krd0 = r15 * 64 + s0;
  const int krd1 = r15 * 64 + s1;
  unsigned short* const pw = &sP[wid][r15 * 64];
  const int pwr0 = ((2 * g) ^ pswz) << 2;
  const int pwr1 = ((8 + 2 * g) ^ pswz) << 2;

  auto stage = [&](int bufi, int kt0s) {
#pragma unroll
    for (int i = 0; i < 2; ++i) {
      const int inst = wid * 2 + i;
      const int row = 8 * inst + srow;
      GLOAD_LDS16(Kb + (size_t)(kt0s + row) * 64 + schunk, &sK[bufi][inst * 512]);
      GLOAD_LDS16(Vb + (size_t)row * 2048 + kt0s + schunk, &sV[bufi][inst * 512]);
    }
  };

  auto do_tile = [&](const unsigned short* kbuf, const unsigned short* vbuf) {
    f32x4 sc[4] = {};
#pragma unroll
    for (int kt = 0; kt < 4; ++kt) {
      bf16x8 kf0 = *(const bf16x8_a*)&kbuf[kt * 1024 + krd0];
      bf16x8 kf1 = *(const bf16x8_a*)&kbuf[kt * 1024 + krd1];
      sc[kt] = MFMA_B16(kf0, qf[0], sc[kt]);
      sc[kt] = MFMA_B16(kf1, qf[1], sc[kt]);
    }

    float a0 = fmaxf(fmaxf(sc[0][0], sc[0][1]), sc[0][2]);
    float a1 = fmaxf(fmaxf(sc[0][3], sc[1][0]), sc[1][1]);
    float a2 = fmaxf(fmaxf(sc[1][2], sc[1][3]), sc[2][0]);
    float a3 = fmaxf(fmaxf(sc[2][1], sc[2][2]), sc[2][3]);
    float a4 = fmaxf(fmaxf(sc[3][0], sc[3][1]), sc[3][2]);
    float b0 = fmaxf(fmaxf(a0, a1), a2);
    float b1 = fmaxf(fmaxf(a3, a4), sc[3][3]);
    float pmax = fmaxf(b0, b1);
    pmax = fmaxf(pmax, __shfl_xor(pmax, 16));
    pmax = fmaxf(pmax, __shfl_xor(pmax, 32));

    const bool allkeep = __all(pmax - mrow <= 11.5441f);
    float fac;
    if (allkeep) {
      fac = 1.0f;
    } else {
      float nm = fmaxf(mrow, pmax);
      fac = EXP2(mrow - nm);
      mrow = nm;
#pragma unroll
      for (int dt = 0; dt < 4; ++dt)
#pragma unroll
        for (int r = 0; r < 4; ++r) o[dt][r] *= fac;
    }

#pragma unroll
    for (int kt = 0; kt < 4; ++kt) {
      bf16x4_a pb;
      pb[0] = (__bf16)EXP2(sc[kt][0] - mrow);
      pb[1] = (__bf16)EXP2(sc[kt][1] - mrow);
      pb[2] = (__bf16)EXP2(sc[kt][2] - mrow);
      pb[3] = (__bf16)EXP2(sc[kt][3] - mrow);
      *(bf16x4_a*)&pw[((4 * kt + g) ^ pswz) << 2] = pb;
    }

    bf16x8 pf0 = *(const bf16x8_a*)&pw[pwr0];
    bf16x8 pf1 = *(const bf16x8_a*)&pw[pwr1];

    f32x4 lacc = {};
    lacc = MFMA_B16(onesb, pf0, lacc);
    lacc = MFMA_B16(onesb, pf1, lacc);
    lrow = lrow * fac + lacc[0];

#pragma unroll
    for (int dt = 0; dt < 4; ++dt) {
      bf16x8 vf0 = *(const bf16x8_a*)&vbuf[dt * 1024 + krd0];
      bf16x8 vf1 = *(const bf16x8_a*)&vbuf[dt * 1024 + krd1];
      o[dt] = MFMA_B16(vf0, pf0, o[dt]);
      o[dt] = MFMA_B16(vf1, pf1, o[dt]);
    }
  };

  stage(0, 0);
#pragma unroll 1
  for (int t = 0; t < 32; t += 2) {
    __syncthreads();
    stage(1, (t + 1) * 64);
    do_tile(&sK[0][0], &sV[0][0]);
    __syncthreads();
    if (t + 2 < 32) stage(0, (t + 2) * 64);
    do_tile(&sK[1][0], &sV[1][0]);
  }

  const int b = bh >> 4, hh = bh & 15;
  const int s = q0 + wid * 16 + r15;
  const float inv = 1.f / lrow;
  unsigned short* orow = out + ((size_t)(b * 2048 + s)) * 1024 + hh * 64;
#pragma unroll
  for (int dt = 0; dt < 4; ++dt) {
    bf16x4_a tq;
    tq[0] = (__bf16)(o[dt][0] * inv);
    tq[1] = (__bf16)(o[dt][1] * inv);
    tq[2] = (__bf16)(o[dt][2] * inv);
    tq[3] = (__bf16)(o[dt][3] * inv);
    *(bf16x4_a*)(orow + dt * 16 + g * 4) = tq;
  }
}

// ---------- fused 2x bf16-partial reduce + bias + residual + LN -> f32 + bf16 ----------
__global__ __launch_bounds__(256) void ln2p_kernel(
    const unsigned short* __restrict__ p0, const unsigned short* __restrict__ p1,
    const float* __restrict__ bias, const float* __restrict__ resid,
    const float* __restrict__ gamma, const float* __restrict__ beta,
    float* __restrict__ outf, unsigned short* __restrict__ outb) {
  const int row = blockIdx.x, tid = threadIdx.x;
  const size_t off = (size_t)row * 1024;
  u16x4_a a4 = *(const u16x4_a*)(p0 + off + tid * 4);
  u16x4_a b4 = *(const u16x4_a*)(p1 + off + tid * 4);
  float4 bb4 = ((const float4*)bias)[tid];
  float4 rr = ((const float4*)(resid + off))[tid];
  float4 v;
  v.x = b2f(a4[0]) + b2f(b4[0]) + bb4.x + rr.x;
  v.y = b2f(a4[1]) + b2f(b4[1]) + bb4.y + rr.y;
  v.z = b2f(a4[2]) + b2f(b4[2]) + bb4.z + rr.z;
  v.w = b2f(a4[3]) + b2f(b4[3]) + bb4.w + rr.w;

  float s = v.x + v.y + v.z + v.w;
  float ss = v.x * v.x + v.y * v.y + v.z * v.z + v.w * v.w;
#pragma unroll
  for (int o2 = 32; o2 > 0; o2 >>= 1) {
    s += __shfl_down(s, o2);
    ss += __shfl_down(ss, o2);
  }
  __shared__ float red[8];
  const int wid = tid >> 6;
  if ((tid & 63) == 0) { red[wid] = s; red[4 + wid] = ss; }
  __syncthreads();
  float S = red[0] + red[1] + red[2] + red[3];
  float SS = red[4] + red[5] + red[6] + red[7];
  const float mean = S * (1.f / 1024.f);
  const float var = SS * (1.f / 1024.f) - mean * mean;
  const float inv = 1.f / sqrtf(var + 1e-10f);
  float4 gg = ((const float4*)gamma)[tid];
  float4 be = ((const float4*)beta)[tid];
  float4 o;
  o.x = (v.x - mean) * inv * gg.x + be.x;
  o.y = (v.y - mean) * inv * gg.y + be.y;
  o.z = (v.z - mean) * inv * gg.z + be.z;
  o.w = (v.w - mean) * inv * gg.w + be.w;
  ((float4*)(outf + off))[tid] = o;
  u16x4_a t = {f2b(o.x), f2b(o.y), f2b(o.z), f2b(o.w)};
  *(u16x4_a*)(outb + off + tid * 4) = t;
}

// ---------- fused 4x bf16-partial reduce + bias + residual + LN -> f32 ----------
__global__ __launch_bounds__(256) void ln4p_kernel(
    const unsigned short* __restrict__ p0, const unsigned short* __restrict__ p1,
    const unsigned short* __restrict__ p2, const unsigned short* __restrict__ p3,
    const float* __restrict__ bias, const float* __restrict__ resid,
    const float* __restrict__ gamma, const float* __restrict__ beta,
    float* __restrict__ outf) {
  const int row = blockIdx.x, tid = threadIdx.x;
  const size_t off = (size_t)row * 1024;
  u16x4_a a4 = *(const u16x4_a*)(p0 + off + tid * 4);
  u16x4_a b4 = *(const u16x4_a*)(p1 + off + tid * 4);
  u16x4_a c4 = *(const u16x4_a*)(p2 + off + tid * 4);
  u16x4_a d4 = *(const u16x4_a*)(p3 + off + tid * 4);
  float4 bb4 = ((const float4*)bias)[tid];
  float4 rr = ((const float4*)(resid + off))[tid];
  float4 v;
  v.x = (b2f(a4[0]) + b2f(b4[0])) + (b2f(c4[0]) + b2f(d4[0])) + bb4.x + rr.x;
  v.y = (b2f(a4[1]) + b2f(b4[1])) + (b2f(c4[1]) + b2f(d4[1])) + bb4.y + rr.y;
  v.z = (b2f(a4[2]) + b2f(b4[2])) + (b2f(c4[2]) + b2f(d4[2])) + bb4.z + rr.z;
  v.w = (b2f(a4[3]) + b2f(b4[3])) + (b2f(c4[3]) + b2f(d4[3])) + bb4.w + rr.w;

  float s = v.x + v.y + v.z + v.w;
  float ss = v.x * v.x + v.y * v.y + v.z * v.z + v.w * v.w;
#pragma unroll
  for (int o2 = 32; o2 > 0; o2 >>= 1) {
    s += __shfl_down(s, o2);
    ss += __shfl_down(ss, o2);
  }
  __shared__ float red[8];
  const int wid = tid >> 6;
  if ((tid & 63) == 0) { red[wid] = s; red[4 + wid] = ss; }
  __syncthreads();
  float S = red[0] + red[1] + red[2] + red[3];
  float SS = red[4] + red[5] + red[6] + red[7];
  const float mean = S * (1.f / 1024.f);
  const float var = SS * (1.f / 1024.f) - mean * mean;
  const float inv = 1.f / sqrtf(var + 1e-10f);
  float4 gg = ((const float4*)gamma)[tid];
  float4 be = ((const float4*)beta)[tid];
  float4 o;
  o.x = (v.x - mean) * inv * gg.x + be.x;
  o.y = (v.y - mean) * inv * gg.y + be.y;
  o.z = (v.z - mean) * inv * gg.z + be.z;
  o.w = (v.w - mean) * inv * gg.w + be.w;
  ((float4*)(outf + off))[tid] = o;
}

// ---------- launch ----------
extern "C" void kernel_launch(void* const* d_in, const int* in_sizes, int n_in,
                              void* d_out, int out_size, void* d_ws, size_t ws_size,
                              hipStream_t stream) {
  const float* x      = (const float*)d_in[0];
  const float* wq     = (const float*)d_in[1];
  const float* bq     = (const float*)d_in[2];
  const float* wk     = (const float*)d_in[3];
  const float* bk     = (const float*)d_in[4];
  const float* wv     = (const float*)d_in[5];
  const float* bv     = (const float*)d_in[6];
  const float* w_proj = (const float*)d_in[7];
  const float* b_proj = (const float*)d_in[8];
  const float* gamma1 = (const float*)d_in[9];
  const float* beta1  = (const float*)d_in[10];
  const float* w1     = (const float*)d_in[11];
  const float* b1     = (const float*)d_in[12];
  const float* w2     = (const float*)d_in[13];
  const float* b2     = (const float*)d_in[14];
  const float* gamma2 = (const float*)d_in[15];
  const float* beta2  = (const float*)d_in[16];

  char* p = (char*)d_ws;
  auto alloc = [&](size_t bytes) {
    char* r = p;
    p += (bytes + 255) & ~(size_t)255;
    return r;
  };
  unsigned short* xb      = (unsigned short*)alloc(4096ull * 1024 * 2);  // 8MB; dead after proj
  unsigned short* Wqkv_t  = (unsigned short*)alloc(3072ull * 1024 * 2);  // 6MB; dead after QKV
  unsigned short* Wproj_t = (unsigned short*)alloc(1024ull * 1024 * 2);  // 2MB; dead after proj
  unsigned short* W2t     = (unsigned short*)alloc(1024ull * 4096 * 2);  // 8MB; live thru FFN2
  float*          biasq   = (float*)alloc(3072 * 4);
  unsigned short* Qb      = (unsigned short*)alloc(4096ull * 1024 * 2);  // 8MB; dead after attn
  unsigned short* Kb      = (unsigned short*)alloc(4096ull * 1024 * 2);  // 8MB; dead after attn
  unsigned short* Vtb     = (unsigned short*)alloc(4096ull * 1024 * 2);  // 8MB; dead after attn
  unsigned short* W1t     = (unsigned short*)alloc(4096ull * 1024 * 2);  // 8MB; dead after FFN1
  float*          out1f   = (float*)alloc(4096ull * 1024 * 4);           // live thru ln4p
  unsigned short* out1b   = (unsigned short*)alloc(4096ull * 1024 * 2);  // dead after FFN1
  unsigned short* ffn_h   = (unsigned short*)alloc(4096ull * 4096 * 2);  // live thru FFN2
  unsigned short* concat  = xb;

  // proj split-K=2 bf16 partials (8MB each; Qb/Kb dead after attn):
  unsigned short* prA = Qb;
  unsigned short* prB = Kb;
  // FFN2 split-K=4 bf16 partials (8MB each; all dead at FFN2 launch):
  unsigned short* pp0 = xb;
  unsigned short* pp1 = Qb;
  unsigned short* pp2 = Kb;
  unsigned short* pp3 = Vtb;

  prepass_kernel<<<16396, 256, 0, stream>>>(x, wq, wk, wv, w_proj, w1, w2, bq, bk, bv,
                                            xb, Wqkv_t, Wproj_t, W1t, W2t, biasq);

  gemm256_kernel<0><<<192, 512, 0, stream>>>(xb, Wqkv_t, 4096, 3072, 1024, 12, 1, biasq,
                                             nullptr, Qb, Kb, Vtb, nullptr, nullptr,
                                             nullptr, nullptr);
  attn_kernel<<<dim3(32, 32), 256, 0, stream>>>(Qb, Kb, Vtb, concat);
  gemm_bt_kernel<<<dim3(8, 32, 2), 256, 0, stream>>>(concat, Wproj_t, 4096, 1024, 512, 1024,
                                                     prA, prB);
  ln2p_kernel<<<4096, 256, 0, stream>>>(prA, prB, b_proj, x, gamma1, beta1, out1f, out1b);
  gemm256_kernel<2><<<256, 512, 0, stream>>>(out1b, W1t, 4096, 4096, 1024, 16, 1, b1,
                                             ffn_h, nullptr, nullptr, nullptr,
                                             nullptr, nullptr, nullptr, nullptr);
  gemm256_kernel<3><<<256, 512, 0, stream>>>(ffn_h, W2t, 4096, 1024, 4096, 4, 4, nullptr,
                                             nullptr, nullptr, nullptr, nullptr,
                                             pp0, pp1, pp2, pp3);
  ln4p_kernel<<<4096, 256, 0, stream>>>(pp0, pp1, pp2, pp3, b2, out1f, gamma2, beta2,
                                        (float*)d_out);
}